// Round 2
// baseline (390.029 us; speedup 1.0000x reference)
//
#include <hip/hip_runtime.h>
#include <stdint.h>

#define B_ 4
#define T1_ 4096
#define T2_ 2048
#define C_ 512
#define H_ 8
#define D_ 64
#define M1_ (B_*T1_)   // 16384
#define M2_ (B_*T2_)   // 8192

using f32x4 = __attribute__((ext_vector_type(4))) float;
using bf16x8 = __attribute__((ext_vector_type(8))) __bf16;
using us8 = __attribute__((ext_vector_type(8))) unsigned short;
using us4 = __attribute__((ext_vector_type(4))) unsigned short;

__device__ __forceinline__ unsigned short f2bf(float f){
  unsigned int u = __builtin_bit_cast(unsigned int, f);
  unsigned int r = (u + 0x7fffu + ((u >> 16) & 1u)) >> 16;
  return (unsigned short)r;
}
__device__ __forceinline__ float bf2f(unsigned short u){
  return __builtin_bit_cast(float, ((unsigned int)u) << 16);
}
__device__ __forceinline__ f32x4 mfma16(us8 a, us8 b, f32x4 c){
  return __builtin_amdgcn_mfma_f32_16x16x32_bf16(
      __builtin_bit_cast(bf16x8, a), __builtin_bit_cast(bf16x8, b), c, 0, 0, 0);
}

typedef const __attribute__((address_space(1))) unsigned int gu32;
typedef __attribute__((address_space(3))) unsigned int lu32;
__device__ __forceinline__ void gl_lds16(const void* g, void* l){
  __builtin_amdgcn_global_load_lds((gu32*)g, (lu32*)l, 16, 0, 0);
}

// ---------------- fp32 -> bf16 convert ----------------
__global__ __launch_bounds__(256) void cvt_bf16(const float* __restrict__ in,
                                                unsigned short* __restrict__ out, int n4){
  int i = blockIdx.x * 256 + threadIdx.x;
  if (i >= n4) return;
  f32x4 v = ((const f32x4*)in)[i];
  us4 o;
  #pragma unroll
  for (int j = 0; j < 4; ++j) o[j] = f2bf(v[j]);
  ((us4*)out)[i] = o;
}

// ---------- C-layout fp32 vals -> swizzled bf16 LDS tile -> coalesced store ----------
__device__ __forceinline__ void tile_write(unsigned short* tile, const f32x4 (&vals)[4][4],
                                           int wr, int wc, int lr, int lk){
  #pragma unroll
  for (int mt = 0; mt < 4; ++mt)
    #pragma unroll
    for (int nt = 0; nt < 4; ++nt)
      #pragma unroll
      for (int r = 0; r < 4; ++r){
        int row = wr*64 + mt*16 + lk*4 + r;
        int cb  = (wc*128 + nt*32 + lr*2) ^ ((row & 7) << 4);
        *(unsigned short*)((char*)tile + row*256 + cb) = f2bf(vals[mt][nt][r]);
      }
}
__device__ __forceinline__ void tile_flush(const unsigned short* tile, unsigned short* g,
                                           size_t row0, int col0, int ldg, int t){
  #pragma unroll
  for (int p = 0; p < 8; ++p){
    int row = p*16 + (t >> 4);
    int cb  = ((t & 15) * 16) ^ ((row & 7) << 4);
    us8 v = *(const us8*)((const char*)tile + row*256 + cb);
    *(us8*)(g + (row0 + row) * (size_t)ldg + col0 + (t & 15) * 8) = v;
  }
}

// ---------------- plain GEMM: out(fp32) = A[M,K] @ Bw[N,K]^T + bias ----------------
__global__ __launch_bounds__(256) void gemm_bt(const unsigned short* __restrict__ A,
                                               const unsigned short* __restrict__ Bw,
                                               const float* __restrict__ bias,
                                               float* __restrict__ out, int M, int N, int Kd){
  __shared__ unsigned short ldsA[128*32];
  __shared__ unsigned short ldsB[128*32];
  const int m0 = blockIdx.x * 128, n0 = blockIdx.y * 128;
  const int t = threadIdx.x;
  const int w = t >> 6, l = t & 63;
  const int wr = w >> 1, wc = w & 1;
  const int lr = l & 15, lk = l >> 4;
  f32x4 acc[4][4] = {};
  for (int k0 = 0; k0 < Kd; k0 += 32){
    {
      int c = t, row = c >> 2, off = (c & 3) * 8;
      gl_lds16(A  + (size_t)(m0+row)*Kd + k0 + off, &ldsA[c*8]);
      gl_lds16(Bw + (size_t)(n0+row)*Kd + k0 + off, &ldsB[c*8]);
      c = t + 256; row = c >> 2; off = (c & 3) * 8;
      gl_lds16(A  + (size_t)(m0+row)*Kd + k0 + off, &ldsA[c*8]);
      gl_lds16(Bw + (size_t)(n0+row)*Kd + k0 + off, &ldsB[c*8]);
    }
    __syncthreads();
    us8 af[4], bfr[4];
    #pragma unroll
    for (int mt = 0; mt < 4; ++mt)
      af[mt] = *(const us8*)&ldsA[(wr*64 + mt*16 + lr)*32 + lk*8];
    #pragma unroll
    for (int nt = 0; nt < 4; ++nt)
      bfr[nt] = *(const us8*)&ldsB[(wc*64 + nt*16 + lr)*32 + lk*8];
    #pragma unroll
    for (int mt = 0; mt < 4; ++mt)
      #pragma unroll
      for (int nt = 0; nt < 4; ++nt)
        acc[mt][nt] = mfma16(af[mt], bfr[nt], acc[mt][nt]);
    __syncthreads();
  }
  #pragma unroll
  for (int mt = 0; mt < 4; ++mt)
    #pragma unroll
    for (int nt = 0; nt < 4; ++nt)
      #pragma unroll
      for (int r = 0; r < 4; ++r){
        int row = m0 + wr*64 + mt*16 + lk*4 + r;
        int col = n0 + wc*64 + nt*16 + lr;
        out[(size_t)row*N + col] = acc[mt][nt][r] + bias[col];
      }
}

// ---------------- fused K+V projection: softmax(K), colsum atomics, bf16 stores ----------------
__global__ __launch_bounds__(256) void kv_fused(const unsigned short* __restrict__ yball,
                                                const unsigned short* __restrict__ wkb,
                                                const unsigned short* __restrict__ wvb,
                                                const float* __restrict__ bk,
                                                const float* __restrict__ bv,
                                                unsigned short* __restrict__ kb,
                                                unsigned short* __restrict__ vb,
                                                float* __restrict__ ksum){
  __shared__ unsigned short smem[16384];       // 32 KB: staging 24 KB, then repack tile 32 KB
  unsigned short* sA = smem;
  unsigned short* sK = smem + 4096;
  unsigned short* sV = smem + 8192;
  const int i = blockIdx.z;
  const int m0 = blockIdx.x * 128, n0 = blockIdx.y * 128;
  const unsigned short* A  = yball + (size_t)i*M2_*C_;
  const unsigned short* Wk = wkb  + (size_t)i*C_*C_;
  const unsigned short* Wv = wvb  + (size_t)i*C_*C_;
  const int t = threadIdx.x;
  const int w = t >> 6, l = t & 63;
  const int wr = w >> 1, wc = w & 1;
  const int lr = l & 15, lk = l >> 4;
  f32x4 aK[4][4] = {}, aV[4][4] = {};
  for (int k0 = 0; k0 < C_; k0 += 32){
    {
      int c = t, row = c >> 2, off = (c & 3) * 8;
      gl_lds16(A  + (size_t)(m0+row)*C_ + k0 + off, &sA[c*8]);
      gl_lds16(Wk + (size_t)(n0+row)*C_ + k0 + off, &sK[c*8]);
      gl_lds16(Wv + (size_t)(n0+row)*C_ + k0 + off, &sV[c*8]);
      c = t + 256; row = c >> 2; off = (c & 3) * 8;
      gl_lds16(A  + (size_t)(m0+row)*C_ + k0 + off, &sA[c*8]);
      gl_lds16(Wk + (size_t)(n0+row)*C_ + k0 + off, &sK[c*8]);
      gl_lds16(Wv + (size_t)(n0+row)*C_ + k0 + off, &sV[c*8]);
    }
    __syncthreads();
    us8 af[4];
    #pragma unroll
    for (int mt = 0; mt < 4; ++mt)
      af[mt] = *(const us8*)&sA[(wr*64 + mt*16 + lr)*32 + lk*8];
    {
      us8 bf_[4];
      #pragma unroll
      for (int nt = 0; nt < 4; ++nt)
        bf_[nt] = *(const us8*)&sK[(wc*64 + nt*16 + lr)*32 + lk*8];
      #pragma unroll
      for (int mt = 0; mt < 4; ++mt)
        #pragma unroll
        for (int nt = 0; nt < 4; ++nt)
          aK[mt][nt] = mfma16(af[mt], bf_[nt], aK[mt][nt]);
    }
    {
      us8 bf_[4];
      #pragma unroll
      for (int nt = 0; nt < 4; ++nt)
        bf_[nt] = *(const us8*)&sV[(wc*64 + nt*16 + lr)*32 + lk*8];
      #pragma unroll
      for (int mt = 0; mt < 4; ++mt)
        #pragma unroll
        for (int nt = 0; nt < 4; ++nt)
          aV[mt][nt] = mfma16(af[mt], bf_[nt], aV[mt][nt]);
    }
    __syncthreads();
  }
  // bias
  float bKc[4], bVc[4];
  #pragma unroll
  for (int nt = 0; nt < 4; ++nt){
    int col = n0 + wc*64 + nt*16 + lr;
    bKc[nt] = bk[(size_t)i*C_ + col];
    bVc[nt] = bv[(size_t)i*C_ + col];
  }
  #pragma unroll
  for (int mt = 0; mt < 4; ++mt)
    #pragma unroll
    for (int nt = 0; nt < 4; ++nt)
      #pragma unroll
      for (int r = 0; r < 4; ++r){
        aK[mt][nt][r] += bKc[nt];
        aV[mt][nt][r] += bVc[nt];
      }
  // in-register softmax over the wave's 64-col head group (lanes share lk)
  #pragma unroll
  for (int mt = 0; mt < 4; ++mt)
    #pragma unroll
    for (int r = 0; r < 4; ++r){
      float m = fmaxf(fmaxf(aK[mt][0][r], aK[mt][1][r]), fmaxf(aK[mt][2][r], aK[mt][3][r]));
      #pragma unroll
      for (int s = 1; s < 16; s <<= 1) m = fmaxf(m, __shfl_xor(m, s, 64));
      float sum = 0.f;
      #pragma unroll
      for (int nt = 0; nt < 4; ++nt){
        float e = __expf(aK[mt][nt][r] - m);
        aK[mt][nt][r] = e; sum += e;
      }
      #pragma unroll
      for (int s = 1; s < 16; s <<= 1) sum += __shfl_xor(sum, s, 64);
      float inv = 1.0f / sum;
      #pragma unroll
      for (int nt = 0; nt < 4; ++nt) aK[mt][nt][r] *= inv;
    }
  // colsum -> ksum atomics (sum across mt,r then across lk groups)
  {
    const int b = m0 / T2_;
    #pragma unroll
    for (int nt = 0; nt < 4; ++nt){
      float cs = 0.f;
      #pragma unroll
      for (int mt = 0; mt < 4; ++mt)
        #pragma unroll
        for (int r = 0; r < 4; ++r) cs += aK[mt][nt][r];
      cs += __shfl_xor(cs, 16, 64);
      cs += __shfl_xor(cs, 32, 64);
      if (lk == 0)
        atomicAdd(&ksum[((size_t)i*B_ + b)*C_ + n0 + wc*64 + nt*16 + lr], cs);
    }
  }
  // repack + store K then V
  tile_write(smem, aK, wr, wc, lr, lk);
  __syncthreads();
  tile_flush(smem, kb + (size_t)i*M2_*C_, m0, n0, C_, t);
  __syncthreads();
  tile_write(smem, aV, wr, wc, lr, lk);
  __syncthreads();
  tile_flush(smem, vb + (size_t)i*M2_*C_, m0, n0, C_, t);
}

// ---------------- context partials: part[i][ch][bh][e*64+d] = sum_n k[n,d] v[n,e] ----------------
__global__ __launch_bounds__(256) void ctx_partial(const unsigned short* __restrict__ kb,
                                                   const unsigned short* __restrict__ vb,
                                                   float* __restrict__ part){
  __shared__ unsigned short lk_[16384];
  __shared__ unsigned short lv_[16384];
  const int bh = blockIdx.x, ch = blockIdx.y, i = blockIdx.z;
  const int b = bh >> 3, h = bh & 7;
  const int t = threadIdx.x;
  const unsigned short* kbi = kb + (size_t)i*M2_*C_;
  const unsigned short* vbi = vb + (size_t)i*M2_*C_;
  size_t rowbase = (size_t)(b*T2_ + ch*256);
  #pragma unroll
  for (int it = 0; it < 8; ++it){
    int c = t + it*256;
    int row = c >> 3, off = (c & 7) * 8;
    gl_lds16(kbi + (rowbase + row)*C_ + h*D_ + off, &lk_[c*8]);
    gl_lds16(vbi + (rowbase + row)*C_ + h*D_ + off, &lv_[c*8]);
  }
  __syncthreads();
  int d0 = (t & 15) * 4, e0 = (t >> 4) * 4;
  float acc[4][4] = {};
  for (int n = 0; n < 256; ++n){
    us4 kq = *(const us4*)&lk_[n*64 + d0];
    us4 vq = *(const us4*)&lv_[n*64 + e0];
    float kf[4], vf[4];
    #pragma unroll
    for (int j = 0; j < 4; ++j){ kf[j] = bf2f(kq[j]); vf[j] = bf2f(vq[j]); }
    #pragma unroll
    for (int jd = 0; jd < 4; ++jd)
      #pragma unroll
      for (int je = 0; je < 4; ++je)
        acc[jd][je] += kf[jd] * vf[je];
  }
  float* dst = part + (((size_t)i*8 + ch)*32 + bh) * 4096;
  #pragma unroll
  for (int jd = 0; jd < 4; ++jd)
    #pragma unroll
    for (int je = 0; je < 4; ++je)
      dst[(e0+je)*64 + (d0+jd)] = acc[jd][je];
}

__global__ __launch_bounds__(256) void ctx_reduce(const float* __restrict__ part,
                                                  unsigned short* __restrict__ ctxTb){
  const int bh = blockIdx.x, i = blockIdx.y, t = threadIdx.x;
  for (int idx = t; idx < 4096; idx += 256){
    float s = 0.f;
    #pragma unroll
    for (int ch = 0; ch < 8; ++ch)
      s += part[(((size_t)i*8 + ch)*32 + bh)*4096 + idx];
    ctxTb[((size_t)i*32 + bh)*4096 + idx] = f2bf(s);
  }
}

// ---------------- fused Q: GEMM + softmax + (den, q@ctx, fold) -> omid ----------------
__global__ __launch_bounds__(256) void q_mega(const unsigned short* __restrict__ xb,
                                              const unsigned short* __restrict__ wqb,
                                              const float* __restrict__ bq,
                                              const unsigned short* __restrict__ ctxTb,
                                              const float* __restrict__ ksum,
                                              unsigned short* __restrict__ omid){
  __shared__ unsigned short smem[16384];       // staging 16 KB, then q/omid tile 32 KB
  unsigned short* sA = smem;
  unsigned short* sB = smem + 4096;
  const int m0 = blockIdx.x * 128, n0 = blockIdx.y * 128;
  const int t = threadIdx.x;
  const int w = t >> 6, l = t & 63;
  const int wr = w >> 1, wc = w & 1;
  const int lr = l & 15, lk = l >> 4;
  f32x4 acc[4][4] = {};
  for (int k0 = 0; k0 < C_; k0 += 32){
    {
      int c = t, row = c >> 2, off = (c & 3) * 8;
      gl_lds16(xb  + (size_t)(m0+row)*C_ + k0 + off, &sA[c*8]);
      gl_lds16(wqb + (size_t)(n0+row)*C_ + k0 + off, &sB[c*8]);
      c = t + 256; row = c >> 2; off = (c & 3) * 8;
      gl_lds16(xb  + (size_t)(m0+row)*C_ + k0 + off, &sA[c*8]);
      gl_lds16(wqb + (size_t)(n0+row)*C_ + k0 + off, &sB[c*8]);
    }
    __syncthreads();
    us8 af[4], bfr[4];
    #pragma unroll
    for (int mt = 0; mt < 4; ++mt)
      af[mt] = *(const us8*)&sA[(wr*64 + mt*16 + lr)*32 + lk*8];
    #pragma unroll
    for (int nt = 0; nt < 4; ++nt)
      bfr[nt] = *(const us8*)&sB[(wc*64 + nt*16 + lr)*32 + lk*8];
    #pragma unroll
    for (int mt = 0; mt < 4; ++mt)
      #pragma unroll
      for (int nt = 0; nt < 4; ++nt)
        acc[mt][nt] = mfma16(af[mt], bfr[nt], acc[mt][nt]);
    __syncthreads();
  }
  // bias + softmax
  {
    float bc[4];
    #pragma unroll
    for (int nt = 0; nt < 4; ++nt) bc[nt] = bq[n0 + wc*64 + nt*16 + lr];
    #pragma unroll
    for (int mt = 0; mt < 4; ++mt)
      #pragma unroll
      for (int r = 0; r < 4; ++r){
        #pragma unroll
        for (int nt = 0; nt < 4; ++nt) acc[mt][nt][r] += bc[nt];
        float m = fmaxf(fmaxf(acc[mt][0][r], acc[mt][1][r]), fmaxf(acc[mt][2][r], acc[mt][3][r]));
        #pragma unroll
        for (int s = 1; s < 16; s <<= 1) m = fmaxf(m, __shfl_xor(m, s, 64));
        float sum = 0.f;
        #pragma unroll
        for (int nt = 0; nt < 4; ++nt){
          float e = __expf(acc[mt][nt][r] - m);
          acc[mt][nt][r] = e; sum += e;
        }
        #pragma unroll
        for (int s = 1; s < 16; s <<= 1) sum += __shfl_xor(sum, s, 64);
        float inv = 1.0f / sum;
        #pragma unroll
        for (int nt = 0; nt < 4; ++nt) acc[mt][nt][r] *= inv;
      }
  }
  const int b = m0 / T1_;
  const int bh = b*8 + (n0 >> 6) + wc;
  // q -> swizzled tile, then A-frags
  tile_write(smem, acc, wr, wc, lr, lk);
  __syncthreads();
  us8 afr[4][2];
  #pragma unroll
  for (int mt = 0; mt < 4; ++mt)
    #pragma unroll
    for (int kk = 0; kk < 2; ++kk){
      int row = wr*64 + mt*16 + lr;
      int cb = (wc*128 + kk*64 + lk*16) ^ ((row & 7) << 4);
      afr[mt][kk] = *(const us8*)((char*)smem + row*256 + cb);
    }
  // denominator MFMA: B rows 0..2 = ksum_i over this head's 64 channels
  us8 bden[2];
  #pragma unroll
  for (int kk = 0; kk < 2; ++kk){
    us8 tmp = {};
    if (lr < 3){
      const float* kp = ksum + ((size_t)lr*B_ + b)*C_ + n0 + wc*64 + kk*32 + lk*8;
      f32x4 c0 = *(const f32x4*)kp;
      f32x4 c1 = *(const f32x4*)(kp + 4);
      #pragma unroll
      for (int j = 0; j < 4; ++j){ tmp[j] = f2bf(c0[j]); tmp[4+j] = f2bf(c1[j]); }
    }
    bden[kk] = tmp;
  }
  f32x4 den[4] = {};
  #pragma unroll
  for (int mt = 0; mt < 4; ++mt)
    #pragma unroll
    for (int kk = 0; kk < 2; ++kk)
      den[mt] = mfma16(afr[mt][kk], bden[kk], den[mt]);
  // per-i: q@ctxT_i, fold with Dinv
  #pragma unroll 1
  for (int i = 0; i < 3; ++i){
    f32x4 dinv[4];
    #pragma unroll
    for (int mt = 0; mt < 4; ++mt)
      #pragma unroll
      for (int r = 0; r < 4; ++r)
        dinv[mt][r] = 1.0f / (__shfl(den[mt][r], (l & 48) | i, 64) + 1e-8f);
    #pragma unroll 1
    for (int nt = 0; nt < 4; ++nt){
      us8 bfr[2];
      #pragma unroll
      for (int kk = 0; kk < 2; ++kk)
        bfr[kk] = *(const us8*)(ctxTb + ((size_t)(i*32 + bh))*4096 + (nt*16 + lr)*64 + kk*32 + lk*8);
      f32x4 p[4] = {};
      #pragma unroll
      for (int mt = 0; mt < 4; ++mt)
        #pragma unroll
        for (int kk = 0; kk < 2; ++kk)
          p[mt] = mfma16(afr[mt][kk], bfr[kk], p[mt]);
      #pragma unroll
      for (int mt = 0; mt < 4; ++mt)
        #pragma unroll
        for (int r = 0; r < 4; ++r)
          acc[mt][nt][r] += p[mt][r] * dinv[mt][r];
    }
  }
  __syncthreads();   // all A-frag reads complete before tile reuse
  tile_write(smem, acc, wr, wc, lr, lk);
  __syncthreads();
  tile_flush(smem, omid, m0, n0, C_, t);
}

extern "C" void kernel_launch(void* const* d_in, const int* in_sizes, int n_in,
                              void* d_out, int out_size, void* d_ws, size_t ws_size,
                              hipStream_t stream){
  const float* x  = (const float*)d_in[0];
  const float* y0 = (const float*)d_in[1];
  const float* y1 = (const float*)d_in[2];
  const float* y2 = (const float*)d_in[3];
  const float* Wq = (const float*)d_in[4];
  const float* bq = (const float*)d_in[5];
  const float* Wk = (const float*)d_in[6];
  const float* bk = (const float*)d_in[7];
  const float* Wv = (const float*)d_in[8];
  const float* bv = (const float*)d_in[9];
  const float* Wo = (const float*)d_in[10];
  const float* bo = (const float*)d_in[11];

  char* ws = (char*)d_ws;
  size_t off = 0;
  auto alloc = [&](size_t bytes)->char*{
    char* p = ws + off; off += (bytes + 1023) & ~((size_t)1023); return p;
  };
  unsigned short* xb    = (unsigned short*)alloc((size_t)M1_*C_*2);
  unsigned short* yball = (unsigned short*)alloc((size_t)3*M2_*C_*2);
  unsigned short* wqb   = (unsigned short*)alloc((size_t)C_*C_*2);
  unsigned short* wkb   = (unsigned short*)alloc((size_t)3*C_*C_*2);
  unsigned short* wvb   = (unsigned short*)alloc((size_t)3*C_*C_*2);
  unsigned short* wob   = (unsigned short*)alloc((size_t)C_*C_*2);
  unsigned short* kb    = (unsigned short*)alloc((size_t)3*M2_*C_*2);
  unsigned short* vb    = (unsigned short*)alloc((size_t)3*M2_*C_*2);
  float*          ksum  = (float*)alloc((size_t)3*B_*C_*4);
  float*          part  = (float*)alloc((size_t)3*8*32*4096*4);
  unsigned short* ctxTb = (unsigned short*)alloc((size_t)3*32*4096*2);
  unsigned short* omid  = (unsigned short*)alloc((size_t)M1_*C_*2);

  hipMemsetAsync(ksum, 0, (size_t)3*B_*C_*4, stream);

  cvt_bf16<<<M1_*C_/4/256, 256, 0, stream>>>(x, xb, M1_*C_/4);
  cvt_bf16<<<M2_*C_/4/256, 256, 0, stream>>>(y0, yball, M2_*C_/4);
  cvt_bf16<<<M2_*C_/4/256, 256, 0, stream>>>(y1, yball + (size_t)M2_*C_, M2_*C_/4);
  cvt_bf16<<<M2_*C_/4/256, 256, 0, stream>>>(y2, yball + (size_t)2*M2_*C_, M2_*C_/4);
  cvt_bf16<<<C_*C_/4/256, 256, 0, stream>>>(Wq, wqb, C_*C_/4);
  cvt_bf16<<<3*C_*C_/4/256, 256, 0, stream>>>(Wk, wkb, 3*C_*C_/4);
  cvt_bf16<<<3*C_*C_/4/256, 256, 0, stream>>>(Wv, wvb, 3*C_*C_/4);
  cvt_bf16<<<C_*C_/4/256, 256, 0, stream>>>(Wo, wob, C_*C_/4);

  kv_fused<<<dim3(M2_/128, C_/128, 3), 256, 0, stream>>>(yball, wkb, wvb, bk, bv, kb, vb, ksum);
  ctx_partial<<<dim3(32, 8, 3), 256, 0, stream>>>(kb, vb, part);
  ctx_reduce<<<dim3(32, 3), 256, 0, stream>>>(part, ctxTb);
  q_mega<<<dim3(M1_/128, C_/128), 256, 0, stream>>>(xb, wqb, bq, ctxTb, ksum, omid);
  gemm_bt<<<dim3(M1_/128, C_/128), 256, 0, stream>>>(omid, wob, bo, (float*)d_out, M1_, C_, C_);
}

// Round 3
// 222.074 us; speedup vs baseline: 1.7563x; 1.7563x over previous
//
#include <hip/hip_runtime.h>
#include <stdint.h>

#define B_ 4
#define T1_ 4096
#define T2_ 2048
#define C_ 512
#define H_ 8
#define D_ 64
#define M1_ (B_*T1_)   // 16384
#define M2_ (B_*T2_)   // 8192

using f32x4 = __attribute__((ext_vector_type(4))) float;
using bf16x8 = __attribute__((ext_vector_type(8))) __bf16;
using us8 = __attribute__((ext_vector_type(8))) unsigned short;
using us4 = __attribute__((ext_vector_type(4))) unsigned short;

__device__ __forceinline__ unsigned short f2bf(float f){
  unsigned int u = __builtin_bit_cast(unsigned int, f);
  unsigned int r = (u + 0x7fffu + ((u >> 16) & 1u)) >> 16;
  return (unsigned short)r;
}
__device__ __forceinline__ float bf2f(unsigned short u){
  return __builtin_bit_cast(float, ((unsigned int)u) << 16);
}
__device__ __forceinline__ f32x4 mfma16(us8 a, us8 b, f32x4 c){
  return __builtin_amdgcn_mfma_f32_16x16x32_bf16(
      __builtin_bit_cast(bf16x8, a), __builtin_bit_cast(bf16x8, b), c, 0, 0, 0);
}

typedef const __attribute__((address_space(1))) unsigned int gu32;
typedef __attribute__((address_space(3))) unsigned int lu32;
__device__ __forceinline__ void gl_lds16(const void* g, void* l){
  __builtin_amdgcn_global_load_lds((gu32*)g, (lu32*)l, 16, 0, 0);
}

// ---------------- fp32 -> bf16 convert ----------------
__global__ __launch_bounds__(256) void cvt_bf16(const float* __restrict__ in,
                                                unsigned short* __restrict__ out, int n4){
  int i = blockIdx.x * 256 + threadIdx.x;
  if (i >= n4) return;
  f32x4 v = ((const f32x4*)in)[i];
  us4 o;
  #pragma unroll
  for (int j = 0; j < 4; ++j) o[j] = f2bf(v[j]);
  ((us4*)out)[i] = o;
}

// ---------- C-layout fp32 vals -> swizzled bf16 LDS tile -> coalesced store ----------
__device__ __forceinline__ void tile_write(unsigned short* tile, const f32x4 (&vals)[4][4],
                                           int wr, int wc, int lr, int lk){
  #pragma unroll
  for (int mt = 0; mt < 4; ++mt)
    #pragma unroll
    for (int nt = 0; nt < 4; ++nt)
      #pragma unroll
      for (int r = 0; r < 4; ++r){
        int row = wr*64 + mt*16 + lk*4 + r;
        int cb  = (wc*128 + nt*32 + lr*2) ^ ((row & 7) << 4);
        *(unsigned short*)((char*)tile + row*256 + cb) = f2bf(vals[mt][nt][r]);
      }
}
__device__ __forceinline__ void tile_flush(const unsigned short* tile, unsigned short* g,
                                           size_t row0, int col0, int ldg, int t){
  #pragma unroll
  for (int p = 0; p < 8; ++p){
    int row = p*16 + (t >> 4);
    int cb  = ((t & 15) * 16) ^ ((row & 7) << 4);
    us8 v = *(const us8*)((const char*)tile + row*256 + cb);
    *(us8*)(g + (row0 + row) * (size_t)ldg + col0 + (t & 15) * 8) = v;
  }
}

// ---------------- plain GEMM: out(fp32) = A[M,K] @ Bw[N,K]^T + bias ----------------
__global__ __launch_bounds__(256) void gemm_bt(const unsigned short* __restrict__ A,
                                               const unsigned short* __restrict__ Bw,
                                               const float* __restrict__ bias,
                                               float* __restrict__ out, int M, int N, int Kd){
  __shared__ unsigned short ldsA[128*32];
  __shared__ unsigned short ldsB[128*32];
  const int m0 = blockIdx.x * 128, n0 = blockIdx.y * 128;
  const int t = threadIdx.x;
  const int w = t >> 6, l = t & 63;
  const int wr = w >> 1, wc = w & 1;
  const int lr = l & 15, lk = l >> 4;
  f32x4 acc[4][4] = {};
  for (int k0 = 0; k0 < Kd; k0 += 32){
    {
      int c = t, row = c >> 2, off = (c & 3) * 8;
      gl_lds16(A  + (size_t)(m0+row)*Kd + k0 + off, &ldsA[c*8]);
      gl_lds16(Bw + (size_t)(n0+row)*Kd + k0 + off, &ldsB[c*8]);
      c = t + 256; row = c >> 2; off = (c & 3) * 8;
      gl_lds16(A  + (size_t)(m0+row)*Kd + k0 + off, &ldsA[c*8]);
      gl_lds16(Bw + (size_t)(n0+row)*Kd + k0 + off, &ldsB[c*8]);
    }
    __syncthreads();
    us8 af[4], bfr[4];
    #pragma unroll
    for (int mt = 0; mt < 4; ++mt)
      af[mt] = *(const us8*)&ldsA[(wr*64 + mt*16 + lr)*32 + lk*8];
    #pragma unroll
    for (int nt = 0; nt < 4; ++nt)
      bfr[nt] = *(const us8*)&ldsB[(wc*64 + nt*16 + lr)*32 + lk*8];
    #pragma unroll
    for (int mt = 0; mt < 4; ++mt)
      #pragma unroll
      for (int nt = 0; nt < 4; ++nt)
        acc[mt][nt] = mfma16(af[mt], bfr[nt], acc[mt][nt]);
    __syncthreads();
  }
  #pragma unroll
  for (int mt = 0; mt < 4; ++mt)
    #pragma unroll
    for (int nt = 0; nt < 4; ++nt)
      #pragma unroll
      for (int r = 0; r < 4; ++r){
        int row = m0 + wr*64 + mt*16 + lk*4 + r;
        int col = n0 + wc*64 + nt*16 + lr;
        out[(size_t)row*N + col] = acc[mt][nt][r] + bias[col];
      }
}

// ---------------- fused K+V projection: softmax(K), colsum atomics, bf16 stores ----------------
__global__ __launch_bounds__(256) void kv_fused(const unsigned short* __restrict__ yball,
                                                const unsigned short* __restrict__ wkb,
                                                const unsigned short* __restrict__ wvb,
                                                const float* __restrict__ bk,
                                                const float* __restrict__ bv,
                                                unsigned short* __restrict__ kb,
                                                unsigned short* __restrict__ vb,
                                                float* __restrict__ ksum){
  __shared__ unsigned short smem[16384];       // 32 KB: staging 24 KB, then repack tile 32 KB
  unsigned short* sA = smem;
  unsigned short* sK = smem + 4096;
  unsigned short* sV = smem + 8192;
  const int i = blockIdx.z;
  const int m0 = blockIdx.x * 128, n0 = blockIdx.y * 128;
  const unsigned short* A  = yball + (size_t)i*M2_*C_;
  const unsigned short* Wk = wkb  + (size_t)i*C_*C_;
  const unsigned short* Wv = wvb  + (size_t)i*C_*C_;
  const int t = threadIdx.x;
  const int w = t >> 6, l = t & 63;
  const int wr = w >> 1, wc = w & 1;
  const int lr = l & 15, lk = l >> 4;
  f32x4 aK[4][4] = {}, aV[4][4] = {};
  for (int k0 = 0; k0 < C_; k0 += 32){
    {
      int c = t, row = c >> 2, off = (c & 3) * 8;
      gl_lds16(A  + (size_t)(m0+row)*C_ + k0 + off, &sA[c*8]);
      gl_lds16(Wk + (size_t)(n0+row)*C_ + k0 + off, &sK[c*8]);
      gl_lds16(Wv + (size_t)(n0+row)*C_ + k0 + off, &sV[c*8]);
      c = t + 256; row = c >> 2; off = (c & 3) * 8;
      gl_lds16(A  + (size_t)(m0+row)*C_ + k0 + off, &sA[c*8]);
      gl_lds16(Wk + (size_t)(n0+row)*C_ + k0 + off, &sK[c*8]);
      gl_lds16(Wv + (size_t)(n0+row)*C_ + k0 + off, &sV[c*8]);
    }
    __syncthreads();
    us8 af[4];
    #pragma unroll
    for (int mt = 0; mt < 4; ++mt)
      af[mt] = *(const us8*)&sA[(wr*64 + mt*16 + lr)*32 + lk*8];
    {
      us8 bf_[4];
      #pragma unroll
      for (int nt = 0; nt < 4; ++nt)
        bf_[nt] = *(const us8*)&sK[(wc*64 + nt*16 + lr)*32 + lk*8];
      #pragma unroll
      for (int mt = 0; mt < 4; ++mt)
        #pragma unroll
        for (int nt = 0; nt < 4; ++nt)
          aK[mt][nt] = mfma16(af[mt], bf_[nt], aK[mt][nt]);
    }
    {
      us8 bf_[4];
      #pragma unroll
      for (int nt = 0; nt < 4; ++nt)
        bf_[nt] = *(const us8*)&sV[(wc*64 + nt*16 + lr)*32 + lk*8];
      #pragma unroll
      for (int mt = 0; mt < 4; ++mt)
        #pragma unroll
        for (int nt = 0; nt < 4; ++nt)
          aV[mt][nt] = mfma16(af[mt], bf_[nt], aV[mt][nt]);
    }
    __syncthreads();
  }
  // bias
  float bKc[4], bVc[4];
  #pragma unroll
  for (int nt = 0; nt < 4; ++nt){
    int col = n0 + wc*64 + nt*16 + lr;
    bKc[nt] = bk[(size_t)i*C_ + col];
    bVc[nt] = bv[(size_t)i*C_ + col];
  }
  #pragma unroll
  for (int mt = 0; mt < 4; ++mt)
    #pragma unroll
    for (int nt = 0; nt < 4; ++nt)
      #pragma unroll
      for (int r = 0; r < 4; ++r){
        aK[mt][nt][r] += bKc[nt];
        aV[mt][nt][r] += bVc[nt];
      }
  // in-register softmax over the wave's 64-col head group (lanes share lk)
  #pragma unroll
  for (int mt = 0; mt < 4; ++mt)
    #pragma unroll
    for (int r = 0; r < 4; ++r){
      float m = fmaxf(fmaxf(aK[mt][0][r], aK[mt][1][r]), fmaxf(aK[mt][2][r], aK[mt][3][r]));
      #pragma unroll
      for (int s = 1; s < 16; s <<= 1) m = fmaxf(m, __shfl_xor(m, s, 64));
      float sum = 0.f;
      #pragma unroll
      for (int nt = 0; nt < 4; ++nt){
        float e = __expf(aK[mt][nt][r] - m);
        aK[mt][nt][r] = e; sum += e;
      }
      #pragma unroll
      for (int s = 1; s < 16; s <<= 1) sum += __shfl_xor(sum, s, 64);
      float inv = 1.0f / sum;
      #pragma unroll
      for (int nt = 0; nt < 4; ++nt) aK[mt][nt][r] *= inv;
    }
  // colsum -> ksum atomics (sum across mt,r then across lk groups)
  {
    const int b = m0 / T2_;
    #pragma unroll
    for (int nt = 0; nt < 4; ++nt){
      float cs = 0.f;
      #pragma unroll
      for (int mt = 0; mt < 4; ++mt)
        #pragma unroll
        for (int r = 0; r < 4; ++r) cs += aK[mt][nt][r];
      cs += __shfl_xor(cs, 16, 64);
      cs += __shfl_xor(cs, 32, 64);
      if (lk == 0)
        atomicAdd(&ksum[((size_t)i*B_ + b)*C_ + n0 + wc*64 + nt*16 + lr], cs);
    }
  }
  // repack + store K then V
  tile_write(smem, aK, wr, wc, lr, lk);
  __syncthreads();
  tile_flush(smem, kb + (size_t)i*M2_*C_, m0, n0, C_, t);
  __syncthreads();
  tile_write(smem, aV, wr, wc, lr, lk);
  __syncthreads();
  tile_flush(smem, vb + (size_t)i*M2_*C_, m0, n0, C_, t);
}

// ---------------- context partials: part[i][ch][bh][e*64+d] = sum_n k[n,d] v[n,e] ----------------
__global__ __launch_bounds__(256) void ctx_partial(const unsigned short* __restrict__ kb,
                                                   const unsigned short* __restrict__ vb,
                                                   float* __restrict__ part){
  __shared__ unsigned short lk_[16384];
  __shared__ unsigned short lv_[16384];
  const int bh = blockIdx.x, ch = blockIdx.y, i = blockIdx.z;
  const int b = bh >> 3, h = bh & 7;
  const int t = threadIdx.x;
  const unsigned short* kbi = kb + (size_t)i*M2_*C_;
  const unsigned short* vbi = vb + (size_t)i*M2_*C_;
  size_t rowbase = (size_t)(b*T2_ + ch*256);
  #pragma unroll
  for (int it = 0; it < 8; ++it){
    int c = t + it*256;
    int row = c >> 3, off = (c & 7) * 8;
    gl_lds16(kbi + (rowbase + row)*C_ + h*D_ + off, &lk_[c*8]);
    gl_lds16(vbi + (rowbase + row)*C_ + h*D_ + off, &lv_[c*8]);
  }
  __syncthreads();
  int d0 = (t & 15) * 4, e0 = (t >> 4) * 4;
  float acc[4][4] = {};
  for (int n = 0; n < 256; ++n){
    us4 kq = *(const us4*)&lk_[n*64 + d0];
    us4 vq = *(const us4*)&lv_[n*64 + e0];
    float kf[4], vf[4];
    #pragma unroll
    for (int j = 0; j < 4; ++j){ kf[j] = bf2f(kq[j]); vf[j] = bf2f(vq[j]); }
    #pragma unroll
    for (int jd = 0; jd < 4; ++jd)
      #pragma unroll
      for (int je = 0; je < 4; ++je)
        acc[jd][je] += kf[jd] * vf[je];
  }
  float* dst = part + (((size_t)i*8 + ch)*32 + bh) * 4096;
  #pragma unroll
  for (int jd = 0; jd < 4; ++jd)
    #pragma unroll
    for (int je = 0; je < 4; ++je)
      dst[(e0+je)*64 + (d0+jd)] = acc[jd][je];
}

__global__ __launch_bounds__(256) void ctx_reduce(const float* __restrict__ part,
                                                  unsigned short* __restrict__ ctxTb){
  const int bh = blockIdx.x, i = blockIdx.y, t = threadIdx.x;
  for (int idx = t; idx < 4096; idx += 256){
    float s = 0.f;
    #pragma unroll
    for (int ch = 0; ch < 8; ++ch)
      s += part[(((size_t)i*8 + ch)*32 + bh)*4096 + idx];
    ctxTb[((size_t)i*32 + bh)*4096 + idx] = f2bf(s);
  }
}

// ---------------- fused Q: GEMM + softmax + (den, q@ctx, fold) -> omid ----------------
__global__ __launch_bounds__(256) void q_mega(const unsigned short* __restrict__ xb,
                                              const unsigned short* __restrict__ wqb,
                                              const float* __restrict__ bq,
                                              const unsigned short* __restrict__ ctxTb,
                                              const float* __restrict__ ksum,
                                              unsigned short* __restrict__ omid){
  __shared__ unsigned short smem[16384];       // staging 16 KB, then q/omid tile 32 KB
  unsigned short* sA = smem;
  unsigned short* sB = smem + 4096;
  const int m0 = blockIdx.x * 128, n0 = blockIdx.y * 128;
  const int t = threadIdx.x;
  const int w = t >> 6, l = t & 63;
  const int wr = w >> 1, wc = w & 1;
  const int lr = l & 15, lk = l >> 4;
  f32x4 acc[4][4] = {};
  for (int k0 = 0; k0 < C_; k0 += 32){
    {
      int c = t, row = c >> 2, off = (c & 3) * 8;
      gl_lds16(xb  + (size_t)(m0+row)*C_ + k0 + off, &sA[c*8]);
      gl_lds16(wqb + (size_t)(n0+row)*C_ + k0 + off, &sB[c*8]);
      c = t + 256; row = c >> 2; off = (c & 3) * 8;
      gl_lds16(xb  + (size_t)(m0+row)*C_ + k0 + off, &sA[c*8]);
      gl_lds16(wqb + (size_t)(n0+row)*C_ + k0 + off, &sB[c*8]);
    }
    __syncthreads();
    us8 af[4], bfr[4];
    #pragma unroll
    for (int mt = 0; mt < 4; ++mt)
      af[mt] = *(const us8*)&sA[(wr*64 + mt*16 + lr)*32 + lk*8];
    #pragma unroll
    for (int nt = 0; nt < 4; ++nt)
      bfr[nt] = *(const us8*)&sB[(wc*64 + nt*16 + lr)*32 + lk*8];
    #pragma unroll
    for (int mt = 0; mt < 4; ++mt)
      #pragma unroll
      for (int nt = 0; nt < 4; ++nt)
        acc[mt][nt] = mfma16(af[mt], bfr[nt], acc[mt][nt]);
    __syncthreads();
  }
  // bias + softmax
  {
    float bc[4];
    #pragma unroll
    for (int nt = 0; nt < 4; ++nt) bc[nt] = bq[n0 + wc*64 + nt*16 + lr];
    #pragma unroll
    for (int mt = 0; mt < 4; ++mt)
      #pragma unroll
      for (int r = 0; r < 4; ++r){
        #pragma unroll
        for (int nt = 0; nt < 4; ++nt) acc[mt][nt][r] += bc[nt];
        float m = fmaxf(fmaxf(acc[mt][0][r], acc[mt][1][r]), fmaxf(acc[mt][2][r], acc[mt][3][r]));
        #pragma unroll
        for (int s = 1; s < 16; s <<= 1) m = fmaxf(m, __shfl_xor(m, s, 64));
        float sum = 0.f;
        #pragma unroll
        for (int nt = 0; nt < 4; ++nt){
          float e = __expf(acc[mt][nt][r] - m);
          acc[mt][nt][r] = e; sum += e;
        }
        #pragma unroll
        for (int s = 1; s < 16; s <<= 1) sum += __shfl_xor(sum, s, 64);
        float inv = 1.0f / sum;
        #pragma unroll
        for (int nt = 0; nt < 4; ++nt) acc[mt][nt][r] *= inv;
      }
  }
  const int b = m0 / T1_;
  const int bh = b*8 + (n0 >> 6) + wc;
  // q -> swizzled tile, then A-frags
  tile_write(smem, acc, wr, wc, lr, lk);
  __syncthreads();
  us8 afr[4][2];
  #pragma unroll
  for (int mt = 0; mt < 4; ++mt)
    #pragma unroll
    for (int kk = 0; kk < 2; ++kk){
      int row = wr*64 + mt*16 + lr;
      int cb = (wc*128 + kk*64 + lk*16) ^ ((row & 7) << 4);
      afr[mt][kk] = *(const us8*)((char*)smem + row*256 + cb);
    }
  // denominator MFMA: B rows 0..2 = ksum_i over this head's 64 channels
  us8 bden[2];
  #pragma unroll
  for (int kk = 0; kk < 2; ++kk){
    us8 tmp = {};
    if (lr < 3){
      const float* kp = ksum + ((size_t)lr*B_ + b)*C_ + n0 + wc*64 + kk*32 + lk*8;
      f32x4 c0 = *(const f32x4*)kp;
      f32x4 c1 = *(const f32x4*)(kp + 4);
      #pragma unroll
      for (int j = 0; j < 4; ++j){ tmp[j] = f2bf(c0[j]); tmp[4+j] = f2bf(c1[j]); }
    }
    bden[kk] = tmp;
  }
  f32x4 den[4] = {};
  #pragma unroll
  for (int mt = 0; mt < 4; ++mt)
    #pragma unroll
    for (int kk = 0; kk < 2; ++kk)
      den[mt] = mfma16(afr[mt][kk], bden[kk], den[mt]);
  // per-i: q@ctxT_i, fold with Dinv  (ALL inner loops fully unrolled -> static acc indexing)
  #pragma unroll 1
  for (int i = 0; i < 3; ++i){
    f32x4 dinv[4];
    #pragma unroll
    for (int mt = 0; mt < 4; ++mt)
      #pragma unroll
      for (int r = 0; r < 4; ++r)
        dinv[mt][r] = 1.0f / (__shfl(den[mt][r], (l & 48) | i, 64) + 1e-8f);
    #pragma unroll
    for (int nt = 0; nt < 4; ++nt){
      us8 bfr[2];
      #pragma unroll
      for (int kk = 0; kk < 2; ++kk)
        bfr[kk] = *(const us8*)(ctxTb + ((size_t)(i*32 + bh))*4096 + (nt*16 + lr)*64 + kk*32 + lk*8);
      f32x4 p[4] = {};
      #pragma unroll
      for (int mt = 0; mt < 4; ++mt)
        #pragma unroll
        for (int kk = 0; kk < 2; ++kk)
          p[mt] = mfma16(afr[mt][kk], bfr[kk], p[mt]);
      #pragma unroll
      for (int mt = 0; mt < 4; ++mt)
        #pragma unroll
        for (int r = 0; r < 4; ++r)
          acc[mt][nt][r] += p[mt][r] * dinv[mt][r];
    }
  }
  __syncthreads();   // all A-frag reads complete before tile reuse
  tile_write(smem, acc, wr, wc, lr, lk);
  __syncthreads();
  tile_flush(smem, omid, m0, n0, C_, t);
}

extern "C" void kernel_launch(void* const* d_in, const int* in_sizes, int n_in,
                              void* d_out, int out_size, void* d_ws, size_t ws_size,
                              hipStream_t stream){
  const float* x  = (const float*)d_in[0];
  const float* y0 = (const float*)d_in[1];
  const float* y1 = (const float*)d_in[2];
  const float* y2 = (const float*)d_in[3];
  const float* Wq = (const float*)d_in[4];
  const float* bq = (const float*)d_in[5];
  const float* Wk = (const float*)d_in[6];
  const float* bk = (const float*)d_in[7];
  const float* Wv = (const float*)d_in[8];
  const float* bv = (const float*)d_in[9];
  const float* Wo = (const float*)d_in[10];
  const float* bo = (const float*)d_in[11];

  char* ws = (char*)d_ws;
  size_t off = 0;
  auto alloc = [&](size_t bytes)->char*{
    char* p = ws + off; off += (bytes + 1023) & ~((size_t)1023); return p;
  };
  unsigned short* xb    = (unsigned short*)alloc((size_t)M1_*C_*2);
  unsigned short* yball = (unsigned short*)alloc((size_t)3*M2_*C_*2);
  unsigned short* wqb   = (unsigned short*)alloc((size_t)C_*C_*2);
  unsigned short* wkb   = (unsigned short*)alloc((size_t)3*C_*C_*2);
  unsigned short* wvb   = (unsigned short*)alloc((size_t)3*C_*C_*2);
  unsigned short* wob   = (unsigned short*)alloc((size_t)C_*C_*2);
  unsigned short* kb    = (unsigned short*)alloc((size_t)3*M2_*C_*2);
  unsigned short* vb    = (unsigned short*)alloc((size_t)3*M2_*C_*2);
  float*          ksum  = (float*)alloc((size_t)3*B_*C_*4);
  float*          part  = (float*)alloc((size_t)3*8*32*4096*4);
  unsigned short* ctxTb = (unsigned short*)alloc((size_t)3*32*4096*2);
  unsigned short* omid  = (unsigned short*)alloc((size_t)M1_*C_*2);

  hipMemsetAsync(ksum, 0, (size_t)3*B_*C_*4, stream);

  cvt_bf16<<<M1_*C_/4/256, 256, 0, stream>>>(x, xb, M1_*C_/4);
  cvt_bf16<<<M2_*C_/4/256, 256, 0, stream>>>(y0, yball, M2_*C_/4);
  cvt_bf16<<<M2_*C_/4/256, 256, 0, stream>>>(y1, yball + (size_t)M2_*C_, M2_*C_/4);
  cvt_bf16<<<M2_*C_/4/256, 256, 0, stream>>>(y2, yball + (size_t)2*M2_*C_, M2_*C_/4);
  cvt_bf16<<<C_*C_/4/256, 256, 0, stream>>>(Wq, wqb, C_*C_/4);
  cvt_bf16<<<3*C_*C_/4/256, 256, 0, stream>>>(Wk, wkb, 3*C_*C_/4);
  cvt_bf16<<<3*C_*C_/4/256, 256, 0, stream>>>(Wv, wvb, 3*C_*C_/4);
  cvt_bf16<<<C_*C_/4/256, 256, 0, stream>>>(Wo, wob, C_*C_/4);

  kv_fused<<<dim3(M2_/128, C_/128, 3), 256, 0, stream>>>(yball, wkb, wvb, bk, bv, kb, vb, ksum);
  ctx_partial<<<dim3(32, 8, 3), 256, 0, stream>>>(kb, vb, part);
  ctx_reduce<<<dim3(32, 3), 256, 0, stream>>>(part, ctxTb);
  q_mega<<<dim3(M1_/128, C_/128), 256, 0, stream>>>(xb, wqb, bq, ctxTb, ksum, omid);
  gemm_bt<<<dim3(M1_/128, C_/128), 256, 0, stream>>>(omid, wob, bo, (float*)d_out, M1_, C_, C_);
}

// Round 4
// 194.046 us; speedup vs baseline: 2.0100x; 1.1444x over previous
//
#include <hip/hip_runtime.h>
#include <stdint.h>

#define B_ 4
#define T1_ 4096
#define T2_ 2048
#define C_ 512
#define H_ 8
#define D_ 64
#define M1_ (B_*T1_)   // 16384
#define M2_ (B_*T2_)   // 8192

using f32x4 = __attribute__((ext_vector_type(4))) float;
using bf16x8 = __attribute__((ext_vector_type(8))) __bf16;
using us8 = __attribute__((ext_vector_type(8))) unsigned short;
using us4 = __attribute__((ext_vector_type(4))) unsigned short;

__device__ __forceinline__ unsigned short f2bf(float f){
  unsigned int u = __builtin_bit_cast(unsigned int, f);
  unsigned int r = (u + 0x7fffu + ((u >> 16) & 1u)) >> 16;
  return (unsigned short)r;
}
__device__ __forceinline__ float bf2f(unsigned short u){
  return __builtin_bit_cast(float, ((unsigned int)u) << 16);
}
__device__ __forceinline__ f32x4 mfma16(us8 a, us8 b, f32x4 c){
  return __builtin_amdgcn_mfma_f32_16x16x32_bf16(
      __builtin_bit_cast(bf16x8, a), __builtin_bit_cast(bf16x8, b), c, 0, 0, 0);
}

typedef const __attribute__((address_space(1))) unsigned int gu32;
typedef __attribute__((address_space(3))) unsigned int lu32;
__device__ __forceinline__ void gl_lds16(const void* g, void* l){
  __builtin_amdgcn_global_load_lds((gu32*)g, (lu32*)l, 16, 0, 0);
}

// ---------------- fused fp32 -> bf16 convert (4 sources per launch) ----------------
__global__ __launch_bounds__(256) void cvt_bf16_4(const float* __restrict__ p0, const float* __restrict__ p1,
                                                  const float* __restrict__ p2, const float* __restrict__ p3,
                                                  unsigned short* o0, unsigned short* o1,
                                                  unsigned short* o2, unsigned short* o3,
                                                  int n0, int n1, int n2, int n3){
  const float* in; unsigned short* out; int n4;
  switch (blockIdx.y){
    case 0: in = p0; out = o0; n4 = n0; break;
    case 1: in = p1; out = o1; n4 = n1; break;
    case 2: in = p2; out = o2; n4 = n2; break;
    default: in = p3; out = o3; n4 = n3; break;
  }
  int i = blockIdx.x * 256 + threadIdx.x;
  if (i >= n4) return;
  f32x4 v = ((const f32x4*)in)[i];
  us4 o;
  #pragma unroll
  for (int j = 0; j < 4; ++j) o[j] = f2bf(v[j]);
  ((us4*)out)[i] = o;
}

// ---------- C-layout fp32 vals -> swizzled bf16 LDS tile -> coalesced store ----------
__device__ __forceinline__ void tile_write(unsigned short* tile, const f32x4 (&vals)[4][4],
                                           int wr, int wc, int lr, int lk){
  #pragma unroll
  for (int mt = 0; mt < 4; ++mt)
    #pragma unroll
    for (int nt = 0; nt < 4; ++nt)
      #pragma unroll
      for (int r = 0; r < 4; ++r){
        int row = wr*64 + mt*16 + lk*4 + r;
        int cb  = (wc*128 + nt*32 + lr*2) ^ ((row & 7) << 4);
        *(unsigned short*)((char*)tile + row*256 + cb) = f2bf(vals[mt][nt][r]);
      }
}
__device__ __forceinline__ void tile_flush(const unsigned short* tile, unsigned short* g,
                                           size_t row0, int col0, int ldg, int t){
  #pragma unroll
  for (int p = 0; p < 8; ++p){
    int row = p*16 + (t >> 4);
    int cb  = ((t & 15) * 16) ^ ((row & 7) << 4);
    us8 v = *(const us8*)((const char*)tile + row*256 + cb);
    *(us8*)(g + (row0 + row) * (size_t)ldg + col0 + (t & 15) * 8) = v;
  }
}

// ---------------- plain GEMM (2-phase dbuf): out(fp32) = A @ Bw^T + bias ----------------
__global__ __launch_bounds__(256) void gemm_bt(const unsigned short* __restrict__ A,
                                               const unsigned short* __restrict__ Bw,
                                               const float* __restrict__ bias,
                                               float* __restrict__ out, int M, int N, int Kd){
  __shared__ unsigned short smem[2*2*4096];    // [buf][A/B][4096] = 32 KB
  const int m0 = blockIdx.x * 128, n0 = blockIdx.y * 128;
  const int t = threadIdx.x;
  const int w = t >> 6, l = t & 63;
  const int wr = w >> 1, wc = w & 1;
  const int lr = l & 15, lk = l >> 4;
  f32x4 acc[4][4] = {};
  auto STAGE = [&](int bb, int k0){
    int c = t, row = c >> 2, off = (c & 3) * 8;
    gl_lds16(A  + (size_t)(m0+row)*Kd + k0 + off, &smem[bb*8192 + c*8]);
    gl_lds16(Bw + (size_t)(n0+row)*Kd + k0 + off, &smem[bb*8192 + 4096 + c*8]);
    c = t + 256; row = c >> 2; off = (c & 3) * 8;
    gl_lds16(A  + (size_t)(m0+row)*Kd + k0 + off, &smem[bb*8192 + c*8]);
    gl_lds16(Bw + (size_t)(n0+row)*Kd + k0 + off, &smem[bb*8192 + 4096 + c*8]);
  };
  STAGE(0, 0);
  __syncthreads();
  for (int k0 = 0; k0 < Kd; k0 += 32){
    const int cur = (k0 >> 5) & 1;
    if (k0 + 32 < Kd) STAGE(cur ^ 1, k0 + 32);
    const unsigned short* sA = &smem[cur*8192];
    const unsigned short* sB = &smem[cur*8192 + 4096];
    us8 af[4], bfr[4];
    #pragma unroll
    for (int mt = 0; mt < 4; ++mt)
      af[mt] = *(const us8*)&sA[(wr*64 + mt*16 + lr)*32 + lk*8];
    #pragma unroll
    for (int nt = 0; nt < 4; ++nt)
      bfr[nt] = *(const us8*)&sB[(wc*64 + nt*16 + lr)*32 + lk*8];
    #pragma unroll
    for (int mt = 0; mt < 4; ++mt)
      #pragma unroll
      for (int nt = 0; nt < 4; ++nt)
        acc[mt][nt] = mfma16(af[mt], bfr[nt], acc[mt][nt]);
    __syncthreads();
  }
  #pragma unroll
  for (int mt = 0; mt < 4; ++mt)
    #pragma unroll
    for (int nt = 0; nt < 4; ++nt)
      #pragma unroll
      for (int r = 0; r < 4; ++r){
        int row = m0 + wr*64 + mt*16 + lk*4 + r;
        int col = n0 + wc*64 + nt*16 + lr;
        out[(size_t)row*N + col] = acc[mt][nt][r] + bias[col];
      }
}

// ---------------- fused K+V projection (2-phase dbuf) ----------------
__global__ __launch_bounds__(256) void kv_fused(const unsigned short* __restrict__ yball,
                                                const unsigned short* __restrict__ wkb,
                                                const unsigned short* __restrict__ wvb,
                                                const float* __restrict__ bk,
                                                const float* __restrict__ bv,
                                                unsigned short* __restrict__ kb,
                                                unsigned short* __restrict__ vb,
                                                float* __restrict__ ksum){
  __shared__ unsigned short smem[2*3*4096];    // [buf][A/K/V][4096] = 48 KB; repack tile aliases
  const int i = blockIdx.z;
  const int m0 = blockIdx.x * 128, n0 = blockIdx.y * 128;
  const unsigned short* A  = yball + (size_t)i*M2_*C_;
  const unsigned short* Wk = wkb  + (size_t)i*C_*C_;
  const unsigned short* Wv = wvb  + (size_t)i*C_*C_;
  const int t = threadIdx.x;
  const int w = t >> 6, l = t & 63;
  const int wr = w >> 1, wc = w & 1;
  const int lr = l & 15, lk = l >> 4;
  f32x4 aK[4][4] = {}, aV[4][4] = {};
  auto STAGE = [&](int bb, int k0){
    int c = t, row = c >> 2, off = (c & 3) * 8;
    gl_lds16(A  + (size_t)(m0+row)*C_ + k0 + off, &smem[bb*12288 + c*8]);
    gl_lds16(Wk + (size_t)(n0+row)*C_ + k0 + off, &smem[bb*12288 + 4096 + c*8]);
    gl_lds16(Wv + (size_t)(n0+row)*C_ + k0 + off, &smem[bb*12288 + 8192 + c*8]);
    c = t + 256; row = c >> 2; off = (c & 3) * 8;
    gl_lds16(A  + (size_t)(m0+row)*C_ + k0 + off, &smem[bb*12288 + c*8]);
    gl_lds16(Wk + (size_t)(n0+row)*C_ + k0 + off, &smem[bb*12288 + 4096 + c*8]);
    gl_lds16(Wv + (size_t)(n0+row)*C_ + k0 + off, &smem[bb*12288 + 8192 + c*8]);
  };
  STAGE(0, 0);
  __syncthreads();
  for (int k0 = 0; k0 < C_; k0 += 32){
    const int cur = (k0 >> 5) & 1;
    if (k0 + 32 < C_) STAGE(cur ^ 1, k0 + 32);
    const unsigned short* sA = &smem[cur*12288];
    const unsigned short* sK = &smem[cur*12288 + 4096];
    const unsigned short* sV = &smem[cur*12288 + 8192];
    us8 af[4];
    #pragma unroll
    for (int mt = 0; mt < 4; ++mt)
      af[mt] = *(const us8*)&sA[(wr*64 + mt*16 + lr)*32 + lk*8];
    {
      us8 bf_[4];
      #pragma unroll
      for (int nt = 0; nt < 4; ++nt)
        bf_[nt] = *(const us8*)&sK[(wc*64 + nt*16 + lr)*32 + lk*8];
      #pragma unroll
      for (int mt = 0; mt < 4; ++mt)
        #pragma unroll
        for (int nt = 0; nt < 4; ++nt)
          aK[mt][nt] = mfma16(af[mt], bf_[nt], aK[mt][nt]);
    }
    {
      us8 bf_[4];
      #pragma unroll
      for (int nt = 0; nt < 4; ++nt)
        bf_[nt] = *(const us8*)&sV[(wc*64 + nt*16 + lr)*32 + lk*8];
      #pragma unroll
      for (int mt = 0; mt < 4; ++mt)
        #pragma unroll
        for (int nt = 0; nt < 4; ++nt)
          aV[mt][nt] = mfma16(af[mt], bf_[nt], aV[mt][nt]);
    }
    __syncthreads();
  }
  // bias
  float bKc[4], bVc[4];
  #pragma unroll
  for (int nt = 0; nt < 4; ++nt){
    int col = n0 + wc*64 + nt*16 + lr;
    bKc[nt] = bk[(size_t)i*C_ + col];
    bVc[nt] = bv[(size_t)i*C_ + col];
  }
  #pragma unroll
  for (int mt = 0; mt < 4; ++mt)
    #pragma unroll
    for (int nt = 0; nt < 4; ++nt)
      #pragma unroll
      for (int r = 0; r < 4; ++r){
        aK[mt][nt][r] += bKc[nt];
        aV[mt][nt][r] += bVc[nt];
      }
  // in-register softmax over the wave's 64-col head group (lanes share lk)
  #pragma unroll
  for (int mt = 0; mt < 4; ++mt)
    #pragma unroll
    for (int r = 0; r < 4; ++r){
      float m = fmaxf(fmaxf(aK[mt][0][r], aK[mt][1][r]), fmaxf(aK[mt][2][r], aK[mt][3][r]));
      #pragma unroll
      for (int s = 1; s < 16; s <<= 1) m = fmaxf(m, __shfl_xor(m, s, 64));
      float sum = 0.f;
      #pragma unroll
      for (int nt = 0; nt < 4; ++nt){
        float e = __expf(aK[mt][nt][r] - m);
        aK[mt][nt][r] = e; sum += e;
      }
      #pragma unroll
      for (int s = 1; s < 16; s <<= 1) sum += __shfl_xor(sum, s, 64);
      float inv = 1.0f / sum;
      #pragma unroll
      for (int nt = 0; nt < 4; ++nt) aK[mt][nt][r] *= inv;
    }
  // colsum -> ksum atomics
  {
    const int b = m0 / T2_;
    #pragma unroll
    for (int nt = 0; nt < 4; ++nt){
      float cs = 0.f;
      #pragma unroll
      for (int mt = 0; mt < 4; ++mt)
        #pragma unroll
        for (int r = 0; r < 4; ++r) cs += aK[mt][nt][r];
      cs += __shfl_xor(cs, 16, 64);
      cs += __shfl_xor(cs, 32, 64);
      if (lk == 0)
        atomicAdd(&ksum[((size_t)i*B_ + b)*C_ + n0 + wc*64 + nt*16 + lr], cs);
    }
  }
  // repack + store K then V (tile aliases the staging LDS)
  tile_write(smem, aK, wr, wc, lr, lk);
  __syncthreads();
  tile_flush(smem, kb + (size_t)i*M2_*C_, m0, n0, C_, t);
  __syncthreads();
  tile_write(smem, aV, wr, wc, lr, lk);
  __syncthreads();
  tile_flush(smem, vb + (size_t)i*M2_*C_, m0, n0, C_, t);
}

// ---------------- context partials: part[i][ch][bh][e*64+d] = sum_n k[n,d] v[n,e] ----------------
__global__ __launch_bounds__(256) void ctx_partial(const unsigned short* __restrict__ kb,
                                                   const unsigned short* __restrict__ vb,
                                                   float* __restrict__ part){
  __shared__ unsigned short lk_[16384];
  __shared__ unsigned short lv_[16384];
  const int bh = blockIdx.x, ch = blockIdx.y, i = blockIdx.z;
  const int b = bh >> 3, h = bh & 7;
  const int t = threadIdx.x;
  const unsigned short* kbi = kb + (size_t)i*M2_*C_;
  const unsigned short* vbi = vb + (size_t)i*M2_*C_;
  size_t rowbase = (size_t)(b*T2_ + ch*256);
  #pragma unroll
  for (int it = 0; it < 8; ++it){
    int c = t + it*256;
    int row = c >> 3, off = (c & 7) * 8;
    gl_lds16(kbi + (rowbase + row)*C_ + h*D_ + off, &lk_[c*8]);
    gl_lds16(vbi + (rowbase + row)*C_ + h*D_ + off, &lv_[c*8]);
  }
  __syncthreads();
  int d0 = (t & 15) * 4, e0 = (t >> 4) * 4;
  float acc[4][4] = {};
  for (int n = 0; n < 256; ++n){
    us4 kq = *(const us4*)&lk_[n*64 + d0];
    us4 vq = *(const us4*)&lv_[n*64 + e0];
    float kf[4], vf[4];
    #pragma unroll
    for (int j = 0; j < 4; ++j){ kf[j] = bf2f(kq[j]); vf[j] = bf2f(vq[j]); }
    #pragma unroll
    for (int jd = 0; jd < 4; ++jd)
      #pragma unroll
      for (int je = 0; je < 4; ++je)
        acc[jd][je] += kf[jd] * vf[je];
  }
  float* dst = part + (((size_t)i*8 + ch)*32 + bh) * 4096;
  #pragma unroll
  for (int jd = 0; jd < 4; ++jd)
    #pragma unroll
    for (int je = 0; je < 4; ++je)
      dst[(e0+je)*64 + (d0+jd)] = acc[jd][je];
}

__global__ __launch_bounds__(256) void ctx_reduce(const float* __restrict__ part,
                                                  unsigned short* __restrict__ ctxTb){
  const int bh = blockIdx.x, i = blockIdx.y, t = threadIdx.x;
  for (int idx = t; idx < 4096; idx += 256){
    float s = 0.f;
    #pragma unroll
    for (int ch = 0; ch < 8; ++ch)
      s += part[(((size_t)i*8 + ch)*32 + bh)*4096 + idx];
    ctxTb[((size_t)i*32 + bh)*4096 + idx] = f2bf(s);
  }
}

// ---------------- fused Q (2-phase dbuf): GEMM + softmax + (den, q@ctx, fold) -> omid ----------------
__global__ __launch_bounds__(256) void q_mega(const unsigned short* __restrict__ xb,
                                              const unsigned short* __restrict__ wqb,
                                              const float* __restrict__ bq,
                                              const unsigned short* __restrict__ ctxTb,
                                              const float* __restrict__ ksum,
                                              unsigned short* __restrict__ omid){
  __shared__ unsigned short smem[16384];       // 2-buf staging 32 KB; repack tile aliases (32 KB)
  const int m0 = blockIdx.x * 128, n0 = blockIdx.y * 128;
  const int t = threadIdx.x;
  const int w = t >> 6, l = t & 63;
  const int wr = w >> 1, wc = w & 1;
  const int lr = l & 15, lk = l >> 4;
  f32x4 acc[4][4] = {};
  auto STAGE = [&](int bb, int k0){
    int c = t, row = c >> 2, off = (c & 3) * 8;
    gl_lds16(xb  + (size_t)(m0+row)*C_ + k0 + off, &smem[bb*8192 + c*8]);
    gl_lds16(wqb + (size_t)(n0+row)*C_ + k0 + off, &smem[bb*8192 + 4096 + c*8]);
    c = t + 256; row = c >> 2; off = (c & 3) * 8;
    gl_lds16(xb  + (size_t)(m0+row)*C_ + k0 + off, &smem[bb*8192 + c*8]);
    gl_lds16(wqb + (size_t)(n0+row)*C_ + k0 + off, &smem[bb*8192 + 4096 + c*8]);
  };
  STAGE(0, 0);
  __syncthreads();
  for (int k0 = 0; k0 < C_; k0 += 32){
    const int cur = (k0 >> 5) & 1;
    if (k0 + 32 < C_) STAGE(cur ^ 1, k0 + 32);
    const unsigned short* sA = &smem[cur*8192];
    const unsigned short* sB = &smem[cur*8192 + 4096];
    us8 af[4], bfr[4];
    #pragma unroll
    for (int mt = 0; mt < 4; ++mt)
      af[mt] = *(const us8*)&sA[(wr*64 + mt*16 + lr)*32 + lk*8];
    #pragma unroll
    for (int nt = 0; nt < 4; ++nt)
      bfr[nt] = *(const us8*)&sB[(wc*64 + nt*16 + lr)*32 + lk*8];
    #pragma unroll
    for (int mt = 0; mt < 4; ++mt)
      #pragma unroll
      for (int nt = 0; nt < 4; ++nt)
        acc[mt][nt] = mfma16(af[mt], bfr[nt], acc[mt][nt]);
    __syncthreads();
  }
  // bias + softmax
  {
    float bc[4];
    #pragma unroll
    for (int nt = 0; nt < 4; ++nt) bc[nt] = bq[n0 + wc*64 + nt*16 + lr];
    #pragma unroll
    for (int mt = 0; mt < 4; ++mt)
      #pragma unroll
      for (int r = 0; r < 4; ++r){
        #pragma unroll
        for (int nt = 0; nt < 4; ++nt) acc[mt][nt][r] += bc[nt];
        float m = fmaxf(fmaxf(acc[mt][0][r], acc[mt][1][r]), fmaxf(acc[mt][2][r], acc[mt][3][r]));
        #pragma unroll
        for (int s = 1; s < 16; s <<= 1) m = fmaxf(m, __shfl_xor(m, s, 64));
        float sum = 0.f;
        #pragma unroll
        for (int nt = 0; nt < 4; ++nt){
          float e = __expf(acc[mt][nt][r] - m);
          acc[mt][nt][r] = e; sum += e;
        }
        #pragma unroll
        for (int s = 1; s < 16; s <<= 1) sum += __shfl_xor(sum, s, 64);
        float inv = 1.0f / sum;
        #pragma unroll
        for (int nt = 0; nt < 4; ++nt) acc[mt][nt][r] *= inv;
      }
  }
  const int b = m0 / T1_;
  const int bh = b*8 + (n0 >> 6) + wc;
  // q -> swizzled tile, then A-frags
  tile_write(smem, acc, wr, wc, lr, lk);
  __syncthreads();
  us8 afr[4][2];
  #pragma unroll
  for (int mt = 0; mt < 4; ++mt)
    #pragma unroll
    for (int kk = 0; kk < 2; ++kk){
      int row = wr*64 + mt*16 + lr;
      int cb = (wc*128 + kk*64 + lk*16) ^ ((row & 7) << 4);
      afr[mt][kk] = *(const us8*)((char*)smem + row*256 + cb);
    }
  // denominator MFMA: B rows 0..2 = ksum_i over this head's 64 channels
  us8 bden[2];
  #pragma unroll
  for (int kk = 0; kk < 2; ++kk){
    us8 tmp = {};
    if (lr < 3){
      const float* kp = ksum + ((size_t)lr*B_ + b)*C_ + n0 + wc*64 + kk*32 + lk*8;
      f32x4 c0 = *(const f32x4*)kp;
      f32x4 c1 = *(const f32x4*)(kp + 4);
      #pragma unroll
      for (int j = 0; j < 4; ++j){ tmp[j] = f2bf(c0[j]); tmp[4+j] = f2bf(c1[j]); }
    }
    bden[kk] = tmp;
  }
  f32x4 den[4] = {};
  #pragma unroll
  for (int mt = 0; mt < 4; ++mt)
    #pragma unroll
    for (int kk = 0; kk < 2; ++kk)
      den[mt] = mfma16(afr[mt][kk], bden[kk], den[mt]);
  // per-i: q@ctxT_i, fold with Dinv (all inner loops fully unrolled -> static acc indexing)
  #pragma unroll 1
  for (int i = 0; i < 3; ++i){
    f32x4 dinv[4];
    #pragma unroll
    for (int mt = 0; mt < 4; ++mt)
      #pragma unroll
      for (int r = 0; r < 4; ++r)
        dinv[mt][r] = 1.0f / (__shfl(den[mt][r], (l & 48) | i, 64) + 1e-8f);
    #pragma unroll
    for (int nt = 0; nt < 4; ++nt){
      us8 bfr[2];
      #pragma unroll
      for (int kk = 0; kk < 2; ++kk)
        bfr[kk] = *(const us8*)(ctxTb + ((size_t)(i*32 + bh))*4096 + (nt*16 + lr)*64 + kk*32 + lk*8);
      f32x4 p[4] = {};
      #pragma unroll
      for (int mt = 0; mt < 4; ++mt)
        #pragma unroll
        for (int kk = 0; kk < 2; ++kk)
          p[mt] = mfma16(afr[mt][kk], bfr[kk], p[mt]);
      #pragma unroll
      for (int mt = 0; mt < 4; ++mt)
        #pragma unroll
        for (int r = 0; r < 4; ++r)
          acc[mt][nt][r] += p[mt][r] * dinv[mt][r];
    }
  }
  __syncthreads();   // all A-frag reads complete before tile reuse
  tile_write(smem, acc, wr, wc, lr, lk);
  __syncthreads();
  tile_flush(smem, omid, m0, n0, C_, t);
}

extern "C" void kernel_launch(void* const* d_in, const int* in_sizes, int n_in,
                              void* d_out, int out_size, void* d_ws, size_t ws_size,
                              hipStream_t stream){
  const float* x  = (const float*)d_in[0];
  const float* y0 = (const float*)d_in[1];
  const float* y1 = (const float*)d_in[2];
  const float* y2 = (const float*)d_in[3];
  const float* Wq = (const float*)d_in[4];
  const float* bq = (const float*)d_in[5];
  const float* Wk = (const float*)d_in[6];
  const float* bk = (const float*)d_in[7];
  const float* Wv = (const float*)d_in[8];
  const float* bv = (const float*)d_in[9];
  const float* Wo = (const float*)d_in[10];
  const float* bo = (const float*)d_in[11];

  char* ws = (char*)d_ws;
  size_t off = 0;
  auto alloc = [&](size_t bytes)->char*{
    char* p = ws + off; off += (bytes + 1023) & ~((size_t)1023); return p;
  };
  unsigned short* xb    = (unsigned short*)alloc((size_t)M1_*C_*2);
  unsigned short* yball = (unsigned short*)alloc((size_t)3*M2_*C_*2);
  unsigned short* wqb   = (unsigned short*)alloc((size_t)C_*C_*2);
  unsigned short* wkb   = (unsigned short*)alloc((size_t)3*C_*C_*2);
  unsigned short* wvb   = (unsigned short*)alloc((size_t)3*C_*C_*2);
  unsigned short* wob   = (unsigned short*)alloc((size_t)C_*C_*2);
  unsigned short* kb    = (unsigned short*)alloc((size_t)3*M2_*C_*2);
  unsigned short* vb    = (unsigned short*)alloc((size_t)3*M2_*C_*2);
  float*          ksum  = (float*)alloc((size_t)3*B_*C_*4);
  float*          part  = (float*)alloc((size_t)3*8*32*4096*4);
  unsigned short* ctxTb = (unsigned short*)alloc((size_t)3*32*4096*2);
  unsigned short* omid  = (unsigned short*)alloc((size_t)M1_*C_*2);

  hipMemsetAsync(ksum, 0, (size_t)3*B_*C_*4, stream);

  // activations: x (2097152 f32x4), y0/y1/y2 (1048576 each)
  cvt_bf16_4<<<dim3(M1_*C_/4/256, 4), 256, 0, stream>>>(
      x, y0, y1, y2, xb, yball, yball + (size_t)M2_*C_, yball + (size_t)2*M2_*C_,
      M1_*C_/4, M2_*C_/4, M2_*C_/4, M2_*C_/4);
  // weights: Wq (65536), Wk (196608), Wv (196608), Wo (65536)
  cvt_bf16_4<<<dim3(3*C_*C_/4/256, 4), 256, 0, stream>>>(
      Wq, Wk, Wv, Wo, wqb, wkb, wvb, wob,
      C_*C_/4, 3*C_*C_/4, 3*C_*C_/4, C_*C_/4);

  kv_fused<<<dim3(M2_/128, C_/128, 3), 256, 0, stream>>>(yball, wkb, wvb, bk, bv, kb, vb, ksum);
  ctx_partial<<<dim3(32, 8, 3), 256, 0, stream>>>(kb, vb, part);
  ctx_reduce<<<dim3(32, 3), 256, 0, stream>>>(part, ctxTb);
  q_mega<<<dim3(M1_/128, C_/128), 256, 0, stream>>>(xb, wqb, bq, ctxTb, ksum, omid);
  gemm_bt<<<dim3(M1_/128, C_/128), 256, 0, stream>>>(omid, wob, bo, (float*)d_out, M1_, C_, C_);
}

// Round 5
// 190.633 us; speedup vs baseline: 2.0460x; 1.0179x over previous
//
#include <hip/hip_runtime.h>
#include <stdint.h>

#define B_ 4
#define T1_ 4096
#define T2_ 2048
#define C_ 512
#define H_ 8
#define D_ 64
#define M1_ (B_*T1_)   // 16384
#define M2_ (B_*T2_)   // 8192

using f32x4 = __attribute__((ext_vector_type(4))) float;
using bf16x8 = __attribute__((ext_vector_type(8))) __bf16;
using us8 = __attribute__((ext_vector_type(8))) unsigned short;
using us4 = __attribute__((ext_vector_type(4))) unsigned short;

__device__ __forceinline__ unsigned short f2bf(float f){
  unsigned int u = __builtin_bit_cast(unsigned int, f);
  unsigned int r = (u + 0x7fffu + ((u >> 16) & 1u)) >> 16;
  return (unsigned short)r;
}
__device__ __forceinline__ float bf2f(unsigned short u){
  return __builtin_bit_cast(float, ((unsigned int)u) << 16);
}
__device__ __forceinline__ f32x4 mfma16(us8 a, us8 b, f32x4 c){
  return __builtin_amdgcn_mfma_f32_16x16x32_bf16(
      __builtin_bit_cast(bf16x8, a), __builtin_bit_cast(bf16x8, b), c, 0, 0, 0);
}

typedef const __attribute__((address_space(1))) unsigned int gu32;
typedef __attribute__((address_space(3))) unsigned int lu32;
__device__ __forceinline__ void gl_lds16(const void* g, void* l){
  __builtin_amdgcn_global_load_lds((gu32*)g, (lu32*)l, 16, 0, 0);
}

// counted-vmcnt barrier: loads stay in flight across the barrier (T4)
#define WAIT_VM(N) asm volatile("s_waitcnt vmcnt(" #N ")" ::: "memory")
#define RAW_BAR()  { __builtin_amdgcn_s_barrier(); __builtin_amdgcn_sched_barrier(0); }

// chunk swizzle: LDS[row][blk] holds global chunk blk^g(row), g=(row>>1)&3.
// 16 rows x same-chunk read -> 8 distinct banks x2 lanes = conflict-free.
__device__ __forceinline__ int swz(int row, int blk){ return blk ^ ((row >> 1) & 3); }

// ---------------- fused fp32 -> bf16 convert (4 sources per launch) ----------------
__global__ __launch_bounds__(256) void cvt_bf16_4(const float* __restrict__ p0, const float* __restrict__ p1,
                                                  const float* __restrict__ p2, const float* __restrict__ p3,
                                                  unsigned short* o0, unsigned short* o1,
                                                  unsigned short* o2, unsigned short* o3,
                                                  int n0, int n1, int n2, int n3){
  const float* in; unsigned short* out; int n4;
  switch (blockIdx.y){
    case 0: in = p0; out = o0; n4 = n0; break;
    case 1: in = p1; out = o1; n4 = n1; break;
    case 2: in = p2; out = o2; n4 = n2; break;
    default: in = p3; out = o3; n4 = n3; break;
  }
  int i = blockIdx.x * 256 + threadIdx.x;
  if (i >= n4) return;
  f32x4 v = ((const f32x4*)in)[i];
  us4 o;
  #pragma unroll
  for (int j = 0; j < 4; ++j) o[j] = f2bf(v[j]);
  ((us4*)out)[i] = o;
}

// ---------- C-layout fp32 vals -> swizzled bf16 LDS tile -> coalesced store ----------
__device__ __forceinline__ void tile_write(unsigned short* tile, const f32x4 (&vals)[4][4],
                                           int wr, int wc, int lr, int lk){
  #pragma unroll
  for (int mt = 0; mt < 4; ++mt)
    #pragma unroll
    for (int nt = 0; nt < 4; ++nt)
      #pragma unroll
      for (int r = 0; r < 4; ++r){
        int row = wr*64 + mt*16 + lk*4 + r;
        int cb  = (wc*128 + nt*32 + lr*2) ^ ((row & 7) << 4);
        *(unsigned short*)((char*)tile + row*256 + cb) = f2bf(vals[mt][nt][r]);
      }
}
__device__ __forceinline__ void tile_flush(const unsigned short* tile, unsigned short* g,
                                           size_t row0, int col0, int ldg, int t){
  #pragma unroll
  for (int p = 0; p < 8; ++p){
    int row = p*16 + (t >> 4);
    int cb  = ((t & 15) * 16) ^ ((row & 7) << 4);
    us8 v = *(const us8*)((const char*)tile + row*256 + cb);
    *(us8*)(g + (row0 + row) * (size_t)ldg + col0 + (t & 15) * 8) = v;
  }
}

// ---------------- plain GEMM (3-buf counted-vmcnt): out(fp32) = A @ Bw^T + bias ----------------
__global__ __launch_bounds__(256, 3) void gemm_bt(const unsigned short* __restrict__ A,
                                                  const unsigned short* __restrict__ Bw,
                                                  const float* __restrict__ bias,
                                                  float* __restrict__ out, int M, int N, int Kd){
  __shared__ unsigned short smem[3*2*4096];    // 48 KB
  const int m0 = blockIdx.x * 128, n0 = blockIdx.y * 128;
  const int t = threadIdx.x;
  const int w = t >> 6, l = t & 63;
  const int wr = w >> 1, wc = w & 1;
  const int lr = l & 15, lk = l >> 4;
  f32x4 acc[4][4] = {};
  auto STAGE = [&](int bb, int k0){
    int c = t, row = c >> 2;
    gl_lds16(A  + (size_t)(m0+row)*Kd + k0 + swz(row, c & 3)*8, &smem[bb*8192 + c*8]);
    gl_lds16(Bw + (size_t)(n0+row)*Kd + k0 + swz(row, c & 3)*8, &smem[bb*8192 + 4096 + c*8]);
    c = t + 256; row = c >> 2;
    gl_lds16(A  + (size_t)(m0+row)*Kd + k0 + swz(row, c & 3)*8, &smem[bb*8192 + c*8]);
    gl_lds16(Bw + (size_t)(n0+row)*Kd + k0 + swz(row, c & 3)*8, &smem[bb*8192 + 4096 + c*8]);
  };
  auto COMPUTE = [&](int bb){
    const unsigned short* sA = &smem[bb*8192];
    const unsigned short* sB = &smem[bb*8192 + 4096];
    us8 af[4], bfr[4];
    #pragma unroll
    for (int mt = 0; mt < 4; ++mt){
      int R = wr*64 + mt*16 + lr;
      af[mt] = *(const us8*)&sA[R*32 + swz(R, lk)*8];
    }
    #pragma unroll
    for (int nt = 0; nt < 4; ++nt){
      int R = wc*64 + nt*16 + lr;
      bfr[nt] = *(const us8*)&sB[R*32 + swz(R, lk)*8];
    }
    __builtin_amdgcn_s_setprio(1);
    #pragma unroll
    for (int mt = 0; mt < 4; ++mt)
      #pragma unroll
      for (int nt = 0; nt < 4; ++nt)
        acc[mt][nt] = mfma16(af[mt], bfr[nt], acc[mt][nt]);
    __builtin_amdgcn_s_setprio(0);
  };
  const int NT = Kd >> 5;
  STAGE(0, 0);
  int cur = 0;
  for (int tt = 0; tt < NT - 1; ++tt){
    int nxt = (cur == 2) ? 0 : cur + 1;
    STAGE(nxt, (tt + 1) * 32);
    WAIT_VM(4);
    RAW_BAR();
    COMPUTE(cur);
    cur = nxt;
  }
  WAIT_VM(0);
  RAW_BAR();
  COMPUTE(cur);
  #pragma unroll
  for (int mt = 0; mt < 4; ++mt)
    #pragma unroll
    for (int nt = 0; nt < 4; ++nt)
      #pragma unroll
      for (int r = 0; r < 4; ++r){
        int row = m0 + wr*64 + mt*16 + lk*4 + r;
        int col = n0 + wc*64 + nt*16 + lr;
        out[(size_t)row*N + col] = acc[mt][nt][r] + bias[col];
      }
}

// ---------------- fused K+V projection: 512 thr, K-waves || V-waves, 3-buf counted-vmcnt ----------------
__global__ __launch_bounds__(512, 4) void kv_fused(const unsigned short* __restrict__ yball,
                                                   const unsigned short* __restrict__ wkb,
                                                   const unsigned short* __restrict__ wvb,
                                                   const float* __restrict__ bk,
                                                   const float* __restrict__ bv,
                                                   unsigned short* __restrict__ kb,
                                                   unsigned short* __restrict__ vb,
                                                   float* __restrict__ ksum){
  __shared__ unsigned short smem[3*3*4096];    // 72 KB staging; repack (64 KB) aliases
  const int i = blockIdx.z;
  const int m0 = blockIdx.x * 128, n0 = blockIdx.y * 128;
  const unsigned short* A  = yball + (size_t)i*M2_*C_;
  const unsigned short* Wk = wkb  + (size_t)i*C_*C_;
  const unsigned short* Wv = wvb  + (size_t)i*C_*C_;
  const int t = threadIdx.x;
  const int w = t >> 6, l = t & 63;
  const int grp = w >> 2;                       // 0 = K, 1 = V
  const int wl = w & 3;
  const int wr = wl >> 1, wc = wl & 1;
  const int lr = l & 15, lk = l >> 4;
  f32x4 acc[4][4] = {};
  auto STAGE = [&](int bb, int k0){
    int c = t, row = c >> 2, off = swz(row, c & 3) * 8;
    gl_lds16(A  + (size_t)(m0+row)*C_ + k0 + off, &smem[bb*12288 + c*8]);
    gl_lds16(Wk + (size_t)(n0+row)*C_ + k0 + off, &smem[bb*12288 + 4096 + c*8]);
    gl_lds16(Wv + (size_t)(n0+row)*C_ + k0 + off, &smem[bb*12288 + 8192 + c*8]);
  };
  auto COMPUTE = [&](int bb){
    const unsigned short* sA = &smem[bb*12288];
    const unsigned short* sW = &smem[bb*12288 + 4096 + grp*4096];
    us8 af[4], bfr[4];
    #pragma unroll
    for (int mt = 0; mt < 4; ++mt){
      int R = wr*64 + mt*16 + lr;
      af[mt] = *(const us8*)&sA[R*32 + swz(R, lk)*8];
    }
    #pragma unroll
    for (int nt = 0; nt < 4; ++nt){
      int R = wc*64 + nt*16 + lr;
      bfr[nt] = *(const us8*)&sW[R*32 + swz(R, lk)*8];
    }
    __builtin_amdgcn_s_setprio(1);
    #pragma unroll
    for (int mt = 0; mt < 4; ++mt)
      #pragma unroll
      for (int nt = 0; nt < 4; ++nt)
        acc[mt][nt] = mfma16(af[mt], bfr[nt], acc[mt][nt]);
    __builtin_amdgcn_s_setprio(0);
  };
  STAGE(0, 0);
  int cur = 0;
  for (int tt = 0; tt < 15; ++tt){
    int nxt = (cur == 2) ? 0 : cur + 1;
    STAGE(nxt, (tt + 1) * 32);
    WAIT_VM(3);
    RAW_BAR();
    COMPUTE(cur);
    cur = nxt;
  }
  WAIT_VM(0);
  RAW_BAR();
  COMPUTE(cur);
  // bias
  {
    const float* bp = (grp ? bv : bk) + (size_t)i*C_;
    float bc[4];
    #pragma unroll
    for (int nt = 0; nt < 4; ++nt) bc[nt] = bp[n0 + wc*64 + nt*16 + lr];
    #pragma unroll
    for (int mt = 0; mt < 4; ++mt)
      #pragma unroll
      for (int nt = 0; nt < 4; ++nt)
        #pragma unroll
        for (int r = 0; r < 4; ++r) acc[mt][nt][r] += bc[nt];
  }
  if (grp == 0){
    // in-register softmax over the wave's 64-col head group
    #pragma unroll
    for (int mt = 0; mt < 4; ++mt)
      #pragma unroll
      for (int r = 0; r < 4; ++r){
        float m = fmaxf(fmaxf(acc[mt][0][r], acc[mt][1][r]), fmaxf(acc[mt][2][r], acc[mt][3][r]));
        #pragma unroll
        for (int s = 1; s < 16; s <<= 1) m = fmaxf(m, __shfl_xor(m, s, 64));
        float sum = 0.f;
        #pragma unroll
        for (int nt = 0; nt < 4; ++nt){
          float e = __expf(acc[mt][nt][r] - m);
          acc[mt][nt][r] = e; sum += e;
        }
        #pragma unroll
        for (int s = 1; s < 16; s <<= 1) sum += __shfl_xor(sum, s, 64);
        float inv = 1.0f / sum;
        #pragma unroll
        for (int nt = 0; nt < 4; ++nt) acc[mt][nt][r] *= inv;
      }
    // colsum -> ksum atomics
    const int b = m0 / T2_;
    #pragma unroll
    for (int nt = 0; nt < 4; ++nt){
      float cs = 0.f;
      #pragma unroll
      for (int mt = 0; mt < 4; ++mt)
        #pragma unroll
        for (int r = 0; r < 4; ++r) cs += acc[mt][nt][r];
      cs += __shfl_xor(cs, 16, 64);
      cs += __shfl_xor(cs, 32, 64);
      if (lk == 0)
        atomicAdd(&ksum[((size_t)i*B_ + b)*C_ + n0 + wc*64 + nt*16 + lr], cs);
    }
  }
  // repack + store (K group -> tile 0, V group -> tile 1; both alias staging)
  __syncthreads();
  tile_write(smem + grp*16384, acc, wr, wc, lr, lk);
  __syncthreads();
  tile_flush(smem + grp*16384, (grp ? vb : kb) + (size_t)i*M2_*C_, m0, n0, C_, t & 255);
}

// ---------------- context partials: part[i][ch][bh][e*64+d] = sum_n k[n,d] v[n,e] ----------------
__global__ __launch_bounds__(256) void ctx_partial(const unsigned short* __restrict__ kb,
                                                   const unsigned short* __restrict__ vb,
                                                   float* __restrict__ part){
  __shared__ unsigned short lk_[16384];
  __shared__ unsigned short lv_[16384];
  const int bh = blockIdx.x, ch = blockIdx.y, i = blockIdx.z;
  const int b = bh >> 3, h = bh & 7;
  const int t = threadIdx.x;
  const unsigned short* kbi = kb + (size_t)i*M2_*C_;
  const unsigned short* vbi = vb + (size_t)i*M2_*C_;
  size_t rowbase = (size_t)(b*T2_ + ch*256);
  #pragma unroll
  for (int it = 0; it < 8; ++it){
    int c = t + it*256;
    int row = c >> 3, off = (c & 7) * 8;
    gl_lds16(kbi + (rowbase + row)*C_ + h*D_ + off, &lk_[c*8]);
    gl_lds16(vbi + (rowbase + row)*C_ + h*D_ + off, &lv_[c*8]);
  }
  __syncthreads();
  int d0 = (t & 15) * 4, e0 = (t >> 4) * 4;
  float acc[4][4] = {};
  for (int n = 0; n < 256; ++n){
    us4 kq = *(const us4*)&lk_[n*64 + d0];
    us4 vq = *(const us4*)&lv_[n*64 + e0];
    float kf[4], vf[4];
    #pragma unroll
    for (int j = 0; j < 4; ++j){ kf[j] = bf2f(kq[j]); vf[j] = bf2f(vq[j]); }
    #pragma unroll
    for (int jd = 0; jd < 4; ++jd)
      #pragma unroll
      for (int je = 0; je < 4; ++je)
        acc[jd][je] += kf[jd] * vf[je];
  }
  float* dst = part + (((size_t)i*8 + ch)*32 + bh) * 4096;
  #pragma unroll
  for (int jd = 0; jd < 4; ++jd)
    #pragma unroll
    for (int je = 0; je < 4; ++je)
      dst[(e0+je)*64 + (d0+jd)] = acc[jd][je];
}

__global__ __launch_bounds__(256) void ctx_reduce(const float* __restrict__ part,
                                                  unsigned short* __restrict__ ctxTb){
  const int bh = blockIdx.x, i = blockIdx.y, t = threadIdx.x;
  for (int idx = t; idx < 4096; idx += 256){
    float s = 0.f;
    #pragma unroll
    for (int ch = 0; ch < 8; ++ch)
      s += part[(((size_t)i*8 + ch)*32 + bh)*4096 + idx];
    ctxTb[((size_t)i*32 + bh)*4096 + idx] = f2bf(s);
  }
}

// ---------------- fused Q (3-buf counted-vmcnt): GEMM + softmax + (den, q@ctx, fold) ----------------
__global__ __launch_bounds__(256, 3) void q_mega(const unsigned short* __restrict__ xb,
                                                 const unsigned short* __restrict__ wqb,
                                                 const float* __restrict__ bq,
                                                 const unsigned short* __restrict__ ctxTb,
                                                 const float* __restrict__ ksum,
                                                 unsigned short* __restrict__ omid){
  __shared__ unsigned short smem[3*2*4096];    // 48 KB; repack tile (32 KB) aliases
  const int m0 = blockIdx.x * 128, n0 = blockIdx.y * 128;
  const int t = threadIdx.x;
  const int w = t >> 6, l = t & 63;
  const int wr = w >> 1, wc = w & 1;
  const int lr = l & 15, lk = l >> 4;
  f32x4 acc[4][4] = {};
  auto STAGE = [&](int bb, int k0){
    int c = t, row = c >> 2;
    gl_lds16(xb  + (size_t)(m0+row)*C_ + k0 + swz(row, c & 3)*8, &smem[bb*8192 + c*8]);
    gl_lds16(wqb + (size_t)(n0+row)*C_ + k0 + swz(row, c & 3)*8, &smem[bb*8192 + 4096 + c*8]);
    c = t + 256; row = c >> 2;
    gl_lds16(xb  + (size_t)(m0+row)*C_ + k0 + swz(row, c & 3)*8, &smem[bb*8192 + c*8]);
    gl_lds16(wqb + (size_t)(n0+row)*C_ + k0 + swz(row, c & 3)*8, &smem[bb*8192 + 4096 + c*8]);
  };
  auto COMPUTE = [&](int bb){
    const unsigned short* sA = &smem[bb*8192];
    const unsigned short* sB = &smem[bb*8192 + 4096];
    us8 af[4], bfr[4];
    #pragma unroll
    for (int mt = 0; mt < 4; ++mt){
      int R = wr*64 + mt*16 + lr;
      af[mt] = *(const us8*)&sA[R*32 + swz(R, lk)*8];
    }
    #pragma unroll
    for (int nt = 0; nt < 4; ++nt){
      int R = wc*64 + nt*16 + lr;
      bfr[nt] = *(const us8*)&sB[R*32 + swz(R, lk)*8];
    }
    __builtin_amdgcn_s_setprio(1);
    #pragma unroll
    for (int mt = 0; mt < 4; ++mt)
      #pragma unroll
      for (int nt = 0; nt < 4; ++nt)
        acc[mt][nt] = mfma16(af[mt], bfr[nt], acc[mt][nt]);
    __builtin_amdgcn_s_setprio(0);
  };
  STAGE(0, 0);
  int cur = 0;
  for (int tt = 0; tt < 15; ++tt){
    int nxt = (cur == 2) ? 0 : cur + 1;
    STAGE(nxt, (tt + 1) * 32);
    WAIT_VM(4);
    RAW_BAR();
    COMPUTE(cur);
    cur = nxt;
  }
  WAIT_VM(0);
  RAW_BAR();
  COMPUTE(cur);
  // bias + softmax
  {
    float bc[4];
    #pragma unroll
    for (int nt = 0; nt < 4; ++nt) bc[nt] = bq[n0 + wc*64 + nt*16 + lr];
    #pragma unroll
    for (int mt = 0; mt < 4; ++mt)
      #pragma unroll
      for (int r = 0; r < 4; ++r){
        #pragma unroll
        for (int nt = 0; nt < 4; ++nt) acc[mt][nt][r] += bc[nt];
        float m = fmaxf(fmaxf(acc[mt][0][r], acc[mt][1][r]), fmaxf(acc[mt][2][r], acc[mt][3][r]));
        #pragma unroll
        for (int s = 1; s < 16; s <<= 1) m = fmaxf(m, __shfl_xor(m, s, 64));
        float sum = 0.f;
        #pragma unroll
        for (int nt = 0; nt < 4; ++nt){
          float e = __expf(acc[mt][nt][r] - m);
          acc[mt][nt][r] = e; sum += e;
        }
        #pragma unroll
        for (int s = 1; s < 16; s <<= 1) sum += __shfl_xor(sum, s, 64);
        float inv = 1.0f / sum;
        #pragma unroll
        for (int nt = 0; nt < 4; ++nt) acc[mt][nt][r] *= inv;
      }
  }
  const int b = m0 / T1_;
  const int bh = b*8 + (n0 >> 6) + wc;
  // q -> swizzled repack tile (aliases staging), then A-frags
  __syncthreads();
  tile_write(smem, acc, wr, wc, lr, lk);
  __syncthreads();
  us8 afr[4][2];
  #pragma unroll
  for (int mt = 0; mt < 4; ++mt)
    #pragma unroll
    for (int kk = 0; kk < 2; ++kk){
      int row = wr*64 + mt*16 + lr;
      int cb = (wc*128 + kk*64 + lk*16) ^ ((row & 7) << 4);
      afr[mt][kk] = *(const us8*)((char*)smem + row*256 + cb);
    }
  // denominator MFMA: B rows 0..2 = ksum_i over this head's 64 channels
  us8 bden[2];
  #pragma unroll
  for (int kk = 0; kk < 2; ++kk){
    us8 tmp = {};
    if (lr < 3){
      const float* kp = ksum + ((size_t)lr*B_ + b)*C_ + n0 + wc*64 + kk*32 + lk*8;
      f32x4 c0 = *(const f32x4*)kp;
      f32x4 c1 = *(const f32x4*)(kp + 4);
      #pragma unroll
      for (int j = 0; j < 4; ++j){ tmp[j] = f2bf(c0[j]); tmp[4+j] = f2bf(c1[j]); }
    }
    bden[kk] = tmp;
  }
  f32x4 den[4] = {};
  #pragma unroll
  for (int mt = 0; mt < 4; ++mt)
    #pragma unroll
    for (int kk = 0; kk < 2; ++kk)
      den[mt] = mfma16(afr[mt][kk], bden[kk], den[mt]);
  // per-i: q@ctxT_i, fold with Dinv (all inner loops fully unrolled -> static acc indexing)
  #pragma unroll 1
  for (int i = 0; i < 3; ++i){
    f32x4 dinv[4];
    #pragma unroll
    for (int mt = 0; mt < 4; ++mt)
      #pragma unroll
      for (int r = 0; r < 4; ++r)
        dinv[mt][r] = 1.0f / (__shfl(den[mt][r], (l & 48) | i, 64) + 1e-8f);
    #pragma unroll
    for (int nt = 0; nt < 4; ++nt){
      us8 bfr[2];
      #pragma unroll
      for (int kk = 0; kk < 2; ++kk)
        bfr[kk] = *(const us8*)(ctxTb + ((size_t)(i*32 + bh))*4096 + (nt*16 + lr)*64 + kk*32 + lk*8);
      f32x4 p[4] = {};
      #pragma unroll
      for (int mt = 0; mt < 4; ++mt)
        #pragma unroll
        for (int kk = 0; kk < 2; ++kk)
          p[mt] = mfma16(afr[mt][kk], bfr[kk], p[mt]);
      #pragma unroll
      for (int mt = 0; mt < 4; ++mt)
        #pragma unroll
        for (int r = 0; r < 4; ++r)
          acc[mt][nt][r] += p[mt][r] * dinv[mt][r];
    }
  }
  __syncthreads();   // all A-frag reads complete before tile reuse
  tile_write(smem, acc, wr, wc, lr, lk);
  __syncthreads();
  tile_flush(smem, omid, m0, n0, C_, t);
}

extern "C" void kernel_launch(void* const* d_in, const int* in_sizes, int n_in,
                              void* d_out, int out_size, void* d_ws, size_t ws_size,
                              hipStream_t stream){
  const float* x  = (const float*)d_in[0];
  const float* y0 = (const float*)d_in[1];
  const float* y1 = (const float*)d_in[2];
  const float* y2 = (const float*)d_in[3];
  const float* Wq = (const float*)d_in[4];
  const float* bq = (const float*)d_in[5];
  const float* Wk = (const float*)d_in[6];
  const float* bk = (const float*)d_in[7];
  const float* Wv = (const float*)d_in[8];
  const float* bv = (const float*)d_in[9];
  const float* Wo = (const float*)d_in[10];
  const float* bo = (const float*)d_in[11];

  char* ws = (char*)d_ws;
  size_t off = 0;
  auto alloc = [&](size_t bytes)->char*{
    char* p = ws + off; off += (bytes + 1023) & ~((size_t)1023); return p;
  };
  unsigned short* xb    = (unsigned short*)alloc((size_t)M1_*C_*2);
  unsigned short* yball = (unsigned short*)alloc((size_t)3*M2_*C_*2);
  unsigned short* wqb   = (unsigned short*)alloc((size_t)C_*C_*2);
  unsigned short* wkb   = (unsigned short*)alloc((size_t)3*C_*C_*2);
  unsigned short* wvb   = (unsigned short*)alloc((size_t)3*C_*C_*2);
  unsigned short* wob   = (unsigned short*)alloc((size_t)C_*C_*2);
  unsigned short* kb    = (unsigned short*)alloc((size_t)3*M2_*C_*2);
  unsigned short* vb    = (unsigned short*)alloc((size_t)3*M2_*C_*2);
  float*          ksum  = (float*)alloc((size_t)3*B_*C_*4);
  float*          part  = (float*)alloc((size_t)3*8*32*4096*4);
  unsigned short* ctxTb = (unsigned short*)alloc((size_t)3*32*4096*2);
  unsigned short* omid  = (unsigned short*)alloc((size_t)M1_*C_*2);

  hipMemsetAsync(ksum, 0, (size_t)3*B_*C_*4, stream);

  cvt_bf16_4<<<dim3(M1_*C_/4/256, 4), 256, 0, stream>>>(
      x, y0, y1, y2, xb, yball, yball + (size_t)M2_*C_, yball + (size_t)2*M2_*C_,
      M1_*C_/4, M2_*C_/4, M2_*C_/4, M2_*C_/4);
  cvt_bf16_4<<<dim3(3*C_*C_/4/256, 4), 256, 0, stream>>>(
      Wq, Wk, Wv, Wo, wqb, wkb, wvb, wob,
      C_*C_/4, 3*C_*C_/4, 3*C_*C_/4, C_*C_/4);

  kv_fused<<<dim3(M2_/128, C_/128, 3), 512, 0, stream>>>(yball, wkb, wvb, bk, bv, kb, vb, ksum);
  ctx_partial<<<dim3(32, 8, 3), 256, 0, stream>>>(kb, vb, part);
  ctx_reduce<<<dim3(32, 3), 256, 0, stream>>>(part, ctxTb);
  q_mega<<<dim3(M1_/128, C_/128), 256, 0, stream>>>(xb, wqb, bq, ctxTb, ksum, omid);
  gemm_bt<<<dim3(M1_/128, C_/128), 256, 0, stream>>>(omid, wob, bo, (float*)d_out, M1_, C_, C_);
}

// Round 7
// 173.488 us; speedup vs baseline: 2.2482x; 1.0988x over previous
//
#include <hip/hip_runtime.h>
#include <stdint.h>

#define B_ 4
#define T1_ 4096
#define T2_ 2048
#define C_ 512
#define H_ 8
#define D_ 64
#define M1_ (B_*T1_)   // 16384
#define M2_ (B_*T2_)   // 8192

using f32x4 = __attribute__((ext_vector_type(4))) float;
using bf16x8 = __attribute__((ext_vector_type(8))) __bf16;
using us8 = __attribute__((ext_vector_type(8))) unsigned short;
using us4 = __attribute__((ext_vector_type(4))) unsigned short;

__device__ __forceinline__ unsigned short f2bf(float f){
  unsigned int u = __builtin_bit_cast(unsigned int, f);
  unsigned int r = (u + 0x7fffu + ((u >> 16) & 1u)) >> 16;
  return (unsigned short)r;
}
__device__ __forceinline__ float bf2f(unsigned short u){
  return __builtin_bit_cast(float, ((unsigned int)u) << 16);
}
__device__ __forceinline__ f32x4 mfma16(us8 a, us8 b, f32x4 c){
  return __builtin_amdgcn_mfma_f32_16x16x32_bf16(
      __builtin_bit_cast(bf16x8, a), __builtin_bit_cast(bf16x8, b), c, 0, 0, 0);
}

typedef const __attribute__((address_space(1))) unsigned int gu32;
typedef __attribute__((address_space(3))) unsigned int lu32;
__device__ __forceinline__ void gl_lds16(const void* g, void* l){
  __builtin_amdgcn_global_load_lds((gu32*)g, (lu32*)l, 16, 0, 0);
}

#define WAIT_VM(N) asm volatile("s_waitcnt vmcnt(" #N ")" ::: "memory")
#define RAW_BAR()  { __builtin_amdgcn_s_barrier(); __builtin_amdgcn_sched_barrier(0); }

// chunk swizzle for the K-loop staging (involution, rule 21)
__device__ __forceinline__ int swz(int row, int blk){ return blk ^ ((row >> 1) & 3); }

// ---------------- fused fp32 -> bf16 convert (4 sources per launch) ----------------
__global__ __launch_bounds__(256) void cvt_bf16_4(const float* __restrict__ p0, const float* __restrict__ p1,
                                                  const float* __restrict__ p2, const float* __restrict__ p3,
                                                  unsigned short* o0, unsigned short* o1,
                                                  unsigned short* o2, unsigned short* o3,
                                                  int n0, int n1, int n2, int n3){
  const float* in; unsigned short* out; int n4;
  switch (blockIdx.y){
    case 0: in = p0; out = o0; n4 = n0; break;
    case 1: in = p1; out = o1; n4 = n1; break;
    case 2: in = p2; out = o2; n4 = n2; break;
    default: in = p3; out = o3; n4 = n3; break;
  }
  int i = blockIdx.x * 256 + threadIdx.x;
  if (i >= n4) return;
  f32x4 v = ((const f32x4*)in)[i];
  us4 o;
  #pragma unroll
  for (int j = 0; j < 4; ++j) o[j] = f2bf(v[j]);
  ((us4*)out)[i] = o;
}

// ---------- C-layout fp32 vals -> swizzled bf16 LDS tile -> coalesced store ----------
__device__ __forceinline__ void tile_write(unsigned short* tile, const f32x4 (&vals)[4][4],
                                           int wr, int wc, int lr, int lk){
  #pragma unroll
  for (int mt = 0; mt < 4; ++mt)
    #pragma unroll
    for (int nt = 0; nt < 4; ++nt)
      #pragma unroll
      for (int r = 0; r < 4; ++r){
        int row = wr*64 + mt*16 + lk*4 + r;
        int cb  = (wc*128 + nt*32 + lr*2) ^ ((row & 7) << 4);
        *(unsigned short*)((char*)tile + row*256 + cb) = f2bf(vals[mt][nt][r]);
      }
}
__device__ __forceinline__ void tile_flush(const unsigned short* tile, unsigned short* g,
                                           size_t row0, int col0, int ldg, int t){
  #pragma unroll
  for (int p = 0; p < 8; ++p){
    int row = p*16 + (t >> 4);
    int cb  = ((t & 15) * 16) ^ ((row & 7) << 4);
    us8 v = *(const us8*)((const char*)tile + row*256 + cb);
    *(us8*)(g + (row0 + row) * (size_t)ldg + col0 + (t & 15) * 8) = v;
  }
}

// ================= merged projection kernel: Q (+softmax), K (+softmax+ksum), V =================
// grid 2048 x 256thr, 48 KB LDS -> 3 blocks/CU. Segments: [0,512)=Q, [512,1280)=K(i), [1280,2048)=V(i)
__global__ __launch_bounds__(256, 3) void proj(const unsigned short* __restrict__ xb,
                                               const unsigned short* __restrict__ yball,
                                               const unsigned short* __restrict__ wqb,
                                               const unsigned short* __restrict__ wkb,
                                               const unsigned short* __restrict__ wvb,
                                               const float* __restrict__ bq,
                                               const float* __restrict__ bk,
                                               const float* __restrict__ bv,
                                               unsigned short* __restrict__ qb,
                                               unsigned short* __restrict__ kb,
                                               unsigned short* __restrict__ vb,
                                               float* __restrict__ ksum){
  __shared__ unsigned short smem[3*2*4096];    // 48 KB staging; 32 KB repack tile aliases
  // XCD-chunked bijective swizzle (nwg=2048, cpx=256)
  const int hw = blockIdx.x;
  const int work = (hw & 7) * 256 + (hw >> 3);
  int seg, ii, m0, n0;
  const unsigned short *A, *W;
  const float* bias;
  if (work < 512){
    seg = 0; ii = 0;
    m0 = (work & 127) << 7; n0 = (work >> 7) << 7;
    A = xb; W = wqb; bias = bq;
  } else {
    int r = work - 512;
    seg = (r >= 768) ? 2 : 1;
    if (r >= 768) r -= 768;
    ii = r >> 8; r &= 255;
    m0 = (r & 63) << 7; n0 = (r >> 6) << 7;
    A = yball + (size_t)ii*M2_*C_;
    W = (seg == 1 ? wkb : wvb) + (size_t)ii*C_*C_;
    bias = (seg == 1 ? bk : bv) + (size_t)ii*C_;
  }
  const int t = threadIdx.x;
  const int w = t >> 6, l = t & 63;
  const int wr = w >> 1, wc = w & 1;
  const int lr = l & 15, lk = l >> 4;
  f32x4 acc[4][4] = {};
  auto STAGE = [&](int bb, int k0){
    int c = t, row = c >> 2;
    gl_lds16(A + (size_t)(m0+row)*C_ + k0 + swz(row, c & 3)*8, &smem[bb*8192 + c*8]);
    gl_lds16(W + (size_t)(n0+row)*C_ + k0 + swz(row, c & 3)*8, &smem[bb*8192 + 4096 + c*8]);
    c = t + 256; row = c >> 2;
    gl_lds16(A + (size_t)(m0+row)*C_ + k0 + swz(row, c & 3)*8, &smem[bb*8192 + c*8]);
    gl_lds16(W + (size_t)(n0+row)*C_ + k0 + swz(row, c & 3)*8, &smem[bb*8192 + 4096 + c*8]);
  };
  auto COMPUTE = [&](int bb){
    const unsigned short* sA = &smem[bb*8192];
    const unsigned short* sB = &smem[bb*8192 + 4096];
    us8 af[4], bfr[4];
    #pragma unroll
    for (int mt = 0; mt < 4; ++mt){
      int R = wr*64 + mt*16 + lr;
      af[mt] = *(const us8*)&sA[R*32 + swz(R, lk)*8];
    }
    #pragma unroll
    for (int nt = 0; nt < 4; ++nt){
      int R = wc*64 + nt*16 + lr;
      bfr[nt] = *(const us8*)&sB[R*32 + swz(R, lk)*8];
    }
    __builtin_amdgcn_s_setprio(1);
    #pragma unroll
    for (int mt = 0; mt < 4; ++mt)
      #pragma unroll
      for (int nt = 0; nt < 4; ++nt)
        acc[mt][nt] = mfma16(af[mt], bfr[nt], acc[mt][nt]);
    __builtin_amdgcn_s_setprio(0);
  };
  STAGE(0, 0);
  int cur = 0;
  for (int tt = 0; tt < 15; ++tt){
    int nxt = (cur == 2) ? 0 : cur + 1;
    STAGE(nxt, (tt + 1) * 32);
    WAIT_VM(4);
    RAW_BAR();
    COMPUTE(cur);
    cur = nxt;
  }
  WAIT_VM(0);
  RAW_BAR();
  COMPUTE(cur);
  // bias
  {
    float bc[4];
    #pragma unroll
    for (int nt = 0; nt < 4; ++nt) bc[nt] = bias[n0 + wc*64 + nt*16 + lr];
    #pragma unroll
    for (int mt = 0; mt < 4; ++mt)
      #pragma unroll
      for (int nt = 0; nt < 4; ++nt)
        #pragma unroll
        for (int r = 0; r < 4; ++r) acc[mt][nt][r] += bc[nt];
  }
  if (seg <= 1){
    // in-register softmax over the wave's 64-col head group
    #pragma unroll
    for (int mt = 0; mt < 4; ++mt)
      #pragma unroll
      for (int r = 0; r < 4; ++r){
        float m = fmaxf(fmaxf(acc[mt][0][r], acc[mt][1][r]), fmaxf(acc[mt][2][r], acc[mt][3][r]));
        #pragma unroll
        for (int s = 1; s < 16; s <<= 1) m = fmaxf(m, __shfl_xor(m, s, 64));
        float sum = 0.f;
        #pragma unroll
        for (int nt = 0; nt < 4; ++nt){
          float e = __expf(acc[mt][nt][r] - m);
          acc[mt][nt][r] = e; sum += e;
        }
        #pragma unroll
        for (int s = 1; s < 16; s <<= 1) sum += __shfl_xor(sum, s, 64);
        float inv = 1.0f / sum;
        #pragma unroll
        for (int nt = 0; nt < 4; ++nt) acc[mt][nt][r] *= inv;
      }
  }
  if (seg == 1){
    // colsum -> ksum atomics
    const int b = m0 >> 11;        // T2_ = 2048 rows per batch
    #pragma unroll
    for (int nt = 0; nt < 4; ++nt){
      float cs = 0.f;
      #pragma unroll
      for (int mt = 0; mt < 4; ++mt)
        #pragma unroll
        for (int r = 0; r < 4; ++r) cs += acc[mt][nt][r];
      cs += __shfl_xor(cs, 16, 64);
      cs += __shfl_xor(cs, 32, 64);
      if (lk == 0)
        atomicAdd(&ksum[((size_t)ii*B_ + b)*C_ + n0 + wc*64 + nt*16 + lr], cs);
    }
  }
  unsigned short* dst = (seg == 0) ? qb : ((seg == 1 ? kb : vb) + (size_t)ii*M2_*C_);
  __syncthreads();
  tile_write(smem, acc, wr, wc, lr, lk);
  __syncthreads();
  tile_flush(smem, dst, m0, n0, C_, t);
}

// ---------------- context partials: part[i][ch][bh][e*64+d] = sum_n k[n,d] v[n,e] ----------------
__global__ __launch_bounds__(256) void ctx_partial(const unsigned short* __restrict__ kb,
                                                   const unsigned short* __restrict__ vb,
                                                   float* __restrict__ part){
  __shared__ unsigned short lk_[16384];
  __shared__ unsigned short lv_[16384];
  const int bh = blockIdx.x, ch = blockIdx.y, i = blockIdx.z;
  const int b = bh >> 3, h = bh & 7;
  const int t = threadIdx.x;
  const unsigned short* kbi = kb + (size_t)i*M2_*C_;
  const unsigned short* vbi = vb + (size_t)i*M2_*C_;
  size_t rowbase = (size_t)(b*T2_ + ch*256);
  #pragma unroll
  for (int it = 0; it < 8; ++it){
    int c = t + it*256;
    int row = c >> 3, off = (c & 7) * 8;
    gl_lds16(kbi + (rowbase + row)*C_ + h*D_ + off, &lk_[c*8]);
    gl_lds16(vbi + (rowbase + row)*C_ + h*D_ + off, &lv_[c*8]);
  }
  __syncthreads();
  int d0 = (t & 15) * 4, e0 = (t >> 4) * 4;
  float acc[4][4] = {};
  for (int n = 0; n < 256; ++n){
    us4 kq = *(const us4*)&lk_[n*64 + d0];
    us4 vq = *(const us4*)&lv_[n*64 + e0];
    float kf[4], vf[4];
    #pragma unroll
    for (int j = 0; j < 4; ++j){ kf[j] = bf2f(kq[j]); vf[j] = bf2f(vq[j]); }
    #pragma unroll
    for (int jd = 0; jd < 4; ++jd)
      #pragma unroll
      for (int je = 0; je < 4; ++je)
        acc[jd][je] += kf[jd] * vf[je];
  }
  float* dst = part + (((size_t)i*8 + ch)*32 + bh) * 4096;
  #pragma unroll
  for (int jd = 0; jd < 4; ++jd)
    #pragma unroll
    for (int je = 0; je < 4; ++je)
      dst[(e0+je)*64 + (d0+jd)] = acc[jd][je];
}

__global__ __launch_bounds__(256) void ctx_reduce(const float* __restrict__ part,
                                                  unsigned short* __restrict__ ctxTb){
  const int bh = blockIdx.x, i = blockIdx.y, t = threadIdx.x;
  for (int idx = t; idx < 4096; idx += 256){
    float s = 0.f;
    #pragma unroll
    for (int ch = 0; ch < 8; ++ch)
      s += part[(((size_t)i*8 + ch)*32 + bh)*4096 + idx];
    ctxTb[((size_t)i*32 + bh)*4096 + idx] = f2bf(s);
  }
}

// ================= combine: omid = q + sum_i (q @ ctx_i) * Dinv_i =================
// 512 blocks x 256 thr; q staged via gl_lds with row-XOR'd source chunks (rule-21 involution)
__global__ __launch_bounds__(256) void combine(const unsigned short* __restrict__ qb,
                                               const unsigned short* __restrict__ ctxTb,
                                               const float* __restrict__ ksum,
                                               unsigned short* __restrict__ omid){
  __shared__ unsigned short tile[128*128];     // 32 KB
  const int hw = blockIdx.x;
  const int work = (hw & 7) * 64 + (hw >> 3);  // nwg=512, cpx=64
  const int m0 = (work & 127) << 7, n0 = (work >> 7) << 7;
  const int t = threadIdx.x;
  const int w = t >> 6, l = t & 63;
  const int wr = w >> 1, wc = w & 1;
  const int lr = l & 15, lk = l >> 4;
  const int b = m0 >> 12;                      // T1_ = 4096 rows per batch
  const int bh = b*8 + (n0 >> 6) + wc;
  // stage q[128 x 128] with per-row chunk XOR on the SOURCE (LDS linear)
  #pragma unroll
  for (int p = 0; p < 8; ++p){
    int idx = p*256 + t;
    int row = idx >> 4, ch = idx & 15;
    gl_lds16(qb + (size_t)(m0+row)*C_ + n0 + (ch ^ (row & 7))*8, &tile[idx*8]);
  }
  WAIT_VM(0);
  __syncthreads();
  // A-frags (swizzled read)
  us8 afr[4][2];
  #pragma unroll
  for (int mt = 0; mt < 4; ++mt)
    #pragma unroll
    for (int kk = 0; kk < 2; ++kk){
      int row = wr*64 + mt*16 + lr;
      int ch = wc*8 + kk*4 + lk;
      afr[mt][kk] = *(const us8*)((const char*)tile + row*256 + ((ch ^ (row & 7)) << 4));
    }
  // acc init = q values in C layout (scalar swizzled reads)
  f32x4 acc[4][4];
  #pragma unroll
  for (int mt = 0; mt < 4; ++mt)
    #pragma unroll
    for (int nt = 0; nt < 4; ++nt)
      #pragma unroll
      for (int r = 0; r < 4; ++r){
        int row = wr*64 + mt*16 + lk*4 + r;
        int cbyte = wc*128 + nt*32 + lr*2;
        int ch = cbyte >> 4;
        unsigned short v = *(const unsigned short*)((const char*)tile + row*256 +
                            ((ch ^ (row & 7)) << 4) + (cbyte & 15));
        acc[mt][nt][r] = bf2f(v);
      }
  // denominator MFMA: B rows 0..2 = ksum_i over this head's 64 channels
  us8 bden[2];
  #pragma unroll
  for (int kk = 0; kk < 2; ++kk){
    us8 tmp = {};
    if (lr < 3){
      const float* kp = ksum + ((size_t)lr*B_ + b)*C_ + n0 + wc*64 + kk*32 + lk*8;
      f32x4 c0 = *(const f32x4*)kp;
      f32x4 c1 = *(const f32x4*)(kp + 4);
      #pragma unroll
      for (int j = 0; j < 4; ++j){ tmp[j] = f2bf(c0[j]); tmp[4+j] = f2bf(c1[j]); }
    }
    bden[kk] = tmp;
  }
  f32x4 den[4] = {};
  #pragma unroll
  for (int mt = 0; mt < 4; ++mt)
    #pragma unroll
    for (int kk = 0; kk < 2; ++kk)
      den[mt] = mfma16(afr[mt][kk], bden[kk], den[mt]);
  // per-i: q@ctxT_i, fold with Dinv (all inner loops fully unrolled)
  #pragma unroll 1
  for (int i = 0; i < 3; ++i){
    f32x4 dinv[4];
    #pragma unroll
    for (int mt = 0; mt < 4; ++mt)
      #pragma unroll
      for (int r = 0; r < 4; ++r)
        dinv[mt][r] = 1.0f / (__shfl(den[mt][r], (l & 48) | i, 64) + 1e-8f);
    #pragma unroll
    for (int nt = 0; nt < 4; ++nt){
      us8 bfr[2];
      #pragma unroll
      for (int kk = 0; kk < 2; ++kk)
        bfr[kk] = *(const us8*)(ctxTb + ((size_t)(i*32 + bh))*4096 + (nt*16 + lr)*64 + kk*32 + lk*8);
      f32x4 p[4] = {};
      #pragma unroll
      for (int mt = 0; mt < 4; ++mt)
        #pragma unroll
        for (int kk = 0; kk < 2; ++kk)
          p[mt] = mfma16(afr[mt][kk], bfr[kk], p[mt]);
      #pragma unroll
      for (int mt = 0; mt < 4; ++mt)
        #pragma unroll
        for (int r = 0; r < 4; ++r)
          acc[mt][nt][r] += p[mt][r] * dinv[mt][r];
    }
  }
  __syncthreads();   // all tile reads complete before reuse
  tile_write(tile, acc, wr, wc, lr, lk);
  __syncthreads();
  tile_flush(tile, omid, m0, n0, C_, t);
}

// ---------------- O-proj GEMM (3-buf counted-vmcnt, 1D grid + XCD swizzle) ----------------
__global__ __launch_bounds__(256, 3) void gemm_bt(const unsigned short* __restrict__ A,
                                                  const unsigned short* __restrict__ Bw,
                                                  const float* __restrict__ bias,
                                                  float* __restrict__ out){
  __shared__ unsigned short smem[3*2*4096];
  const int hw = blockIdx.x;
  const int work = (hw & 7) * 64 + (hw >> 3);  // nwg=512, cpx=64
  const int m0 = (work & 127) << 7, n0 = (work >> 7) << 7;
  const int t = threadIdx.x;
  const int w = t >> 6, l = t & 63;
  const int wr = w >> 1, wc = w & 1;
  const int lr = l & 15, lk = l >> 4;
  f32x4 acc[4][4] = {};
  auto STAGE = [&](int bb, int k0){
    int c = t, row = c >> 2;
    gl_lds16(A  + (size_t)(m0+row)*C_ + k0 + swz(row, c & 3)*8, &smem[bb*8192 + c*8]);
    gl_lds16(Bw + (size_t)(n0+row)*C_ + k0 + swz(row, c & 3)*8, &smem[bb*8192 + 4096 + c*8]);
    c = t + 256; row = c >> 2;
    gl_lds16(A  + (size_t)(m0+row)*C_ + k0 + swz(row, c & 3)*8, &smem[bb*8192 + c*8]);
    gl_lds16(Bw + (size_t)(n0+row)*C_ + k0 + swz(row, c & 3)*8, &smem[bb*8192 + 4096 + c*8]);
  };
  auto COMPUTE = [&](int bb){
    const unsigned short* sA = &smem[bb*8192];
    const unsigned short* sB = &smem[bb*8192 + 4096];
    us8 af[4], bfr[4];
    #pragma unroll
    for (int mt = 0; mt < 4; ++mt){
      int R = wr*64 + mt*16 + lr;
      af[mt] = *(const us8*)&sA[R*32 + swz(R, lk)*8];
    }
    #pragma unroll
    for (int nt = 0; nt < 4; ++nt){
      int R = wc*64 + nt*16 + lr;
      bfr[nt] = *(const us8*)&sB[R*32 + swz(R, lk)*8];
    }
    __builtin_amdgcn_s_setprio(1);
    #pragma unroll
    for (int mt = 0; mt < 4; ++mt)
      #pragma unroll
      for (int nt = 0; nt < 4; ++nt)
        acc[mt][nt] = mfma16(af[mt], bfr[nt], acc[mt][nt]);
    __builtin_amdgcn_s_setprio(0);
  };
  STAGE(0, 0);
  int cur = 0;
  for (int tt = 0; tt < 15; ++tt){
    int nxt = (cur == 2) ? 0 : cur + 1;
    STAGE(nxt, (tt + 1) * 32);
    WAIT_VM(4);
    RAW_BAR();
    COMPUTE(cur);
    cur = nxt;
  }
  WAIT_VM(0);
  RAW_BAR();
  COMPUTE(cur);
  #pragma unroll
  for (int mt = 0; mt < 4; ++mt)
    #pragma unroll
    for (int nt = 0; nt < 4; ++nt)
      #pragma unroll
      for (int r = 0; r < 4; ++r){
        int row = m0 + wr*64 + mt*16 + lk*4 + r;
        int col = n0 + wc*64 + nt*16 + lr;
        out[(size_t)row*C_ + col] = acc[mt][nt][r] + bias[col];
      }
}

extern "C" void kernel_launch(void* const* d_in, const int* in_sizes, int n_in,
                              void* d_out, int out_size, void* d_ws, size_t ws_size,
                              hipStream_t stream){
  const float* x  = (const float*)d_in[0];
  const float* y0 = (const float*)d_in[1];
  const float* y1 = (const float*)d_in[2];
  const float* y2 = (const float*)d_in[3];
  const float* Wq = (const float*)d_in[4];
  const float* bq = (const float*)d_in[5];
  const float* Wk = (const float*)d_in[6];
  const float* bk = (const float*)d_in[7];
  const float* Wv = (const float*)d_in[8];
  const float* bv = (const float*)d_in[9];
  const float* Wo = (const float*)d_in[10];
  const float* bo = (const float*)d_in[11];

  char* ws = (char*)d_ws;
  size_t off = 0;
  auto alloc = [&](size_t bytes)->char*{
    char* p = ws + off; off += (bytes + 1023) & ~((size_t)1023); return p;
  };
  unsigned short* xb    = (unsigned short*)alloc((size_t)M1_*C_*2);
  unsigned short* yball = (unsigned short*)alloc((size_t)3*M2_*C_*2);
  unsigned short* wqb   = (unsigned short*)alloc((size_t)C_*C_*2);
  unsigned short* wkb   = (unsigned short*)alloc((size_t)3*C_*C_*2);
  unsigned short* wvb   = (unsigned short*)alloc((size_t)3*C_*C_*2);
  unsigned short* wob   = (unsigned short*)alloc((size_t)C_*C_*2);
  unsigned short* qb    = (unsigned short*)alloc((size_t)M1_*C_*2);
  unsigned short* kb    = (unsigned short*)alloc((size_t)3*M2_*C_*2);
  unsigned short* vb    = (unsigned short*)alloc((size_t)3*M2_*C_*2);
  float*          ksum  = (float*)alloc((size_t)3*B_*C_*4);
  float*          part  = (float*)alloc((size_t)3*8*32*4096*4);
  unsigned short* ctxTb = (unsigned short*)alloc((size_t)3*32*4096*2);
  unsigned short* omid  = (unsigned short*)alloc((size_t)M1_*C_*2);

  (void)hipMemsetAsync(ksum, 0, (size_t)3*B_*C_*4, stream);

  cvt_bf16_4<<<dim3(M1_*C_/4/256, 4), 256, 0, stream>>>(
      x, y0, y1, y2, xb, yball, yball + (size_t)M2_*C_, yball + (size_t)2*M2_*C_,
      M1_*C_/4, M2_*C_/4, M2_*C_/4, M2_*C_/4);
  cvt_bf16_4<<<dim3(3*C_*C_/4/256, 4), 256, 0, stream>>>(
      Wq, Wk, Wv, Wo, wqb, wkb, wvb, wob,
      C_*C_/4, 3*C_*C_/4, 3*C_*C_/4, C_*C_/4);

  proj<<<2048, 256, 0, stream>>>(xb, yball, wqb, wkb, wvb, bq, bk, bv, qb, kb, vb, ksum);
  ctx_partial<<<dim3(32, 8, 3), 256, 0, stream>>>(kb, vb, part);
  ctx_reduce<<<dim3(32, 3), 256, 0, stream>>>(part, ctxTb);
  combine<<<512, 256, 0, stream>>>(qb, ctxTb, ksum, omid);
  gemm_bt<<<512, 256, 0, stream>>>(omid, wob, bo, (float*)d_out);
}

// Round 8
// 161.680 us; speedup vs baseline: 2.4124x; 1.0730x over previous
//
#include <hip/hip_runtime.h>
#include <stdint.h>

#define B_ 4
#define T1_ 4096
#define T2_ 2048
#define C_ 512
#define H_ 8
#define D_ 64
#define M1_ (B_*T1_)   // 16384
#define M2_ (B_*T2_)   // 8192

using f32x4 = __attribute__((ext_vector_type(4))) float;
using bf16x8 = __attribute__((ext_vector_type(8))) __bf16;
using us8 = __attribute__((ext_vector_type(8))) unsigned short;
using us4 = __attribute__((ext_vector_type(4))) unsigned short;

__device__ __forceinline__ unsigned short f2bf(float f){
  unsigned int u = __builtin_bit_cast(unsigned int, f);
  unsigned int r = (u + 0x7fffu + ((u >> 16) & 1u)) >> 16;
  return (unsigned short)r;
}
__device__ __forceinline__ float bf2f(unsigned short u){
  return __builtin_bit_cast(float, ((unsigned int)u) << 16);
}
__device__ __forceinline__ f32x4 mfma16(us8 a, us8 b, f32x4 c){
  return __builtin_amdgcn_mfma_f32_16x16x32_bf16(
      __builtin_bit_cast(bf16x8, a), __builtin_bit_cast(bf16x8, b), c, 0, 0, 0);
}

typedef const __attribute__((address_space(1))) unsigned int gu32;
typedef __attribute__((address_space(3))) unsigned int lu32;
__device__ __forceinline__ void gl_lds16(const void* g, void* l){
  __builtin_amdgcn_global_load_lds((gu32*)g, (lu32*)l, 16, 0, 0);
}

#define WAIT_VM(N) asm volatile("s_waitcnt vmcnt(" #N ")" ::: "memory")
#define RAW_BAR()  { __builtin_amdgcn_s_barrier(); __builtin_amdgcn_sched_barrier(0); }

// chunk swizzle for the K-loop staging (involution, rule 21)
__device__ __forceinline__ int swz(int row, int blk){ return blk ^ ((row >> 1) & 3); }

// ---------------- fused fp32 -> bf16 convert (4 sources per launch) ----------------
__global__ __launch_bounds__(256) void cvt_bf16_4(const float* __restrict__ p0, const float* __restrict__ p1,
                                                  const float* __restrict__ p2, const float* __restrict__ p3,
                                                  unsigned short* o0, unsigned short* o1,
                                                  unsigned short* o2, unsigned short* o3,
                                                  int n0, int n1, int n2, int n3){
  const float* in; unsigned short* out; int n4;
  switch (blockIdx.y){
    case 0: in = p0; out = o0; n4 = n0; break;
    case 1: in = p1; out = o1; n4 = n1; break;
    case 2: in = p2; out = o2; n4 = n2; break;
    default: in = p3; out = o3; n4 = n3; break;
  }
  int i = blockIdx.x * 256 + threadIdx.x;
  if (i >= n4) return;
  f32x4 v = ((const f32x4*)in)[i];
  us4 o;
  #pragma unroll
  for (int j = 0; j < 4; ++j) o[j] = f2bf(v[j]);
  ((us4*)out)[i] = o;
}

// ---------- C-layout fp32 vals -> swizzled bf16 LDS tile -> coalesced store ----------
__device__ __forceinline__ void tile_write(unsigned short* tile, const f32x4 (&vals)[4][4],
                                           int wr, int wc, int lr, int lk){
  #pragma unroll
  for (int mt = 0; mt < 4; ++mt)
    #pragma unroll
    for (int nt = 0; nt < 4; ++nt)
      #pragma unroll
      for (int r = 0; r < 4; ++r){
        int row = wr*64 + mt*16 + lk*4 + r;
        int cb  = (wc*128 + nt*32 + lr*2) ^ ((row & 7) << 4);
        *(unsigned short*)((char*)tile + row*256 + cb) = f2bf(vals[mt][nt][r]);
      }
}
__device__ __forceinline__ void tile_flush(const unsigned short* tile, unsigned short* g,
                                           size_t row0, int col0, int ldg, int t){
  #pragma unroll
  for (int p = 0; p < 8; ++p){
    int row = p*16 + (t >> 4);
    int cb  = ((t & 15) * 16) ^ ((row & 7) << 4);
    us8 v = *(const us8*)((const char*)tile + row*256 + cb);
    *(us8*)(g + (row0 + row) * (size_t)ldg + col0 + (t & 15) * 8) = v;
  }
}
// transpose flush: tile[row=n][col=ch] -> gT[(ch0+ch)][n_base+n], 256B runs per 16-lane group
__device__ __forceinline__ void tile_flush_T(const unsigned short* tile, unsigned short* gT,
                                             size_t ch0, int n_base, int t){
  const int chunk = t & 15, nl = chunk * 8;
  #pragma unroll
  for (int pass = 0; pass < 8; ++pass){
    int cl = pass*16 + (t >> 4);
    us8 v;
    #pragma unroll
    for (int j = 0; j < 8; ++j){
      int row = nl + j;
      v[j] = *(const unsigned short*)((const char*)tile + row*256 + ((cl*2) ^ ((row & 7) << 4)));
    }
    *(us8*)(gT + (ch0 + cl) * (size_t)T2_ + n_base + nl) = v;
  }
}

// ================= merged projection kernel: Q (+softmax), K (+softmax+ksum, ->kbT), V (->vbT) ======
// grid 2048 x 256thr, 48 KB LDS -> 3 blocks/CU.
// work order groups all n-tiles (and the K/V pair) of one A-panel adjacently for L2 reuse.
__global__ __launch_bounds__(256, 3) void proj(const unsigned short* __restrict__ xb,
                                               const unsigned short* __restrict__ yball,
                                               const unsigned short* __restrict__ wqb,
                                               const unsigned short* __restrict__ wkb,
                                               const unsigned short* __restrict__ wvb,
                                               const float* __restrict__ bq,
                                               const float* __restrict__ bk,
                                               const float* __restrict__ bv,
                                               unsigned short* __restrict__ qb,
                                               unsigned short* __restrict__ kbT,
                                               unsigned short* __restrict__ vbT,
                                               float* __restrict__ ksum){
  __shared__ unsigned short smem[3*2*4096];    // 48 KB staging; 32 KB repack tile aliases
  // XCD-chunked bijective swizzle (nwg=2048, cpx=256): consecutive works -> same XCD
  const int hw = blockIdx.x;
  const int work = (hw & 7) * 256 + (hw >> 3);
  int seg, ii, m0, n0;
  const unsigned short *A, *W;
  const float* bias;
  if (work < 512){
    // Q: 128 m-groups x 4 n  (A-panel shared by 4 consecutive works)
    seg = 0; ii = 0;
    m0 = (work >> 2) << 7; n0 = (work & 3) << 7;
    A = xb; W = wqb; bias = bq;
  } else {
    // K/V: 192 (i,m)-groups x 8 {K n0..3, V n0..3} (y-panel shared by 8 consecutive works)
    int r = work - 512;
    int g = r >> 3, s = r & 7;
    ii = g >> 6; m0 = (g & 63) << 7;
    seg = (s < 4) ? 1 : 2;
    n0 = (s & 3) << 7;
    A = yball + (size_t)ii*M2_*C_;
    W = (seg == 1 ? wkb : wvb) + (size_t)ii*C_*C_;
    bias = (seg == 1 ? bk : bv) + (size_t)ii*C_;
  }
  const int t = threadIdx.x;
  const int w = t >> 6, l = t & 63;
  const int wr = w >> 1, wc = w & 1;
  const int lr = l & 15, lk = l >> 4;
  f32x4 acc[4][4] = {};
  auto STAGE = [&](int bb, int k0){
    int c = t, row = c >> 2;
    gl_lds16(A + (size_t)(m0+row)*C_ + k0 + swz(row, c & 3)*8, &smem[bb*8192 + c*8]);
    gl_lds16(W + (size_t)(n0+row)*C_ + k0 + swz(row, c & 3)*8, &smem[bb*8192 + 4096 + c*8]);
    c = t + 256; row = c >> 2;
    gl_lds16(A + (size_t)(m0+row)*C_ + k0 + swz(row, c & 3)*8, &smem[bb*8192 + c*8]);
    gl_lds16(W + (size_t)(n0+row)*C_ + k0 + swz(row, c & 3)*8, &smem[bb*8192 + 4096 + c*8]);
  };
  auto COMPUTE = [&](int bb){
    const unsigned short* sA = &smem[bb*8192];
    const unsigned short* sB = &smem[bb*8192 + 4096];
    us8 af[4], bfr[4];
    #pragma unroll
    for (int mt = 0; mt < 4; ++mt){
      int R = wr*64 + mt*16 + lr;
      af[mt] = *(const us8*)&sA[R*32 + swz(R, lk)*8];
    }
    #pragma unroll
    for (int nt = 0; nt < 4; ++nt){
      int R = wc*64 + nt*16 + lr;
      bfr[nt] = *(const us8*)&sB[R*32 + swz(R, lk)*8];
    }
    __builtin_amdgcn_s_setprio(1);
    #pragma unroll
    for (int mt = 0; mt < 4; ++mt)
      #pragma unroll
      for (int nt = 0; nt < 4; ++nt)
        acc[mt][nt] = mfma16(af[mt], bfr[nt], acc[mt][nt]);
    __builtin_amdgcn_s_setprio(0);
  };
  STAGE(0, 0);
  int cur = 0;
  for (int tt = 0; tt < 15; ++tt){
    int nxt = (cur == 2) ? 0 : cur + 1;
    STAGE(nxt, (tt + 1) * 32);
    WAIT_VM(4);
    RAW_BAR();
    COMPUTE(cur);
    cur = nxt;
  }
  WAIT_VM(0);
  RAW_BAR();
  COMPUTE(cur);
  // bias
  {
    float bc[4];
    #pragma unroll
    for (int nt = 0; nt < 4; ++nt) bc[nt] = bias[n0 + wc*64 + nt*16 + lr];
    #pragma unroll
    for (int mt = 0; mt < 4; ++mt)
      #pragma unroll
      for (int nt = 0; nt < 4; ++nt)
        #pragma unroll
        for (int r = 0; r < 4; ++r) acc[mt][nt][r] += bc[nt];
  }
  if (seg <= 1){
    // in-register softmax over the wave's 64-col head group
    #pragma unroll
    for (int mt = 0; mt < 4; ++mt)
      #pragma unroll
      for (int r = 0; r < 4; ++r){
        float m = fmaxf(fmaxf(acc[mt][0][r], acc[mt][1][r]), fmaxf(acc[mt][2][r], acc[mt][3][r]));
        #pragma unroll
        for (int s = 1; s < 16; s <<= 1) m = fmaxf(m, __shfl_xor(m, s, 64));
        float sum = 0.f;
        #pragma unroll
        for (int nt = 0; nt < 4; ++nt){
          float e = __expf(acc[mt][nt][r] - m);
          acc[mt][nt][r] = e; sum += e;
        }
        #pragma unroll
        for (int s = 1; s < 16; s <<= 1) sum += __shfl_xor(sum, s, 64);
        float inv = 1.0f / sum;
        #pragma unroll
        for (int nt = 0; nt < 4; ++nt) acc[mt][nt][r] *= inv;
      }
  }
  if (seg == 1){
    // colsum -> ksum atomics
    const int b = m0 >> 11;
    #pragma unroll
    for (int nt = 0; nt < 4; ++nt){
      float cs = 0.f;
      #pragma unroll
      for (int mt = 0; mt < 4; ++mt)
        #pragma unroll
        for (int r = 0; r < 4; ++r) cs += acc[mt][nt][r];
      cs += __shfl_xor(cs, 16, 64);
      cs += __shfl_xor(cs, 32, 64);
      if (lk == 0)
        atomicAdd(&ksum[((size_t)ii*B_ + b)*C_ + n0 + wc*64 + nt*16 + lr], cs);
    }
  }
  __syncthreads();
  tile_write(smem, acc, wr, wc, lr, lk);
  __syncthreads();
  if (seg == 0){
    tile_flush(smem, qb, m0, n0, C_, t);
  } else {
    const int b = m0 >> 11;
    const int n_base = m0 & 2047;
    unsigned short* gT = (seg == 1 ? kbT : vbT);
    tile_flush_T(smem, gT, ((size_t)ii*B_ + b)*C_ + n0, n_base, t);
  }
}

// ================= ctx via MFMA: part[i][kc][bh][e*64+d] = sum_n k[n,d] v[n,e] =================
// kbT/vbT are [ (i*B+b)*C + ch ][ n ] row-major over n. grid (32 bh, 8 kc, 3 i) x 256 thr.
__global__ __launch_bounds__(256) void ctx_mfma(const unsigned short* __restrict__ kbT,
                                                const unsigned short* __restrict__ vbT,
                                                float* __restrict__ part){
  const int bh = blockIdx.x, kc = blockIdx.y, i = blockIdx.z;
  const int b = bh >> 3, h = bh & 7;
  const size_t rowbase = ((size_t)i*B_ + b)*C_ + h*64;
  const unsigned short* kT = kbT + rowbase*T2_;
  const unsigned short* vT = vbT + rowbase*T2_;
  const int t = threadIdx.x;
  const int w = t >> 6, l = t & 63;
  const int qr = w >> 1, qc = w & 1;     // 32x32 quadrant per wave
  const int lr = l & 15, lk = l >> 4;
  const int n00 = kc * 256;
  f32x4 acc[2][2] = {};
  #pragma unroll
  for (int it = 0; it < 8; ++it){
    const int k0 = n00 + it*32 + lk*8;
    us8 a0 = *(const us8*)(kT + (size_t)(qr*32 +      lr)*T2_ + k0);
    us8 a1 = *(const us8*)(kT + (size_t)(qr*32 + 16 + lr)*T2_ + k0);
    us8 b0 = *(const us8*)(vT + (size_t)(qc*32 +      lr)*T2_ + k0);
    us8 b1 = *(const us8*)(vT + (size_t)(qc*32 + 16 + lr)*T2_ + k0);
    acc[0][0] = mfma16(a0, b0, acc[0][0]);
    acc[0][1] = mfma16(a0, b1, acc[0][1]);
    acc[1][0] = mfma16(a1, b0, acc[1][0]);
    acc[1][1] = mfma16(a1, b1, acc[1][1]);
  }
  float* dst = part + (((size_t)i*8 + kc)*32 + bh)*4096;
  #pragma unroll
  for (int fa = 0; fa < 2; ++fa)
    #pragma unroll
    for (int fb = 0; fb < 2; ++fb){
      int d0 = qr*32 + fa*16 + lk*4;
      int e  = qc*32 + fb*16 + lr;
      *(f32x4*)(dst + e*64 + d0) = acc[fa][fb];
    }
}

__global__ __launch_bounds__(256) void ctx_reduce(const float* __restrict__ part,
                                                  unsigned short* __restrict__ ctxTb){
  const int bh = blockIdx.x, i = blockIdx.y, t = threadIdx.x;
  for (int idx = t; idx < 4096; idx += 256){
    float s = 0.f;
    #pragma unroll
    for (int kc = 0; kc < 8; ++kc)
      s += part[(((size_t)i*8 + kc)*32 + bh)*4096 + idx];
    ctxTb[((size_t)i*32 + bh)*4096 + idx] = f2bf(s);
  }
}

// ================= combine: omid = q + sum_i (q @ ctx_i) * Dinv_i =================
__global__ __launch_bounds__(256) void combine(const unsigned short* __restrict__ qb,
                                               const unsigned short* __restrict__ ctxTb,
                                               const float* __restrict__ ksum,
                                               unsigned short* __restrict__ omid){
  __shared__ unsigned short tile[128*128];     // 32 KB
  const int hw = blockIdx.x;
  const int work = (hw & 7) * 64 + (hw >> 3);  // nwg=512, cpx=64
  const int m0 = (work & 127) << 7, n0 = (work >> 7) << 7;
  const int t = threadIdx.x;
  const int w = t >> 6, l = t & 63;
  const int wr = w >> 1, wc = w & 1;
  const int lr = l & 15, lk = l >> 4;
  const int b = m0 >> 12;
  const int bh = b*8 + (n0 >> 6) + wc;
  // stage q[128 x 128] with per-row chunk XOR on the SOURCE (LDS linear)
  #pragma unroll
  for (int p = 0; p < 8; ++p){
    int idx = p*256 + t;
    int row = idx >> 4, ch = idx & 15;
    gl_lds16(qb + (size_t)(m0+row)*C_ + n0 + (ch ^ (row & 7))*8, &tile[idx*8]);
  }
  WAIT_VM(0);
  __syncthreads();
  // A-frags (swizzled read)
  us8 afr[4][2];
  #pragma unroll
  for (int mt = 0; mt < 4; ++mt)
    #pragma unroll
    for (int kk = 0; kk < 2; ++kk){
      int row = wr*64 + mt*16 + lr;
      int ch = wc*8 + kk*4 + lk;
      afr[mt][kk] = *(const us8*)((const char*)tile + row*256 + ((ch ^ (row & 7)) << 4));
    }
  // acc init = q values in C layout (scalar swizzled reads)
  f32x4 acc[4][4];
  #pragma unroll
  for (int mt = 0; mt < 4; ++mt)
    #pragma unroll
    for (int nt = 0; nt < 4; ++nt)
      #pragma unroll
      for (int r = 0; r < 4; ++r){
        int row = wr*64 + mt*16 + lk*4 + r;
        int cbyte = wc*128 + nt*32 + lr*2;
        int ch = cbyte >> 4;
        unsigned short v = *(const unsigned short*)((const char*)tile + row*256 +
                            ((ch ^ (row & 7)) << 4) + (cbyte & 15));
        acc[mt][nt][r] = bf2f(v);
      }
  // denominator MFMA: B rows 0..2 = ksum_i over this head's 64 channels
  us8 bden[2];
  #pragma unroll
  for (int kk = 0; kk < 2; ++kk){
    us8 tmp = {};
    if (lr < 3){
      const float* kp = ksum + ((size_t)lr*B_ + b)*C_ + n0 + wc*64 + kk*32 + lk*8;
      f32x4 c0 = *(const f32x4*)kp;
      f32x4 c1 = *(const f32x4*)(kp + 4);
      #pragma unroll
      for (int j = 0; j < 4; ++j){ tmp[j] = f2bf(c0[j]); tmp[4+j] = f2bf(c1[j]); }
    }
    bden[kk] = tmp;
  }
  f32x4 den[4] = {};
  #pragma unroll
  for (int mt = 0; mt < 4; ++mt)
    #pragma unroll
    for (int kk = 0; kk < 2; ++kk)
      den[mt] = mfma16(afr[mt][kk], bden[kk], den[mt]);
  // per-i: q@ctxT_i, fold with Dinv (all inner loops fully unrolled)
  #pragma unroll 1
  for (int i = 0; i < 3; ++i){
    f32x4 dinv[4];
    #pragma unroll
    for (int mt = 0; mt < 4; ++mt)
      #pragma unroll
      for (int r = 0; r < 4; ++r)
        dinv[mt][r] = 1.0f / (__shfl(den[mt][r], (l & 48) | i, 64) + 1e-8f);
    #pragma unroll
    for (int nt = 0; nt < 4; ++nt){
      us8 bfr[2];
      #pragma unroll
      for (int kk = 0; kk < 2; ++kk)
        bfr[kk] = *(const us8*)(ctxTb + ((size_t)(i*32 + bh))*4096 + (nt*16 + lr)*64 + kk*32 + lk*8);
      f32x4 p[4] = {};
      #pragma unroll
      for (int mt = 0; mt < 4; ++mt)
        #pragma unroll
        for (int kk = 0; kk < 2; ++kk)
          p[mt] = mfma16(afr[mt][kk], bfr[kk], p[mt]);
      #pragma unroll
      for (int mt = 0; mt < 4; ++mt)
        #pragma unroll
        for (int r = 0; r < 4; ++r)
          acc[mt][nt][r] += p[mt][r] * dinv[mt][r];
    }
  }
  __syncthreads();
  tile_write(tile, acc, wr, wc, lr, lk);
  __syncthreads();
  tile_flush(tile, omid, m0, n0, C_, t);
}

// ---------------- O-proj GEMM (3-buf counted-vmcnt, 1D grid + XCD swizzle) ----------------
__global__ __launch_bounds__(256, 3) void gemm_bt(const unsigned short* __restrict__ A,
                                                  const unsigned short* __restrict__ Bw,
                                                  const float* __restrict__ bias,
                                                  float* __restrict__ out){
  __shared__ unsigned short smem[3*2*4096];
  const int hw = blockIdx.x;
  const int work = (hw & 7) * 64 + (hw >> 3);  // nwg=512, cpx=64
  const int m0 = ((work >> 2) & 127) << 7, n0 = (work & 3) << 7;
  const int t = threadIdx.x;
  const int w = t >> 6, l = t & 63;
  const int wr = w >> 1, wc = w & 1;
  const int lr = l & 15, lk = l >> 4;
  f32x4 acc[4][4] = {};
  auto STAGE = [&](int bb, int k0){
    int c = t, row = c >> 2;
    gl_lds16(A  + (size_t)(m0+row)*C_ + k0 + swz(row, c & 3)*8, &smem[bb*8192 + c*8]);
    gl_lds16(Bw + (size_t)(n0+row)*C_ + k0 + swz(row, c & 3)*8, &smem[bb*8192 + 4096 + c*8]);
    c = t + 256; row = c >> 2;
    gl_lds16(A  + (size_t)(m0+row)*C_ + k0 + swz(row, c & 3)*8, &smem[bb*8192 + c*8]);
    gl_lds16(Bw + (size_t)(n0+row)*C_ + k0 + swz(row, c & 3)*8, &smem[bb*8192 + 4096 + c*8]);
  };
  auto COMPUTE = [&](int bb){
    const unsigned short* sA = &smem[bb*8192];
    const unsigned short* sB = &smem[bb*8192 + 4096];
    us8 af[4], bfr[4];
    #pragma unroll
    for (int mt = 0; mt < 4; ++mt){
      int R = wr*64 + mt*16 + lr;
      af[mt] = *(const us8*)&sA[R*32 + swz(R, lk)*8];
    }
    #pragma unroll
    for (int nt = 0; nt < 4; ++nt){
      int R = wc*64 + nt*16 + lr;
      bfr[nt] = *(const us8*)&sB[R*32 + swz(R, lk)*8];
    }
    __builtin_amdgcn_s_setprio(1);
    #pragma unroll
    for (int mt = 0; mt < 4; ++mt)
      #pragma unroll
      for (int nt = 0; nt < 4; ++nt)
        acc[mt][nt] = mfma16(af[mt], bfr[nt], acc[mt][nt]);
    __builtin_amdgcn_s_setprio(0);
  };
  STAGE(0, 0);
  int cur = 0;
  for (int tt = 0; tt < 15; ++tt){
    int nxt = (cur == 2) ? 0 : cur + 1;
    STAGE(nxt, (tt + 1) * 32);
    WAIT_VM(4);
    RAW_BAR();
    COMPUTE(cur);
    cur = nxt;
  }
  WAIT_VM(0);
  RAW_BAR();
  COMPUTE(cur);
  #pragma unroll
  for (int mt = 0; mt < 4; ++mt)
    #pragma unroll
    for (int nt = 0; nt < 4; ++nt)
      #pragma unroll
      for (int r = 0; r < 4; ++r){
        int row = m0 + wr*64 + mt*16 + lk*4 + r;
        int col = n0 + wc*64 + nt*16 + lr;
        out[(size_t)row*C_ + col] = acc[mt][nt][r] + bias[col];
      }
}

extern "C" void kernel_launch(void* const* d_in, const int* in_sizes, int n_in,
                              void* d_out, int out_size, void* d_ws, size_t ws_size,
                              hipStream_t stream){
  const float* x  = (const float*)d_in[0];
  const float* y0 = (const float*)d_in[1];
  const float* y1 = (const float*)d_in[2];
  const float* y2 = (const float*)d_in[3];
  const float* Wq = (const float*)d_in[4];
  const float* bq = (const float*)d_in[5];
  const float* Wk = (const float*)d_in[6];
  const float* bk = (const float*)d_in[7];
  const float* Wv = (const float*)d_in[8];
  const float* bv = (const float*)d_in[9];
  const float* Wo = (const float*)d_in[10];
  const float* bo = (const float*)d_in[11];

  char* ws = (char*)d_ws;
  size_t off = 0;
  auto alloc = [&](size_t bytes)->char*{
    char* p = ws + off; off += (bytes + 1023) & ~((size_t)1023); return p;
  };
  unsigned short* xb    = (unsigned short*)alloc((size_t)M1_*C_*2);
  unsigned short* yball = (unsigned short*)alloc((size_t)3*M2_*C_*2);
  unsigned short* wqb   = (unsigned short*)alloc((size_t)C_*C_*2);
  unsigned short* wkb   = (unsigned short*)alloc((size_t)3*C_*C_*2);
  unsigned short* wvb   = (unsigned short*)alloc((size_t)3*C_*C_*2);
  unsigned short* wob   = (unsigned short*)alloc((size_t)C_*C_*2);
  unsigned short* qb    = (unsigned short*)alloc((size_t)M1_*C_*2);
  unsigned short* kbT   = (unsigned short*)alloc((size_t)3*B_*C_*T2_*2);
  unsigned short* vbT   = (unsigned short*)alloc((size_t)3*B_*C_*T2_*2);
  float*          ksum  = (float*)alloc((size_t)3*B_*C_*4);
  float*          part  = (float*)alloc((size_t)3*8*32*4096*4);
  unsigned short* ctxTb = (unsigned short*)alloc((size_t)3*32*4096*2);
  unsigned short* omid  = (unsigned short*)alloc((size_t)M1_*C_*2);

  (void)hipMemsetAsync(ksum, 0, (size_t)3*B_*C_*4, stream);

  cvt_bf16_4<<<dim3(M1_*C_/4/256, 4), 256, 0, stream>>>(
      x, y0, y1, y2, xb, yball, yball + (size_t)M2_*C_, yball + (size_t)2*M2_*C_,
      M1_*C_/4, M2_*C_/4, M2_*C_/4, M2_*C_/4);
  cvt_bf16_4<<<dim3(3*C_*C_/4/256, 4), 256, 0, stream>>>(
      Wq, Wk, Wv, Wo, wqb, wkb, wvb, wob,
      C_*C_/4, 3*C_*C_/4, 3*C_*C_/4, C_*C_/4);

  proj<<<2048, 256, 0, stream>>>(xb, yball, wqb, wkb, wvb, bq, bk, bv, qb, kbT, vbT, ksum);
  ctx_mfma<<<dim3(32, 8, 3), 256, 0, stream>>>(kbT, vbT, part);
  ctx_reduce<<<dim3(32, 3), 256, 0, stream>>>(part, ctxTb);
  combine<<<512, 256, 0, stream>>>(qb, ctxTb, ksum, omid);
  gemm_bt<<<512, 256, 0, stream>>>(omid, wob, bo, (float*)d_out);
}

// Round 9
// 141.760 us; speedup vs baseline: 2.7513x; 1.1405x over previous
//
#include <hip/hip_runtime.h>
#include <stdint.h>

#define B_ 4
#define T1_ 4096
#define T2_ 2048
#define C_ 512
#define H_ 8
#define D_ 64
#define M1_ (B_*T1_)   // 16384
#define M2_ (B_*T2_)   // 8192

using f32x4 = __attribute__((ext_vector_type(4))) float;
using bf16x8 = __attribute__((ext_vector_type(8))) __bf16;
using us8 = __attribute__((ext_vector_type(8))) unsigned short;
using us4 = __attribute__((ext_vector_type(4))) unsigned short;

__device__ __forceinline__ unsigned short f2bf(float f){
  unsigned int u = __builtin_bit_cast(unsigned int, f);
  unsigned int r = (u + 0x7fffu + ((u >> 16) & 1u)) >> 16;
  return (unsigned short)r;
}
__device__ __forceinline__ float bf2f(unsigned short u){
  return __builtin_bit_cast(float, ((unsigned int)u) << 16);
}
__device__ __forceinline__ f32x4 mfma16(us8 a, us8 b, f32x4 c){
  return __builtin_amdgcn_mfma_f32_16x16x32_bf16(
      __builtin_bit_cast(bf16x8, a), __builtin_bit_cast(bf16x8, b), c, 0, 0, 0);
}

typedef const __attribute__((address_space(1))) unsigned int gu32;
typedef __attribute__((address_space(3))) unsigned int lu32;
__device__ __forceinline__ void gl_lds16(const void* g, void* l){
  __builtin_amdgcn_global_load_lds((gu32*)g, (lu32*)l, 16, 0, 0);
}

#define WAIT_VM(N) asm volatile("s_waitcnt vmcnt(" #N ")" ::: "memory")
#define RAW_BAR()  { __builtin_amdgcn_s_barrier(); __builtin_amdgcn_sched_barrier(0); }

// chunk swizzle for the K-loop staging (involution, rule 21)
__device__ __forceinline__ int swz(int row, int blk){ return blk ^ ((row >> 1) & 3); }

// ---------------- fused fp32 -> bf16 convert (4 sources per launch) ----------------
__global__ __launch_bounds__(256) void cvt_bf16_4(const float* __restrict__ p0, const float* __restrict__ p1,
                                                  const float* __restrict__ p2, const float* __restrict__ p3,
                                                  unsigned short* o0, unsigned short* o1,
                                                  unsigned short* o2, unsigned short* o3,
                                                  int n0, int n1, int n2, int n3){
  const float* in; unsigned short* out; int n4;
  switch (blockIdx.y){
    case 0: in = p0; out = o0; n4 = n0; break;
    case 1: in = p1; out = o1; n4 = n1; break;
    case 2: in = p2; out = o2; n4 = n2; break;
    default: in = p3; out = o3; n4 = n3; break;
  }
  int i = blockIdx.x * 256 + threadIdx.x;
  if (i >= n4) return;
  f32x4 v = ((const f32x4*)in)[i];
  us4 o;
  #pragma unroll
  for (int j = 0; j < 4; ++j) o[j] = f2bf(v[j]);
  ((us4*)out)[i] = o;
}

// ---------- C-layout fp32 vals -> swizzled bf16 LDS tile -> coalesced store ----------
__device__ __forceinline__ void tile_write(unsigned short* tile, const f32x4 (&vals)[4][4],
                                           int wr, int wc, int lr, int lk){
  #pragma unroll
  for (int mt = 0; mt < 4; ++mt)
    #pragma unroll
    for (int nt = 0; nt < 4; ++nt)
      #pragma unroll
      for (int r = 0; r < 4; ++r){
        int row = wr*64 + mt*16 + lk*4 + r;
        int cb  = (wc*128 + nt*32 + lr*2) ^ ((row & 7) << 4);
        *(unsigned short*)((char*)tile + row*256 + cb) = f2bf(vals[mt][nt][r]);
      }
}
// transposed write: value for output (row=ch, col=n) -> tile[ch][n] (same swizzle family)
__device__ __forceinline__ void tile_write_T(unsigned short* tile, const f32x4 (&vals)[4][4],
                                             int wr, int wc, int lr, int lk){
  #pragma unroll
  for (int mt = 0; mt < 4; ++mt)
    #pragma unroll
    for (int nt = 0; nt < 4; ++nt)
      #pragma unroll
      for (int r = 0; r < 4; ++r){
        int n  = wr*64 + mt*16 + lk*4 + r;     // output column (time index)
        int ch = wc*64 + nt*16 + lr;           // output row (channel)
        int cb = (n*2) ^ ((ch & 7) << 4);
        *(unsigned short*)((char*)tile + ch*256 + cb) = f2bf(vals[mt][nt][r]);
      }
}
__device__ __forceinline__ void tile_flush(const unsigned short* tile, unsigned short* g,
                                           size_t row0, int col0, int ldg, int t){
  #pragma unroll
  for (int p = 0; p < 8; ++p){
    int row = p*16 + (t >> 4);
    int cb  = ((t & 15) * 16) ^ ((row & 7) << 4);
    us8 v = *(const us8*)((const char*)tile + row*256 + cb);
    *(us8*)(g + (row0 + row) * (size_t)ldg + col0 + (t & 15) * 8) = v;
  }
}

// ================= merged projection kernel: Q (+softmax), K (+softmax+ksum, ->kbT), V (->vbT) ======
// grid 2048 x 256thr, 48 KB LDS -> 3 blocks/CU.
// work order groups all n-tiles (and the K/V pair) of one A-panel adjacently for L2 reuse.
__global__ __launch_bounds__(256, 3) void proj(const unsigned short* __restrict__ xb,
                                               const unsigned short* __restrict__ yball,
                                               const unsigned short* __restrict__ wqb,
                                               const unsigned short* __restrict__ wkb,
                                               const unsigned short* __restrict__ wvb,
                                               const float* __restrict__ bq,
                                               const float* __restrict__ bk,
                                               const float* __restrict__ bv,
                                               unsigned short* __restrict__ qb,
                                               unsigned short* __restrict__ kbT,
                                               unsigned short* __restrict__ vbT,
                                               float* __restrict__ ksum){
  __shared__ unsigned short smem[3*2*4096];    // 48 KB staging; 32 KB repack tile aliases
  // XCD-chunked bijective swizzle (nwg=2048, cpx=256): consecutive works -> same XCD
  const int hw = blockIdx.x;
  const int work = (hw & 7) * 256 + (hw >> 3);
  int seg, ii, m0, n0;
  const unsigned short *A, *W;
  const float* bias;
  if (work < 512){
    // Q: 128 m-groups x 4 n  (A-panel shared by 4 consecutive works)
    seg = 0; ii = 0;
    m0 = (work >> 2) << 7; n0 = (work & 3) << 7;
    A = xb; W = wqb; bias = bq;
  } else {
    // K/V: 192 (i,m)-groups x 8 {K n0..3, V n0..3} (y-panel shared by 8 consecutive works)
    int r = work - 512;
    int g = r >> 3, s = r & 7;
    ii = g >> 6; m0 = (g & 63) << 7;
    seg = (s < 4) ? 1 : 2;
    n0 = (s & 3) << 7;
    A = yball + (size_t)ii*M2_*C_;
    W = (seg == 1 ? wkb : wvb) + (size_t)ii*C_*C_;
    bias = (seg == 1 ? bk : bv) + (size_t)ii*C_;
  }
  const int t = threadIdx.x;
  const int w = t >> 6, l = t & 63;
  const int wr = w >> 1, wc = w & 1;
  const int lr = l & 15, lk = l >> 4;
  f32x4 acc[4][4] = {};
  auto STAGE = [&](int bb, int k0){
    int c = t, row = c >> 2;
    gl_lds16(A + (size_t)(m0+row)*C_ + k0 + swz(row, c & 3)*8, &smem[bb*8192 + c*8]);
    gl_lds16(W + (size_t)(n0+row)*C_ + k0 + swz(row, c & 3)*8, &smem[bb*8192 + 4096 + c*8]);
    c = t + 256; row = c >> 2;
    gl_lds16(A + (size_t)(m0+row)*C_ + k0 + swz(row, c & 3)*8, &smem[bb*8192 + c*8]);
    gl_lds16(W + (size_t)(n0+row)*C_ + k0 + swz(row, c & 3)*8, &smem[bb*8192 + 4096 + c*8]);
  };
  auto COMPUTE = [&](int bb){
    const unsigned short* sA = &smem[bb*8192];
    const unsigned short* sB = &smem[bb*8192 + 4096];
    us8 af[4], bfr[4];
    #pragma unroll
    for (int mt = 0; mt < 4; ++mt){
      int R = wr*64 + mt*16 + lr;
      af[mt] = *(const us8*)&sA[R*32 + swz(R, lk)*8];
    }
    #pragma unroll
    for (int nt = 0; nt < 4; ++nt){
      int R = wc*64 + nt*16 + lr;
      bfr[nt] = *(const us8*)&sB[R*32 + swz(R, lk)*8];
    }
    __builtin_amdgcn_s_setprio(1);
    #pragma unroll
    for (int mt = 0; mt < 4; ++mt)
      #pragma unroll
      for (int nt = 0; nt < 4; ++nt)
        acc[mt][nt] = mfma16(af[mt], bfr[nt], acc[mt][nt]);
    __builtin_amdgcn_s_setprio(0);
  };
  STAGE(0, 0);
  int cur = 0;
  for (int tt = 0; tt < 15; ++tt){
    int nxt = (cur == 2) ? 0 : cur + 1;
    STAGE(nxt, (tt + 1) * 32);
    WAIT_VM(4);
    RAW_BAR();
    COMPUTE(cur);
    cur = nxt;
  }
  WAIT_VM(0);
  RAW_BAR();
  COMPUTE(cur);
  // bias
  {
    float bc[4];
    #pragma unroll
    for (int nt = 0; nt < 4; ++nt) bc[nt] = bias[n0 + wc*64 + nt*16 + lr];
    #pragma unroll
    for (int mt = 0; mt < 4; ++mt)
      #pragma unroll
      for (int nt = 0; nt < 4; ++nt)
        #pragma unroll
        for (int r = 0; r < 4; ++r) acc[mt][nt][r] += bc[nt];
  }
  if (seg <= 1){
    // in-register softmax over the wave's 64-col head group
    #pragma unroll
    for (int mt = 0; mt < 4; ++mt)
      #pragma unroll
      for (int r = 0; r < 4; ++r){
        float m = fmaxf(fmaxf(acc[mt][0][r], acc[mt][1][r]), fmaxf(acc[mt][2][r], acc[mt][3][r]));
        #pragma unroll
        for (int s = 1; s < 16; s <<= 1) m = fmaxf(m, __shfl_xor(m, s, 64));
        float sum = 0.f;
        #pragma unroll
        for (int nt = 0; nt < 4; ++nt){
          float e = __expf(acc[mt][nt][r] - m);
          acc[mt][nt][r] = e; sum += e;
        }
        #pragma unroll
        for (int s = 1; s < 16; s <<= 1) sum += __shfl_xor(sum, s, 64);
        float inv = 1.0f / sum;
        #pragma unroll
        for (int nt = 0; nt < 4; ++nt) acc[mt][nt][r] *= inv;
      }
  }
  if (seg == 1){
    // colsum -> ksum atomics
    const int b = m0 >> 11;
    #pragma unroll
    for (int nt = 0; nt < 4; ++nt){
      float cs = 0.f;
      #pragma unroll
      for (int mt = 0; mt < 4; ++mt)
        #pragma unroll
        for (int r = 0; r < 4; ++r) cs += acc[mt][nt][r];
      cs += __shfl_xor(cs, 16, 64);
      cs += __shfl_xor(cs, 32, 64);
      if (lk == 0)
        atomicAdd(&ksum[((size_t)ii*B_ + b)*C_ + n0 + wc*64 + nt*16 + lr], cs);
    }
  }
  __syncthreads();
  if (seg == 0){
    tile_write(smem, acc, wr, wc, lr, lk);
    __syncthreads();
    tile_flush(smem, qb, m0, n0, C_, t);
  } else {
    // transpose at WRITE side (conflict-free), flush with the standard row-contiguous reader
    tile_write_T(smem, acc, wr, wc, lr, lk);
    __syncthreads();
    const int b = m0 >> 11;
    const int n_base = m0 & 2047;
    unsigned short* gT = (seg == 1 ? kbT : vbT);
    tile_flush(smem, gT, ((size_t)ii*B_ + b)*C_ + n0, n_base, T2_, t);
  }
}

// ================= ctx via MFMA: part[i][kc][bh][e*64+d] = sum_n k[n,d] v[n,e] =================
// kbT/vbT are [ (i*B+b)*C + ch ][ n ] row-major over n. grid (32 bh, 8 kc, 3 i) x 256 thr.
__global__ __launch_bounds__(256) void ctx_mfma(const unsigned short* __restrict__ kbT,
                                                const unsigned short* __restrict__ vbT,
                                                float* __restrict__ part){
  const int bh = blockIdx.x, kc = blockIdx.y, i = blockIdx.z;
  const int b = bh >> 3, h = bh & 7;
  const size_t rowbase = ((size_t)i*B_ + b)*C_ + h*64;
  const unsigned short* kT = kbT + rowbase*T2_;
  const unsigned short* vT = vbT + rowbase*T2_;
  const int t = threadIdx.x;
  const int w = t >> 6, l = t & 63;
  const int qr = w >> 1, qc = w & 1;     // 32x32 quadrant per wave
  const int lr = l & 15, lk = l >> 4;
  const int n00 = kc * 256;
  f32x4 acc[2][2] = {};
  #pragma unroll
  for (int it = 0; it < 8; ++it){
    const int k0 = n00 + it*32 + lk*8;
    us8 a0 = *(const us8*)(kT + (size_t)(qr*32 +      lr)*T2_ + k0);
    us8 a1 = *(const us8*)(kT + (size_t)(qr*32 + 16 + lr)*T2_ + k0);
    us8 b0 = *(const us8*)(vT + (size_t)(qc*32 +      lr)*T2_ + k0);
    us8 b1 = *(const us8*)(vT + (size_t)(qc*32 + 16 + lr)*T2_ + k0);
    acc[0][0] = mfma16(a0, b0, acc[0][0]);
    acc[0][1] = mfma16(a0, b1, acc[0][1]);
    acc[1][0] = mfma16(a1, b0, acc[1][0]);
    acc[1][1] = mfma16(a1, b1, acc[1][1]);
  }
  float* dst = part + (((size_t)i*8 + kc)*32 + bh)*4096;
  #pragma unroll
  for (int fa = 0; fa < 2; ++fa)
    #pragma unroll
    for (int fb = 0; fb < 2; ++fb){
      int d0 = qr*32 + fa*16 + lk*4;
      int e  = qc*32 + fb*16 + lr;
      *(f32x4*)(dst + e*64 + d0) = acc[fa][fb];
    }
}

__global__ __launch_bounds__(256) void ctx_reduce(const float* __restrict__ part,
                                                  unsigned short* __restrict__ ctxTb){
  const int bh = blockIdx.x, i = blockIdx.y, t = threadIdx.x;
  for (int idx = t; idx < 4096; idx += 256){
    float s = 0.f;
    #pragma unroll
    for (int kc = 0; kc < 8; ++kc)
      s += part[(((size_t)i*8 + kc)*32 + bh)*4096 + idx];
    ctxTb[((size_t)i*32 + bh)*4096 + idx] = f2bf(s);
  }
}

// ================= combine: omid = q + sum_i (q @ ctx_i) * Dinv_i =================
__global__ __launch_bounds__(256) void combine(const unsigned short* __restrict__ qb,
                                               const unsigned short* __restrict__ ctxTb,
                                               const float* __restrict__ ksum,
                                               unsigned short* __restrict__ omid){
  __shared__ unsigned short tile[128*128];     // 32 KB
  const int hw = blockIdx.x;
  const int work = (hw & 7) * 64 + (hw >> 3);  // nwg=512, cpx=64
  const int m0 = (work & 127) << 7, n0 = (work >> 7) << 7;
  const int t = threadIdx.x;
  const int w = t >> 6, l = t & 63;
  const int wr = w >> 1, wc = w & 1;
  const int lr = l & 15, lk = l >> 4;
  const int b = m0 >> 12;
  const int bh = b*8 + (n0 >> 6) + wc;
  // stage q[128 x 128] with per-row chunk XOR on the SOURCE (LDS linear)
  #pragma unroll
  for (int p = 0; p < 8; ++p){
    int idx = p*256 + t;
    int row = idx >> 4, ch = idx & 15;
    gl_lds16(qb + (size_t)(m0+row)*C_ + n0 + (ch ^ (row & 7))*8, &tile[idx*8]);
  }
  WAIT_VM(0);
  __syncthreads();
  // A-frags (swizzled read)
  us8 afr[4][2];
  #pragma unroll
  for (int mt = 0; mt < 4; ++mt)
    #pragma unroll
    for (int kk = 0; kk < 2; ++kk){
      int row = wr*64 + mt*16 + lr;
      int ch = wc*8 + kk*4 + lk;
      afr[mt][kk] = *(const us8*)((const char*)tile + row*256 + ((ch ^ (row & 7)) << 4));
    }
  // acc init = q values in C layout (scalar swizzled reads)
  f32x4 acc[4][4];
  #pragma unroll
  for (int mt = 0; mt < 4; ++mt)
    #pragma unroll
    for (int nt = 0; nt < 4; ++nt)
      #pragma unroll
      for (int r = 0; r < 4; ++r){
        int row = wr*64 + mt*16 + lk*4 + r;
        int cbyte = wc*128 + nt*32 + lr*2;
        int ch = cbyte >> 4;
        unsigned short v = *(const unsigned short*)((const char*)tile + row*256 +
                            ((ch ^ (row & 7)) << 4) + (cbyte & 15));
        acc[mt][nt][r] = bf2f(v);
      }
  // denominator MFMA: B rows 0..2 = ksum_i over this head's 64 channels
  us8 bden[2];
  #pragma unroll
  for (int kk = 0; kk < 2; ++kk){
    us8 tmp = {};
    if (lr < 3){
      const float* kp = ksum + ((size_t)lr*B_ + b)*C_ + n0 + wc*64 + kk*32 + lk*8;
      f32x4 c0 = *(const f32x4*)kp;
      f32x4 c1 = *(const f32x4*)(kp + 4);
      #pragma unroll
      for (int j = 0; j < 4; ++j){ tmp[j] = f2bf(c0[j]); tmp[4+j] = f2bf(c1[j]); }
    }
    bden[kk] = tmp;
  }
  f32x4 den[4] = {};
  #pragma unroll
  for (int mt = 0; mt < 4; ++mt)
    #pragma unroll
    for (int kk = 0; kk < 2; ++kk)
      den[mt] = mfma16(afr[mt][kk], bden[kk], den[mt]);
  // per-i: q@ctxT_i, fold with Dinv (all inner loops fully unrolled)
  #pragma unroll 1
  for (int i = 0; i < 3; ++i){
    f32x4 dinv[4];
    #pragma unroll
    for (int mt = 0; mt < 4; ++mt)
      #pragma unroll
      for (int r = 0; r < 4; ++r)
        dinv[mt][r] = 1.0f / (__shfl(den[mt][r], (l & 48) | i, 64) + 1e-8f);
    #pragma unroll
    for (int nt = 0; nt < 4; ++nt){
      us8 bfr[2];
      #pragma unroll
      for (int kk = 0; kk < 2; ++kk)
        bfr[kk] = *(const us8*)(ctxTb + ((size_t)(i*32 + bh))*4096 + (nt*16 + lr)*64 + kk*32 + lk*8);
      f32x4 p[4] = {};
      #pragma unroll
      for (int mt = 0; mt < 4; ++mt)
        #pragma unroll
        for (int kk = 0; kk < 2; ++kk)
          p[mt] = mfma16(afr[mt][kk], bfr[kk], p[mt]);
      #pragma unroll
      for (int mt = 0; mt < 4; ++mt)
        #pragma unroll
        for (int r = 0; r < 4; ++r)
          acc[mt][nt][r] += p[mt][r] * dinv[mt][r];
    }
  }
  __syncthreads();
  tile_write(tile, acc, wr, wc, lr, lk);
  __syncthreads();
  tile_flush(tile, omid, m0, n0, C_, t);
}

// ---------------- O-proj GEMM (3-buf counted-vmcnt, 1D grid + XCD swizzle) ----------------
__global__ __launch_bounds__(256, 3) void gemm_bt(const unsigned short* __restrict__ A,
                                                  const unsigned short* __restrict__ Bw,
                                                  const float* __restrict__ bias,
                                                  float* __restrict__ out){
  __shared__ unsigned short smem[3*2*4096];
  const int hw = blockIdx.x;
  const int work = (hw & 7) * 64 + (hw >> 3);  // nwg=512, cpx=64
  const int m0 = ((work >> 2) & 127) << 7, n0 = (work & 3) << 7;
  const int t = threadIdx.x;
  const int w = t >> 6, l = t & 63;
  const int wr = w >> 1, wc = w & 1;
  const int lr = l & 15, lk = l >> 4;
  f32x4 acc[4][4] = {};
  auto STAGE = [&](int bb, int k0){
    int c = t, row = c >> 2;
    gl_lds16(A  + (size_t)(m0+row)*C_ + k0 + swz(row, c & 3)*8, &smem[bb*8192 + c*8]);
    gl_lds16(Bw + (size_t)(n0+row)*C_ + k0 + swz(row, c & 3)*8, &smem[bb*8192 + 4096 + c*8]);
    c = t + 256; row = c >> 2;
    gl_lds16(A  + (size_t)(m0+row)*C_ + k0 + swz(row, c & 3)*8, &smem[bb*8192 + c*8]);
    gl_lds16(Bw + (size_t)(n0+row)*C_ + k0 + swz(row, c & 3)*8, &smem[bb*8192 + 4096 + c*8]);
  };
  auto COMPUTE = [&](int bb){
    const unsigned short* sA = &smem[bb*8192];
    const unsigned short* sB = &smem[bb*8192 + 4096];
    us8 af[4], bfr[4];
    #pragma unroll
    for (int mt = 0; mt < 4; ++mt){
      int R = wr*64 + mt*16 + lr;
      af[mt] = *(const us8*)&sA[R*32 + swz(R, lk)*8];
    }
    #pragma unroll
    for (int nt = 0; nt < 4; ++nt){
      int R = wc*64 + nt*16 + lr;
      bfr[nt] = *(const us8*)&sB[R*32 + swz(R, lk)*8];
    }
    __builtin_amdgcn_s_setprio(1);
    #pragma unroll
    for (int mt = 0; mt < 4; ++mt)
      #pragma unroll
      for (int nt = 0; nt < 4; ++nt)
        acc[mt][nt] = mfma16(af[mt], bfr[nt], acc[mt][nt]);
    __builtin_amdgcn_s_setprio(0);
  };
  STAGE(0, 0);
  int cur = 0;
  for (int tt = 0; tt < 15; ++tt){
    int nxt = (cur == 2) ? 0 : cur + 1;
    STAGE(nxt, (tt + 1) * 32);
    WAIT_VM(4);
    RAW_BAR();
    COMPUTE(cur);
    cur = nxt;
  }
  WAIT_VM(0);
  RAW_BAR();
  COMPUTE(cur);
  #pragma unroll
  for (int mt = 0; mt < 4; ++mt)
    #pragma unroll
    for (int nt = 0; nt < 4; ++nt)
      #pragma unroll
      for (int r = 0; r < 4; ++r){
        int row = m0 + wr*64 + mt*16 + lk*4 + r;
        int col = n0 + wc*64 + nt*16 + lr;
        out[(size_t)row*C_ + col] = acc[mt][nt][r] + bias[col];
      }
}

extern "C" void kernel_launch(void* const* d_in, const int* in_sizes, int n_in,
                              void* d_out, int out_size, void* d_ws, size_t ws_size,
                              hipStream_t stream){
  const float* x  = (const float*)d_in[0];
  const float* y0 = (const float*)d_in[1];
  const float* y1 = (const float*)d_in[2];
  const float* y2 = (const float*)d_in[3];
  const float* Wq = (const float*)d_in[4];
  const float* bq = (const float*)d_in[5];
  const float* Wk = (const float*)d_in[6];
  const float* bk = (const float*)d_in[7];
  const float* Wv = (const float*)d_in[8];
  const float* bv = (const float*)d_in[9];
  const float* Wo = (const float*)d_in[10];
  const float* bo = (const float*)d_in[11];

  char* ws = (char*)d_ws;
  size_t off = 0;
  auto alloc = [&](size_t bytes)->char*{
    char* p = ws + off; off += (bytes + 1023) & ~((size_t)1023); return p;
  };
  unsigned short* xb    = (unsigned short*)alloc((size_t)M1_*C_*2);
  unsigned short* yball = (unsigned short*)alloc((size_t)3*M2_*C_*2);
  unsigned short* wqb   = (unsigned short*)alloc((size_t)C_*C_*2);
  unsigned short* wkb   = (unsigned short*)alloc((size_t)3*C_*C_*2);
  unsigned short* wvb   = (unsigned short*)alloc((size_t)3*C_*C_*2);
  unsigned short* wob   = (unsigned short*)alloc((size_t)C_*C_*2);
  unsigned short* qb    = (unsigned short*)alloc((size_t)M1_*C_*2);
  unsigned short* kbT   = (unsigned short*)alloc((size_t)3*B_*C_*T2_*2);
  unsigned short* vbT   = (unsigned short*)alloc((size_t)3*B_*C_*T2_*2);
  float*          ksum  = (float*)alloc((size_t)3*B_*C_*4);
  float*          part  = (float*)alloc((size_t)3*8*32*4096*4);
  unsigned short* ctxTb = (unsigned short*)alloc((size_t)3*32*4096*2);
  unsigned short* omid  = (unsigned short*)alloc((size_t)M1_*C_*2);

  (void)hipMemsetAsync(ksum, 0, (size_t)3*B_*C_*4, stream);

  cvt_bf16_4<<<dim3(M1_*C_/4/256, 4), 256, 0, stream>>>(
      x, y0, y1, y2, xb, yball, yball + (size_t)M2_*C_, yball + (size_t)2*M2_*C_,
      M1_*C_/4, M2_*C_/4, M2_*C_/4, M2_*C_/4);
  cvt_bf16_4<<<dim3(3*C_*C_/4/256, 4), 256, 0, stream>>>(
      Wq, Wk, Wv, Wo, wqb, wkb, wvb, wob,
      C_*C_/4, 3*C_*C_/4, 3*C_*C_/4, C_*C_/4);

  proj<<<2048, 256, 0, stream>>>(xb, yball, wqb, wkb, wvb, bq, bk, bv, qb, kbT, vbT, ksum);
  ctx_mfma<<<dim3(32, 8, 3), 256, 0, stream>>>(kbT, vbT, part);
  ctx_reduce<<<dim3(32, 3), 256, 0, stream>>>(part, ctxTb);
  combine<<<512, 256, 0, stream>>>(qb, ctxTb, ksum, omid);
  gemm_bt<<<512, 256, 0, stream>>>(omid, wob, bo, (float*)d_out);
}

// Round 10
// 125.211 us; speedup vs baseline: 3.1150x; 1.1322x over previous
//
#include <hip/hip_runtime.h>
#include <stdint.h>

#define B_ 4
#define T1_ 4096
#define T2_ 2048
#define C_ 512
#define H_ 8
#define D_ 64
#define M1_ (B_*T1_)   // 16384
#define M2_ (B_*T2_)   // 8192

using f32x4 = __attribute__((ext_vector_type(4))) float;
using bf16x8 = __attribute__((ext_vector_type(8))) __bf16;
using us8 = __attribute__((ext_vector_type(8))) unsigned short;
using us4 = __attribute__((ext_vector_type(4))) unsigned short;

__device__ __forceinline__ unsigned short f2bf(float f){
  unsigned int u = __builtin_bit_cast(unsigned int, f);
  unsigned int r = (u + 0x7fffu + ((u >> 16) & 1u)) >> 16;
  return (unsigned short)r;
}
__device__ __forceinline__ float bf2f(unsigned short u){
  return __builtin_bit_cast(float, ((unsigned int)u) << 16);
}
__device__ __forceinline__ f32x4 mfma16(us8 a, us8 b, f32x4 c){
  return __builtin_amdgcn_mfma_f32_16x16x32_bf16(
      __builtin_bit_cast(bf16x8, a), __builtin_bit_cast(bf16x8, b), c, 0, 0, 0);
}
__device__ __forceinline__ us8 cvt8(f32x4 a, f32x4 b){
  us8 v;
  #pragma unroll
  for (int j = 0; j < 4; ++j){ v[j] = f2bf(a[j]); v[4+j] = f2bf(b[j]); }
  return v;
}

typedef const __attribute__((address_space(1))) unsigned int gu32;
typedef __attribute__((address_space(3))) unsigned int lu32;
__device__ __forceinline__ void gl_lds16(const void* g, void* l){
  __builtin_amdgcn_global_load_lds((gu32*)g, (lu32*)l, 16, 0, 0);
}

#define WAIT_VM(N) asm volatile("s_waitcnt vmcnt(" #N ")" ::: "memory")
#define WAIT_LGKM() asm volatile("s_waitcnt lgkmcnt(0)" ::: "memory")
#define RAW_BAR()  { __builtin_amdgcn_s_barrier(); __builtin_amdgcn_sched_barrier(0); }

// chunk swizzle for the K-loop staging (involution, rule 21)
__device__ __forceinline__ int swz(int row, int blk){ return blk ^ ((row >> 1) & 3); }

// ---------------- fp32 -> bf16 convert (weights only now) ----------------
__global__ __launch_bounds__(256) void cvt_bf16_4(const float* __restrict__ p0, const float* __restrict__ p1,
                                                  const float* __restrict__ p2, const float* __restrict__ p3,
                                                  unsigned short* o0, unsigned short* o1,
                                                  unsigned short* o2, unsigned short* o3,
                                                  int n0, int n1, int n2, int n3){
  const float* in; unsigned short* out; int n4;
  switch (blockIdx.y){
    case 0: in = p0; out = o0; n4 = n0; break;
    case 1: in = p1; out = o1; n4 = n1; break;
    case 2: in = p2; out = o2; n4 = n2; break;
    default: in = p3; out = o3; n4 = n3; break;
  }
  int i = blockIdx.x * 256 + threadIdx.x;
  if (i >= n4) return;
  f32x4 v = ((const f32x4*)in)[i];
  us4 o;
  #pragma unroll
  for (int j = 0; j < 4; ++j) o[j] = f2bf(v[j]);
  ((us4*)out)[i] = o;
}

// ---------- C-layout fp32 vals -> swizzled bf16 LDS tile -> coalesced store ----------
__device__ __forceinline__ void tile_write(unsigned short* tile, const f32x4 (&vals)[4][4],
                                           int wr, int wc, int lr, int lk){
  #pragma unroll
  for (int mt = 0; mt < 4; ++mt)
    #pragma unroll
    for (int nt = 0; nt < 4; ++nt)
      #pragma unroll
      for (int r = 0; r < 4; ++r){
        int row = wr*64 + mt*16 + lk*4 + r;
        int cb  = (wc*128 + nt*32 + lr*2) ^ ((row & 7) << 4);
        *(unsigned short*)((char*)tile + row*256 + cb) = f2bf(vals[mt][nt][r]);
      }
}
// transposed write: value for output (row=ch, col=n) -> tile[ch][n] (same swizzle family)
__device__ __forceinline__ void tile_write_T(unsigned short* tile, const f32x4 (&vals)[4][4],
                                             int wr, int wc, int lr, int lk){
  #pragma unroll
  for (int mt = 0; mt < 4; ++mt)
    #pragma unroll
    for (int nt = 0; nt < 4; ++nt)
      #pragma unroll
      for (int r = 0; r < 4; ++r){
        int n  = wr*64 + mt*16 + lk*4 + r;     // output column (time index)
        int ch = wc*64 + nt*16 + lr;           // output row (channel)
        int cb = (n*2) ^ ((ch & 7) << 4);
        *(unsigned short*)((char*)tile + ch*256 + cb) = f2bf(vals[mt][nt][r]);
      }
}
__device__ __forceinline__ void tile_flush(const unsigned short* tile, unsigned short* g,
                                           size_t row0, int col0, int ldg, int t){
  #pragma unroll
  for (int p = 0; p < 8; ++p){
    int row = p*16 + (t >> 4);
    int cb  = ((t & 15) * 16) ^ ((row & 7) << 4);
    us8 v = *(const us8*)((const char*)tile + row*256 + cb);
    *(us8*)(g + (row0 + row) * (size_t)ldg + col0 + (t & 15) * 8) = v;
  }
}

// ================= merged projection kernel (fp32 A reg-staged + cvt, bf16 W via gl_lds) =========
// grid 2048 x 256thr, 40 KB LDS: A dbuf 2x8KB @0, W tribuf 3x8KB @8192; repack tile (32KB) aliases.
__global__ __launch_bounds__(256, 3) void proj(const float* __restrict__ xf,
                                               const float* __restrict__ y0f,
                                               const float* __restrict__ y1f,
                                               const float* __restrict__ y2f,
                                               const unsigned short* __restrict__ wqb,
                                               const unsigned short* __restrict__ wkb,
                                               const unsigned short* __restrict__ wvb,
                                               const float* __restrict__ bq,
                                               const float* __restrict__ bk,
                                               const float* __restrict__ bv,
                                               unsigned short* __restrict__ qb,
                                               unsigned short* __restrict__ kbT,
                                               unsigned short* __restrict__ vbT,
                                               float* __restrict__ ksum){
  __shared__ unsigned short smem[20480];       // 40 KB
  const int hw = blockIdx.x;
  const int work = (hw & 7) * 256 + (hw >> 3); // XCD-chunked bijective swizzle
  int seg, ii, m0, n0;
  const float* Af;
  const unsigned short* W;
  const float* bias;
  if (work < 512){
    seg = 0; ii = 0;
    m0 = (work >> 2) << 7; n0 = (work & 3) << 7;
    Af = xf; W = wqb; bias = bq;
  } else {
    int r = work - 512;
    int g = r >> 3, s = r & 7;
    ii = g >> 6; m0 = (g & 63) << 7;
    seg = (s < 4) ? 1 : 2;
    n0 = (s & 3) << 7;
    Af = (ii == 0) ? y0f : (ii == 1 ? y1f : y2f);
    W = (seg == 1 ? wkb : wvb) + (size_t)ii*C_*C_;
    bias = (seg == 1 ? bk : bv) + (size_t)ii*C_;
  }
  const int t = threadIdx.x;
  const int w = t >> 6, l = t & 63;
  const int wr = w >> 1, wc = w & 1;
  const int lr = l & 15, lk = l >> 4;
  const int row0 = t >> 2,          b0 = t & 3;
  const int row1 = (t + 256) >> 2,  b1 = t & 3;
  f32x4 acc[4][4] = {};
  f32x4 ar0[4], ar1[4];

#define LOADA(AR, TT) { \
    const float* ap0 = Af + (size_t)(m0+row0)*C_ + (TT)*32 + b0*8; \
    const float* ap1 = Af + (size_t)(m0+row1)*C_ + (TT)*32 + b1*8; \
    AR[0] = *(const f32x4*)ap0; AR[1] = *(const f32x4*)(ap0 + 4); \
    AR[2] = *(const f32x4*)ap1; AR[3] = *(const f32x4*)(ap1 + 4); }
#define DSWA(AR, BUF) { \
    *(us8*)&smem[(BUF)*4096 + row0*32 + swz(row0,b0)*8] = cvt8(AR[0], AR[1]); \
    *(us8*)&smem[(BUF)*4096 + row1*32 + swz(row1,b1)*8] = cvt8(AR[2], AR[3]); }
#define GLW(BUF, TT) { \
    int c=t, row=c>>2; \
    gl_lds16(W + (size_t)(n0+row)*C_ + (TT)*32 + swz(row,c&3)*8, &smem[8192+(BUF)*4096 + c*8]); \
    c=t+256; row=c>>2; \
    gl_lds16(W + (size_t)(n0+row)*C_ + (TT)*32 + swz(row,c&3)*8, &smem[8192+(BUF)*4096 + c*8]); }
#define PCOMP(S, WB) { \
    const unsigned short* sA = &smem[(S)*4096]; \
    const unsigned short* sW = &smem[8192 + (WB)*4096]; \
    us8 af[4], bfr[4]; \
    _Pragma("unroll") \
    for (int mt = 0; mt < 4; ++mt){ int R = wr*64 + mt*16 + lr; af[mt] = *(const us8*)&sA[R*32 + swz(R, lk)*8]; } \
    _Pragma("unroll") \
    for (int nt = 0; nt < 4; ++nt){ int R = wc*64 + nt*16 + lr; bfr[nt] = *(const us8*)&sW[R*32 + swz(R, lk)*8]; } \
    __builtin_amdgcn_s_setprio(1); \
    _Pragma("unroll") \
    for (int mt = 0; mt < 4; ++mt) \
      _Pragma("unroll") \
      for (int nt = 0; nt < 4; ++nt) \
        acc[mt][nt] = mfma16(af[mt], bfr[nt], acc[mt][nt]); \
    __builtin_amdgcn_s_setprio(0); }
#define PSTEP(T, AR, S) { \
    WAIT_VM(6); \
    DSWA(AR, S); \
    if ((T) + 2 < 16) { LOADA(AR, (T)+2); GLW(((T)+2)%3, (T)+2); } \
    WAIT_LGKM(); \
    RAW_BAR(); \
    PCOMP(S, (T)%3); }
#define PSTEPL(T, AR, S) { \
    WAIT_VM(0); \
    DSWA(AR, S); \
    WAIT_LGKM(); \
    RAW_BAR(); \
    PCOMP(S, (T)%3); }

  LOADA(ar0, 0); GLW(0, 0);
  LOADA(ar1, 1); GLW(1, 1);
  PSTEP(0,  ar0, 0) PSTEP(1,  ar1, 1) PSTEP(2,  ar0, 0) PSTEP(3,  ar1, 1)
  PSTEP(4,  ar0, 0) PSTEP(5,  ar1, 1) PSTEP(6,  ar0, 0) PSTEP(7,  ar1, 1)
  PSTEP(8,  ar0, 0) PSTEP(9,  ar1, 1) PSTEP(10, ar0, 0) PSTEP(11, ar1, 1)
  PSTEP(12, ar0, 0) PSTEP(13, ar1, 1) PSTEP(14, ar0, 0) PSTEPL(15, ar1, 1)
#undef LOADA
#undef DSWA
#undef GLW
#undef PCOMP
#undef PSTEP
#undef PSTEPL

  // bias
  {
    float bc[4];
    #pragma unroll
    for (int nt = 0; nt < 4; ++nt) bc[nt] = bias[n0 + wc*64 + nt*16 + lr];
    #pragma unroll
    for (int mt = 0; mt < 4; ++mt)
      #pragma unroll
      for (int nt = 0; nt < 4; ++nt)
        #pragma unroll
        for (int r = 0; r < 4; ++r) acc[mt][nt][r] += bc[nt];
  }
  if (seg <= 1){
    // in-register softmax over the wave's 64-col head group
    #pragma unroll
    for (int mt = 0; mt < 4; ++mt)
      #pragma unroll
      for (int r = 0; r < 4; ++r){
        float m = fmaxf(fmaxf(acc[mt][0][r], acc[mt][1][r]), fmaxf(acc[mt][2][r], acc[mt][3][r]));
        #pragma unroll
        for (int s = 1; s < 16; s <<= 1) m = fmaxf(m, __shfl_xor(m, s, 64));
        float sum = 0.f;
        #pragma unroll
        for (int nt = 0; nt < 4; ++nt){
          float e = __expf(acc[mt][nt][r] - m);
          acc[mt][nt][r] = e; sum += e;
        }
        #pragma unroll
        for (int s = 1; s < 16; s <<= 1) sum += __shfl_xor(sum, s, 64);
        float inv = 1.0f / sum;
        #pragma unroll
        for (int nt = 0; nt < 4; ++nt) acc[mt][nt][r] *= inv;
      }
  }
  if (seg == 1){
    // colsum -> ksum atomics
    const int b = m0 >> 11;
    #pragma unroll
    for (int nt = 0; nt < 4; ++nt){
      float cs = 0.f;
      #pragma unroll
      for (int mt = 0; mt < 4; ++mt)
        #pragma unroll
        for (int r = 0; r < 4; ++r) cs += acc[mt][nt][r];
      cs += __shfl_xor(cs, 16, 64);
      cs += __shfl_xor(cs, 32, 64);
      if (lk == 0)
        atomicAdd(&ksum[((size_t)ii*B_ + b)*C_ + n0 + wc*64 + nt*16 + lr], cs);
    }
  }
  __syncthreads();
  if (seg == 0){
    tile_write(smem, acc, wr, wc, lr, lk);
    __syncthreads();
    tile_flush(smem, qb, m0, n0, C_, t);
  } else {
    tile_write_T(smem, acc, wr, wc, lr, lk);
    __syncthreads();
    const int b = m0 >> 11;
    const int n_base = m0 & 2047;
    unsigned short* gT = (seg == 1 ? kbT : vbT);
    tile_flush(smem, gT, ((size_t)ii*B_ + b)*C_ + n0, n_base, T2_, t);
  }
}

// ================= ctx via MFMA: part[i][kc][bh][e*64+d] = sum_n k[n,d] v[n,e] =================
__global__ __launch_bounds__(256) void ctx_mfma(const unsigned short* __restrict__ kbT,
                                                const unsigned short* __restrict__ vbT,
                                                float* __restrict__ part){
  const int bh = blockIdx.x, kc = blockIdx.y, i = blockIdx.z;
  const int b = bh >> 3, h = bh & 7;
  const size_t rowbase = ((size_t)i*B_ + b)*C_ + h*64;
  const unsigned short* kT = kbT + rowbase*T2_;
  const unsigned short* vT = vbT + rowbase*T2_;
  const int t = threadIdx.x;
  const int w = t >> 6, l = t & 63;
  const int qr = w >> 1, qc = w & 1;
  const int lr = l & 15, lk = l >> 4;
  const int n00 = kc * 256;
  f32x4 acc[2][2] = {};
  #pragma unroll
  for (int it = 0; it < 8; ++it){
    const int k0 = n00 + it*32 + lk*8;
    us8 a0 = *(const us8*)(kT + (size_t)(qr*32 +      lr)*T2_ + k0);
    us8 a1 = *(const us8*)(kT + (size_t)(qr*32 + 16 + lr)*T2_ + k0);
    us8 b0 = *(const us8*)(vT + (size_t)(qc*32 +      lr)*T2_ + k0);
    us8 b1 = *(const us8*)(vT + (size_t)(qc*32 + 16 + lr)*T2_ + k0);
    acc[0][0] = mfma16(a0, b0, acc[0][0]);
    acc[0][1] = mfma16(a0, b1, acc[0][1]);
    acc[1][0] = mfma16(a1, b0, acc[1][0]);
    acc[1][1] = mfma16(a1, b1, acc[1][1]);
  }
  float* dst = part + (((size_t)i*8 + kc)*32 + bh)*4096;
  #pragma unroll
  for (int fa = 0; fa < 2; ++fa)
    #pragma unroll
    for (int fb = 0; fb < 2; ++fb){
      int d0 = qr*32 + fa*16 + lk*4;
      int e  = qc*32 + fb*16 + lr;
      *(f32x4*)(dst + e*64 + d0) = acc[fa][fb];
    }
}

__global__ __launch_bounds__(256) void ctx_reduce(const float* __restrict__ part,
                                                  unsigned short* __restrict__ ctxTb){
  const int bh = blockIdx.x, i = blockIdx.y, t = threadIdx.x;
  for (int idx = t; idx < 4096; idx += 256){
    float s = 0.f;
    #pragma unroll
    for (int kc = 0; kc < 8; ++kc)
      s += part[(((size_t)i*8 + kc)*32 + bh)*4096 + idx];
    ctxTb[((size_t)i*32 + bh)*4096 + idx] = f2bf(s);
  }
}

// ================= combine: omid = q + sum_i (q @ ctx_i) * Dinv_i =================
__global__ __launch_bounds__(256) void combine(const unsigned short* __restrict__ qb,
                                               const unsigned short* __restrict__ ctxTb,
                                               const float* __restrict__ ksum,
                                               unsigned short* __restrict__ omid){
  __shared__ unsigned short tile[128*128];
  const int hw = blockIdx.x;
  const int work = (hw & 7) * 64 + (hw >> 3);
  const int m0 = (work & 127) << 7, n0 = (work >> 7) << 7;
  const int t = threadIdx.x;
  const int w = t >> 6, l = t & 63;
  const int wr = w >> 1, wc = w & 1;
  const int lr = l & 15, lk = l >> 4;
  const int b = m0 >> 12;
  const int bh = b*8 + (n0 >> 6) + wc;
  #pragma unroll
  for (int p = 0; p < 8; ++p){
    int idx = p*256 + t;
    int row = idx >> 4, ch = idx & 15;
    gl_lds16(qb + (size_t)(m0+row)*C_ + n0 + (ch ^ (row & 7))*8, &tile[idx*8]);
  }
  WAIT_VM(0);
  __syncthreads();
  us8 afr[4][2];
  #pragma unroll
  for (int mt = 0; mt < 4; ++mt)
    #pragma unroll
    for (int kk = 0; kk < 2; ++kk){
      int row = wr*64 + mt*16 + lr;
      int ch = wc*8 + kk*4 + lk;
      afr[mt][kk] = *(const us8*)((const char*)tile + row*256 + ((ch ^ (row & 7)) << 4));
    }
  f32x4 acc[4][4];
  #pragma unroll
  for (int mt = 0; mt < 4; ++mt)
    #pragma unroll
    for (int nt = 0; nt < 4; ++nt)
      #pragma unroll
      for (int r = 0; r < 4; ++r){
        int row = wr*64 + mt*16 + lk*4 + r;
        int cbyte = wc*128 + nt*32 + lr*2;
        int ch = cbyte >> 4;
        unsigned short v = *(const unsigned short*)((const char*)tile + row*256 +
                            ((ch ^ (row & 7)) << 4) + (cbyte & 15));
        acc[mt][nt][r] = bf2f(v);
      }
  us8 bden[2];
  #pragma unroll
  for (int kk = 0; kk < 2; ++kk){
    us8 tmp = {};
    if (lr < 3){
      const float* kp = ksum + ((size_t)lr*B_ + b)*C_ + n0 + wc*64 + kk*32 + lk*8;
      f32x4 c0 = *(const f32x4*)kp;
      f32x4 c1 = *(const f32x4*)(kp + 4);
      #pragma unroll
      for (int j = 0; j < 4; ++j){ tmp[j] = f2bf(c0[j]); tmp[4+j] = f2bf(c1[j]); }
    }
    bden[kk] = tmp;
  }
  f32x4 den[4] = {};
  #pragma unroll
  for (int mt = 0; mt < 4; ++mt)
    #pragma unroll
    for (int kk = 0; kk < 2; ++kk)
      den[mt] = mfma16(afr[mt][kk], bden[kk], den[mt]);
  #pragma unroll 1
  for (int i = 0; i < 3; ++i){
    f32x4 dinv[4];
    #pragma unroll
    for (int mt = 0; mt < 4; ++mt)
      #pragma unroll
      for (int r = 0; r < 4; ++r)
        dinv[mt][r] = 1.0f / (__shfl(den[mt][r], (l & 48) | i, 64) + 1e-8f);
    #pragma unroll
    for (int nt = 0; nt < 4; ++nt){
      us8 bfr[2];
      #pragma unroll
      for (int kk = 0; kk < 2; ++kk)
        bfr[kk] = *(const us8*)(ctxTb + ((size_t)(i*32 + bh))*4096 + (nt*16 + lr)*64 + kk*32 + lk*8);
      f32x4 p[4] = {};
      #pragma unroll
      for (int mt = 0; mt < 4; ++mt)
        #pragma unroll
        for (int kk = 0; kk < 2; ++kk)
          p[mt] = mfma16(afr[mt][kk], bfr[kk], p[mt]);
      #pragma unroll
      for (int mt = 0; mt < 4; ++mt)
        #pragma unroll
        for (int r = 0; r < 4; ++r)
          acc[mt][nt][r] += p[mt][r] * dinv[mt][r];
    }
  }
  __syncthreads();
  tile_write(tile, acc, wr, wc, lr, lk);
  __syncthreads();
  tile_flush(tile, omid, m0, n0, C_, t);
}

// ---------------- O-proj GEMM (3-buf, depth-2 counted-vmcnt) ----------------
__global__ __launch_bounds__(256, 3) void gemm_bt(const unsigned short* __restrict__ A,
                                                  const unsigned short* __restrict__ Bw,
                                                  const float* __restrict__ bias,
                                                  float* __restrict__ out){
  __shared__ unsigned short smem[3*2*4096];
  const int hw = blockIdx.x;
  const int work = (hw & 7) * 64 + (hw >> 3);
  const int m0 = ((work >> 2) & 127) << 7, n0 = (work & 3) << 7;
  const int t = threadIdx.x;
  const int w = t >> 6, l = t & 63;
  const int wr = w >> 1, wc = w & 1;
  const int lr = l & 15, lk = l >> 4;
  f32x4 acc[4][4] = {};

#define GSTAGE(BB, TT) { \
    int c = t, row = c >> 2; \
    gl_lds16(A  + (size_t)(m0+row)*C_ + (TT)*32 + swz(row, c & 3)*8, &smem[(BB)*8192 + c*8]); \
    gl_lds16(Bw + (size_t)(n0+row)*C_ + (TT)*32 + swz(row, c & 3)*8, &smem[(BB)*8192 + 4096 + c*8]); \
    c = t + 256; row = c >> 2; \
    gl_lds16(A  + (size_t)(m0+row)*C_ + (TT)*32 + swz(row, c & 3)*8, &smem[(BB)*8192 + c*8]); \
    gl_lds16(Bw + (size_t)(n0+row)*C_ + (TT)*32 + swz(row, c & 3)*8, &smem[(BB)*8192 + 4096 + c*8]); }
#define GCOMP(BB) { \
    const unsigned short* sA = &smem[(BB)*8192]; \
    const unsigned short* sB = &smem[(BB)*8192 + 4096]; \
    us8 af[4], bfr[4]; \
    _Pragma("unroll") \
    for (int mt = 0; mt < 4; ++mt){ int R = wr*64 + mt*16 + lr; af[mt] = *(const us8*)&sA[R*32 + swz(R, lk)*8]; } \
    _Pragma("unroll") \
    for (int nt = 0; nt < 4; ++nt){ int R = wc*64 + nt*16 + lr; bfr[nt] = *(const us8*)&sB[R*32 + swz(R, lk)*8]; } \
    __builtin_amdgcn_s_setprio(1); \
    _Pragma("unroll") \
    for (int mt = 0; mt < 4; ++mt) \
      _Pragma("unroll") \
      for (int nt = 0; nt < 4; ++nt) \
        acc[mt][nt] = mfma16(af[mt], bfr[nt], acc[mt][nt]); \
    __builtin_amdgcn_s_setprio(0); }
#define GSTEP(T, N) { \
    if ((T) + 2 < 16) GSTAGE(((T)+2)%3, (T)+2); \
    WAIT_VM(N); \
    RAW_BAR(); \
    GCOMP((T)%3); }

  GSTAGE(0, 0); GSTAGE(1, 1);
  GSTEP(0, 8)  GSTEP(1, 8)  GSTEP(2, 8)  GSTEP(3, 8)
  GSTEP(4, 8)  GSTEP(5, 8)  GSTEP(6, 8)  GSTEP(7, 8)
  GSTEP(8, 8)  GSTEP(9, 8)  GSTEP(10, 8) GSTEP(11, 8)
  GSTEP(12, 8) GSTEP(13, 8) GSTEP(14, 4) GSTEP(15, 0)
#undef GSTAGE
#undef GCOMP
#undef GSTEP

  #pragma unroll
  for (int mt = 0; mt < 4; ++mt)
    #pragma unroll
    for (int nt = 0; nt < 4; ++nt)
      #pragma unroll
      for (int r = 0; r < 4; ++r){
        int row = m0 + wr*64 + mt*16 + lk*4 + r;
        int col = n0 + wc*64 + nt*16 + lr;
        out[(size_t)row*C_ + col] = acc[mt][nt][r] + bias[col];
      }
}

extern "C" void kernel_launch(void* const* d_in, const int* in_sizes, int n_in,
                              void* d_out, int out_size, void* d_ws, size_t ws_size,
                              hipStream_t stream){
  const float* x  = (const float*)d_in[0];
  const float* y0 = (const float*)d_in[1];
  const float* y1 = (const float*)d_in[2];
  const float* y2 = (const float*)d_in[3];
  const float* Wq = (const float*)d_in[4];
  const float* bq = (const float*)d_in[5];
  const float* Wk = (const float*)d_in[6];
  const float* bk = (const float*)d_in[7];
  const float* Wv = (const float*)d_in[8];
  const float* bv = (const float*)d_in[9];
  const float* Wo = (const float*)d_in[10];
  const float* bo = (const float*)d_in[11];

  char* ws = (char*)d_ws;
  size_t off = 0;
  auto alloc = [&](size_t bytes)->char*{
    char* p = ws + off; off += (bytes + 1023) & ~((size_t)1023); return p;
  };
  unsigned short* wqb   = (unsigned short*)alloc((size_t)C_*C_*2);
  unsigned short* wkb   = (unsigned short*)alloc((size_t)3*C_*C_*2);
  unsigned short* wvb   = (unsigned short*)alloc((size_t)3*C_*C_*2);
  unsigned short* wob   = (unsigned short*)alloc((size_t)C_*C_*2);
  unsigned short* qb    = (unsigned short*)alloc((size_t)M1_*C_*2);
  unsigned short* kbT   = (unsigned short*)alloc((size_t)3*B_*C_*T2_*2);
  unsigned short* vbT   = (unsigned short*)alloc((size_t)3*B_*C_*T2_*2);
  float*          ksum  = (float*)alloc((size_t)3*B_*C_*4);
  float*          part  = (float*)alloc((size_t)3*8*32*4096*4);
  unsigned short* ctxTb = (unsigned short*)alloc((size_t)3*32*4096*2);
  unsigned short* omid  = (unsigned short*)alloc((size_t)M1_*C_*2);

  (void)hipMemsetAsync(ksum, 0, (size_t)3*B_*C_*4, stream);

  // weights-only convert (~1.5 MB)
  cvt_bf16_4<<<dim3(3*C_*C_/4/256, 4), 256, 0, stream>>>(
      Wq, Wk, Wv, Wo, wqb, wkb, wvb, wob,
      C_*C_/4, 3*C_*C_/4, 3*C_*C_/4, C_*C_/4);

  proj<<<2048, 256, 0, stream>>>(x, y0, y1, y2, wqb, wkb, wvb, bq, bk, bv, qb, kbT, vbT, ksum);
  ctx_mfma<<<dim3(32, 8, 3), 256, 0, stream>>>(kbT, vbT, part);
  ctx_reduce<<<dim3(32, 3), 256, 0, stream>>>(part, ctxTb);
  combine<<<512, 256, 0, stream>>>(qb, ctxTb, ksum, omid);
  gemm_bt<<<512, 256, 0, stream>>>(omid, wob, bo, (float*)d_out);
}

// Round 11
// 123.265 us; speedup vs baseline: 3.1641x; 1.0158x over previous
//
#include <hip/hip_runtime.h>
#include <stdint.h>

#define B_ 4
#define T1_ 4096
#define T2_ 2048
#define C_ 512
#define H_ 8
#define D_ 64
#define M1_ (B_*T1_)   // 16384
#define M2_ (B_*T2_)   // 8192

using f32x4 = __attribute__((ext_vector_type(4))) float;
using bf16x8 = __attribute__((ext_vector_type(8))) __bf16;
using us8 = __attribute__((ext_vector_type(8))) unsigned short;
using us4 = __attribute__((ext_vector_type(4))) unsigned short;

__device__ __forceinline__ unsigned short f2bf(float f){
  unsigned int u = __builtin_bit_cast(unsigned int, f);
  unsigned int r = (u + 0x7fffu + ((u >> 16) & 1u)) >> 16;
  return (unsigned short)r;
}
__device__ __forceinline__ float bf2f(unsigned short u){
  return __builtin_bit_cast(float, ((unsigned int)u) << 16);
}
__device__ __forceinline__ f32x4 mfma16(us8 a, us8 b, f32x4 c){
  return __builtin_amdgcn_mfma_f32_16x16x32_bf16(
      __builtin_bit_cast(bf16x8, a), __builtin_bit_cast(bf16x8, b), c, 0, 0, 0);
}
// hot-path cvt: compiler emits packed v_cvt (m240: prefer cast over hand-asm)
__device__ __forceinline__ us8 cvt8(f32x4 a, f32x4 b){
  us8 v;
  #pragma unroll
  for (int j = 0; j < 4; ++j){
    v[j]   = __builtin_bit_cast(unsigned short, (__bf16)a[j]);
    v[4+j] = __builtin_bit_cast(unsigned short, (__bf16)b[j]);
  }
  return v;
}

typedef const __attribute__((address_space(1))) unsigned int gu32;
typedef __attribute__((address_space(3))) unsigned int lu32;
__device__ __forceinline__ void gl_lds16(const void* g, void* l){
  __builtin_amdgcn_global_load_lds((gu32*)g, (lu32*)l, 16, 0, 0);
}

#define WAIT_VM(N) asm volatile("s_waitcnt vmcnt(" #N ")" ::: "memory")
#define WAIT_LGKM() asm volatile("s_waitcnt lgkmcnt(0)" ::: "memory")
#define RAW_BAR()  { __builtin_amdgcn_s_barrier(); __builtin_amdgcn_sched_barrier(0); }

// chunk swizzle for the K-loop staging (involution, rule 21)
__device__ __forceinline__ int swz(int row, int blk){ return blk ^ ((row >> 1) & 3); }

// ---------------- fp32 -> bf16 convert (weights only) ----------------
__global__ __launch_bounds__(256) void cvt_bf16_4(const float* __restrict__ p0, const float* __restrict__ p1,
                                                  const float* __restrict__ p2, const float* __restrict__ p3,
                                                  unsigned short* o0, unsigned short* o1,
                                                  unsigned short* o2, unsigned short* o3,
                                                  int n0, int n1, int n2, int n3){
  const float* in; unsigned short* out; int n4;
  switch (blockIdx.y){
    case 0: in = p0; out = o0; n4 = n0; break;
    case 1: in = p1; out = o1; n4 = n1; break;
    case 2: in = p2; out = o2; n4 = n2; break;
    default: in = p3; out = o3; n4 = n3; break;
  }
  int i = blockIdx.x * 256 + threadIdx.x;
  if (i >= n4) return;
  f32x4 v = ((const f32x4*)in)[i];
  us4 o;
  #pragma unroll
  for (int j = 0; j < 4; ++j) o[j] = f2bf(v[j]);
  ((us4*)out)[i] = o;
}

// ---------- C-layout fp32 vals -> swizzled bf16 LDS tile -> coalesced store ----------
__device__ __forceinline__ void tile_write(unsigned short* tile, const f32x4 (&vals)[4][4],
                                           int wr, int wc, int lr, int lk){
  #pragma unroll
  for (int mt = 0; mt < 4; ++mt)
    #pragma unroll
    for (int nt = 0; nt < 4; ++nt)
      #pragma unroll
      for (int r = 0; r < 4; ++r){
        int row = wr*64 + mt*16 + lk*4 + r;
        int cb  = (wc*128 + nt*32 + lr*2) ^ ((row & 7) << 4);
        *(unsigned short*)((char*)tile + row*256 + cb) = f2bf(vals[mt][nt][r]);
      }
}
// transposed write: value for output (row=ch, col=n) -> tile[ch][n] (same swizzle family)
__device__ __forceinline__ void tile_write_T(unsigned short* tile, const f32x4 (&vals)[4][4],
                                             int wr, int wc, int lr, int lk){
  #pragma unroll
  for (int mt = 0; mt < 4; ++mt)
    #pragma unroll
    for (int nt = 0; nt < 4; ++nt)
      #pragma unroll
      for (int r = 0; r < 4; ++r){
        int n  = wr*64 + mt*16 + lk*4 + r;     // output column (time index)
        int ch = wc*64 + nt*16 + lr;           // output row (channel)
        int cb = (n*2) ^ ((ch & 7) << 4);
        *(unsigned short*)((char*)tile + ch*256 + cb) = f2bf(vals[mt][nt][r]);
      }
}
__device__ __forceinline__ void tile_flush(const unsigned short* tile, unsigned short* g,
                                           size_t row0, int col0, int ldg, int t){
  #pragma unroll
  for (int p = 0; p < 8; ++p){
    int row = p*16 + (t >> 4);
    int cb  = ((t & 15) * 16) ^ ((row & 7) << 4);
    us8 v = *(const us8*)((const char*)tile + row*256 + cb);
    *(us8*)(g + (row0 + row) * (size_t)ldg + col0 + (t & 15) * 8) = v;
  }
}

// ================= merged projection kernel (fp32 A reg-staged + cvt, bf16 W via gl_lds) =========
// grid 2048 x 256thr, 48 KB LDS: A tribuf 3x8KB @0, W tribuf 3x8KB @24576B; repack tile aliases.
// Pipeline: DSWA(T+1) + loads issued BEFORE PCOMP(T); vmcnt/lgkm drains AFTER PCOMP (hidden).
__global__ __launch_bounds__(256, 3) void proj(const float* __restrict__ xf,
                                               const float* __restrict__ y0f,
                                               const float* __restrict__ y1f,
                                               const float* __restrict__ y2f,
                                               const unsigned short* __restrict__ wqb,
                                               const unsigned short* __restrict__ wkb,
                                               const unsigned short* __restrict__ wvb,
                                               const float* __restrict__ bq,
                                               const float* __restrict__ bk,
                                               const float* __restrict__ bv,
                                               unsigned short* __restrict__ qb,
                                               unsigned short* __restrict__ kbT,
                                               unsigned short* __restrict__ vbT,
                                               float* __restrict__ ksum){
  __shared__ unsigned short smem[24576];       // 48 KB
  const int hw = blockIdx.x;
  const int work = (hw & 7) * 256 + (hw >> 3); // XCD-chunked bijective swizzle
  int seg, ii, m0, n0;
  const float* Af;
  const unsigned short* W;
  const float* bias;
  if (work < 512){
    seg = 0; ii = 0;
    m0 = (work >> 2) << 7; n0 = (work & 3) << 7;
    Af = xf; W = wqb; bias = bq;
  } else {
    int r = work - 512;
    int g = r >> 3, s = r & 7;
    ii = g >> 6; m0 = (g & 63) << 7;
    seg = (s < 4) ? 1 : 2;
    n0 = (s & 3) << 7;
    Af = (ii == 0) ? y0f : (ii == 1 ? y1f : y2f);
    W = (seg == 1 ? wkb : wvb) + (size_t)ii*C_*C_;
    bias = (seg == 1 ? bk : bv) + (size_t)ii*C_;
  }
  const int t = threadIdx.x;
  const int w = t >> 6, l = t & 63;
  const int wr = w >> 1, wc = w & 1;
  const int lr = l & 15, lk = l >> 4;
  const int row0 = t >> 2,          b0 = t & 3;
  const int row1 = (t + 256) >> 2,  b1 = t & 3;
  f32x4 acc[4][4] = {};
  f32x4 ar0[4], ar1[4];

#define LOADA(AR, TT) { \
    const float* ap0 = Af + (size_t)(m0+row0)*C_ + (TT)*32 + b0*8; \
    const float* ap1 = Af + (size_t)(m0+row1)*C_ + (TT)*32 + b1*8; \
    AR[0] = *(const f32x4*)ap0; AR[1] = *(const f32x4*)(ap0 + 4); \
    AR[2] = *(const f32x4*)ap1; AR[3] = *(const f32x4*)(ap1 + 4); }
#define DSWA(AR, BUF) { \
    *(us8*)&smem[(BUF)*4096 + row0*32 + swz(row0,b0)*8] = cvt8(AR[0], AR[1]); \
    *(us8*)&smem[(BUF)*4096 + row1*32 + swz(row1,b1)*8] = cvt8(AR[2], AR[3]); }
#define GLW(BUF, TT) { \
    int c=t, row=c>>2; \
    gl_lds16(W + (size_t)(n0+row)*C_ + (TT)*32 + swz(row,c&3)*8, &smem[12288+(BUF)*4096 + c*8]); \
    c=t+256; row=c>>2; \
    gl_lds16(W + (size_t)(n0+row)*C_ + (TT)*32 + swz(row,c&3)*8, &smem[12288+(BUF)*4096 + c*8]); }
#define PCOMP(S, WB) { \
    const unsigned short* sA = &smem[(S)*4096]; \
    const unsigned short* sW = &smem[12288 + (WB)*4096]; \
    us8 af[4], bfr[4]; \
    _Pragma("unroll") \
    for (int mt = 0; mt < 4; ++mt){ int R = wr*64 + mt*16 + lr; af[mt] = *(const us8*)&sA[R*32 + swz(R, lk)*8]; } \
    _Pragma("unroll") \
    for (int nt = 0; nt < 4; ++nt){ int R = wc*64 + nt*16 + lr; bfr[nt] = *(const us8*)&sW[R*32 + swz(R, lk)*8]; } \
    __builtin_amdgcn_s_setprio(1); \
    _Pragma("unroll") \
    for (int mt = 0; mt < 4; ++mt) \
      _Pragma("unroll") \
      for (int nt = 0; nt < 4; ++nt) \
        acc[mt][nt] = mfma16(af[mt], bfr[nt], acc[mt][nt]); \
    __builtin_amdgcn_s_setprio(0); }
// steady-state step: enter with [A(T+1)x4, W(T+1)x2] outstanding (6)
#define PSTEP(T, ARW, ARL) { \
    WAIT_VM(2); \
    DSWA(ARW, ((T)+1)%3); \
    LOADA(ARL, (T)+2); \
    GLW(((T)+2)%3, (T)+2); \
    PCOMP((T)%3, (T)%3); \
    WAIT_LGKM(); \
    WAIT_VM(6); \
    RAW_BAR(); }

  LOADA(ar0, 0); GLW(0, 0);
  LOADA(ar1, 1); GLW(1, 1);
  WAIT_VM(8);            // A(0) regs ready
  DSWA(ar0, 0);
  WAIT_LGKM();
  WAIT_VM(6);            // W(0) drained -> visible after barrier
  RAW_BAR();
  PSTEP(0,  ar1, ar0) PSTEP(1,  ar0, ar1) PSTEP(2,  ar1, ar0) PSTEP(3,  ar0, ar1)
  PSTEP(4,  ar1, ar0) PSTEP(5,  ar0, ar1) PSTEP(6,  ar1, ar0) PSTEP(7,  ar0, ar1)
  PSTEP(8,  ar1, ar0) PSTEP(9,  ar0, ar1) PSTEP(10, ar1, ar0) PSTEP(11, ar0, ar1)
  PSTEP(12, ar1, ar0) PSTEP(13, ar0, ar1)
  { // step 14: no more loads
    WAIT_VM(2);
    DSWA(ar1, 0);        // tile 15 -> bufA 0
    PCOMP(2, 2);
    WAIT_LGKM();
    WAIT_VM(0);          // W(15) drained
    RAW_BAR();
  }
  PCOMP(0, 0);           // step 15
#undef LOADA
#undef DSWA
#undef GLW
#undef PCOMP
#undef PSTEP

  // bias
  {
    float bc[4];
    #pragma unroll
    for (int nt = 0; nt < 4; ++nt) bc[nt] = bias[n0 + wc*64 + nt*16 + lr];
    #pragma unroll
    for (int mt = 0; mt < 4; ++mt)
      #pragma unroll
      for (int nt = 0; nt < 4; ++nt)
        #pragma unroll
        for (int r = 0; r < 4; ++r) acc[mt][nt][r] += bc[nt];
  }
  if (seg <= 1){
    // in-register softmax over the wave's 64-col head group
    #pragma unroll
    for (int mt = 0; mt < 4; ++mt)
      #pragma unroll
      for (int r = 0; r < 4; ++r){
        float m = fmaxf(fmaxf(acc[mt][0][r], acc[mt][1][r]), fmaxf(acc[mt][2][r], acc[mt][3][r]));
        #pragma unroll
        for (int s = 1; s < 16; s <<= 1) m = fmaxf(m, __shfl_xor(m, s, 64));
        float sum = 0.f;
        #pragma unroll
        for (int nt = 0; nt < 4; ++nt){
          float e = __expf(acc[mt][nt][r] - m);
          acc[mt][nt][r] = e; sum += e;
        }
        #pragma unroll
        for (int s = 1; s < 16; s <<= 1) sum += __shfl_xor(sum, s, 64);
        float inv = 1.0f / sum;
        #pragma unroll
        for (int nt = 0; nt < 4; ++nt) acc[mt][nt][r] *= inv;
      }
  }
  if (seg == 1){
    // colsum -> ksum atomics
    const int b = m0 >> 11;
    #pragma unroll
    for (int nt = 0; nt < 4; ++nt){
      float cs = 0.f;
      #pragma unroll
      for (int mt = 0; mt < 4; ++mt)
        #pragma unroll
        for (int r = 0; r < 4; ++r) cs += acc[mt][nt][r];
      cs += __shfl_xor(cs, 16, 64);
      cs += __shfl_xor(cs, 32, 64);
      if (lk == 0)
        atomicAdd(&ksum[((size_t)ii*B_ + b)*C_ + n0 + wc*64 + nt*16 + lr], cs);
    }
  }
  __syncthreads();
  if (seg == 0){
    tile_write(smem, acc, wr, wc, lr, lk);
    __syncthreads();
    tile_flush(smem, qb, m0, n0, C_, t);
  } else {
    tile_write_T(smem, acc, wr, wc, lr, lk);
    __syncthreads();
    const int b = m0 >> 11;
    const int n_base = m0 & 2047;
    unsigned short* gT = (seg == 1 ? kbT : vbT);
    tile_flush(smem, gT, ((size_t)ii*B_ + b)*C_ + n0, n_base, T2_, t);
  }
}

// ================= ctx via MFMA: part[i][kc][bh][e*64+d] = sum_n k[n,d] v[n,e] =================
__global__ __launch_bounds__(256) void ctx_mfma(const unsigned short* __restrict__ kbT,
                                                const unsigned short* __restrict__ vbT,
                                                float* __restrict__ part){
  const int bh = blockIdx.x, kc = blockIdx.y, i = blockIdx.z;
  const int b = bh >> 3, h = bh & 7;
  const size_t rowbase = ((size_t)i*B_ + b)*C_ + h*64;
  const unsigned short* kT = kbT + rowbase*T2_;
  const unsigned short* vT = vbT + rowbase*T2_;
  const int t = threadIdx.x;
  const int w = t >> 6, l = t & 63;
  const int qr = w >> 1, qc = w & 1;
  const int lr = l & 15, lk = l >> 4;
  const int n00 = kc * 256;
  f32x4 acc[2][2] = {};
  #pragma unroll
  for (int it = 0; it < 8; ++it){
    const int k0 = n00 + it*32 + lk*8;
    us8 a0 = *(const us8*)(kT + (size_t)(qr*32 +      lr)*T2_ + k0);
    us8 a1 = *(const us8*)(kT + (size_t)(qr*32 + 16 + lr)*T2_ + k0);
    us8 b0 = *(const us8*)(vT + (size_t)(qc*32 +      lr)*T2_ + k0);
    us8 b1 = *(const us8*)(vT + (size_t)(qc*32 + 16 + lr)*T2_ + k0);
    acc[0][0] = mfma16(a0, b0, acc[0][0]);
    acc[0][1] = mfma16(a0, b1, acc[0][1]);
    acc[1][0] = mfma16(a1, b0, acc[1][0]);
    acc[1][1] = mfma16(a1, b1, acc[1][1]);
  }
  float* dst = part + (((size_t)i*8 + kc)*32 + bh)*4096;
  #pragma unroll
  for (int fa = 0; fa < 2; ++fa)
    #pragma unroll
    for (int fb = 0; fb < 2; ++fb){
      int d0 = qr*32 + fa*16 + lk*4;
      int e  = qc*32 + fb*16 + lr;
      *(f32x4*)(dst + e*64 + d0) = acc[fa][fb];
    }
}

__global__ __launch_bounds__(256) void ctx_reduce(const float* __restrict__ part,
                                                  unsigned short* __restrict__ ctxTb){
  const int bh = blockIdx.x, i = blockIdx.y, t = threadIdx.x;
  for (int idx = t; idx < 4096; idx += 256){
    float s = 0.f;
    #pragma unroll
    for (int kc = 0; kc < 8; ++kc)
      s += part[(((size_t)i*8 + kc)*32 + bh)*4096 + idx];
    ctxTb[((size_t)i*32 + bh)*4096 + idx] = f2bf(s);
  }
}

// ================= combine: omid = q + sum_i (q @ ctx_i) * Dinv_i =================
__global__ __launch_bounds__(256) void combine(const unsigned short* __restrict__ qb,
                                               const unsigned short* __restrict__ ctxTb,
                                               const float* __restrict__ ksum,
                                               unsigned short* __restrict__ omid){
  __shared__ unsigned short tile[128*128];
  const int hw = blockIdx.x;
  const int work = (hw & 7) * 64 + (hw >> 3);
  const int m0 = (work & 127) << 7, n0 = (work >> 7) << 7;
  const int t = threadIdx.x;
  const int w = t >> 6, l = t & 63;
  const int wr = w >> 1, wc = w & 1;
  const int lr = l & 15, lk = l >> 4;
  const int b = m0 >> 12;
  const int bh = b*8 + (n0 >> 6) + wc;
  #pragma unroll
  for (int p = 0; p < 8; ++p){
    int idx = p*256 + t;
    int row = idx >> 4, ch = idx & 15;
    gl_lds16(qb + (size_t)(m0+row)*C_ + n0 + (ch ^ (row & 7))*8, &tile[idx*8]);
  }
  WAIT_VM(0);
  __syncthreads();
  us8 afr[4][2];
  #pragma unroll
  for (int mt = 0; mt < 4; ++mt)
    #pragma unroll
    for (int kk = 0; kk < 2; ++kk){
      int row = wr*64 + mt*16 + lr;
      int ch = wc*8 + kk*4 + lk;
      afr[mt][kk] = *(const us8*)((const char*)tile + row*256 + ((ch ^ (row & 7)) << 4));
    }
  f32x4 acc[4][4];
  #pragma unroll
  for (int mt = 0; mt < 4; ++mt)
    #pragma unroll
    for (int nt = 0; nt < 4; ++nt)
      #pragma unroll
      for (int r = 0; r < 4; ++r){
        int row = wr*64 + mt*16 + lk*4 + r;
        int cbyte = wc*128 + nt*32 + lr*2;
        int ch = cbyte >> 4;
        unsigned short v = *(const unsigned short*)((const char*)tile + row*256 +
                            ((ch ^ (row & 7)) << 4) + (cbyte & 15));
        acc[mt][nt][r] = bf2f(v);
      }
  us8 bden[2];
  #pragma unroll
  for (int kk = 0; kk < 2; ++kk){
    us8 tmp = {};
    if (lr < 3){
      const float* kp = ksum + ((size_t)lr*B_ + b)*C_ + n0 + wc*64 + kk*32 + lk*8;
      f32x4 c0 = *(const f32x4*)kp;
      f32x4 c1 = *(const f32x4*)(kp + 4);
      #pragma unroll
      for (int j = 0; j < 4; ++j){ tmp[j] = f2bf(c0[j]); tmp[4+j] = f2bf(c1[j]); }
    }
    bden[kk] = tmp;
  }
  f32x4 den[4] = {};
  #pragma unroll
  for (int mt = 0; mt < 4; ++mt)
    #pragma unroll
    for (int kk = 0; kk < 2; ++kk)
      den[mt] = mfma16(afr[mt][kk], bden[kk], den[mt]);
  #pragma unroll 1
  for (int i = 0; i < 3; ++i){
    f32x4 dinv[4];
    #pragma unroll
    for (int mt = 0; mt < 4; ++mt)
      #pragma unroll
      for (int r = 0; r < 4; ++r)
        dinv[mt][r] = 1.0f / (__shfl(den[mt][r], (l & 48) | i, 64) + 1e-8f);
    #pragma unroll
    for (int nt = 0; nt < 4; ++nt){
      us8 bfr[2];
      #pragma unroll
      for (int kk = 0; kk < 2; ++kk)
        bfr[kk] = *(const us8*)(ctxTb + ((size_t)(i*32 + bh))*4096 + (nt*16 + lr)*64 + kk*32 + lk*8);
      f32x4 p[4] = {};
      #pragma unroll
      for (int mt = 0; mt < 4; ++mt)
        #pragma unroll
        for (int kk = 0; kk < 2; ++kk)
          p[mt] = mfma16(afr[mt][kk], bfr[kk], p[mt]);
      #pragma unroll
      for (int mt = 0; mt < 4; ++mt)
        #pragma unroll
        for (int r = 0; r < 4; ++r)
          acc[mt][nt][r] += p[mt][r] * dinv[mt][r];
    }
  }
  __syncthreads();
  tile_write(tile, acc, wr, wc, lr, lk);
  __syncthreads();
  tile_flush(tile, omid, m0, n0, C_, t);
}

// ---------------- O-proj GEMM (3-buf, depth-2 counted-vmcnt) ----------------
__global__ __launch_bounds__(256, 3) void gemm_bt(const unsigned short* __restrict__ A,
                                                  const unsigned short* __restrict__ Bw,
                                                  const float* __restrict__ bias,
                                                  float* __restrict__ out){
  __shared__ unsigned short smem[3*2*4096];
  const int hw = blockIdx.x;
  const int work = (hw & 7) * 64 + (hw >> 3);
  const int m0 = ((work >> 2) & 127) << 7, n0 = (work & 3) << 7;
  const int t = threadIdx.x;
  const int w = t >> 6, l = t & 63;
  const int wr = w >> 1, wc = w & 1;
  const int lr = l & 15, lk = l >> 4;
  f32x4 acc[4][4] = {};

#define GSTAGE(BB, TT) { \
    int c = t, row = c >> 2; \
    gl_lds16(A  + (size_t)(m0+row)*C_ + (TT)*32 + swz(row, c & 3)*8, &smem[(BB)*8192 + c*8]); \
    gl_lds16(Bw + (size_t)(n0+row)*C_ + (TT)*32 + swz(row, c & 3)*8, &smem[(BB)*8192 + 4096 + c*8]); \
    c = t + 256; row = c >> 2; \
    gl_lds16(A  + (size_t)(m0+row)*C_ + (TT)*32 + swz(row, c & 3)*8, &smem[(BB)*8192 + c*8]); \
    gl_lds16(Bw + (size_t)(n0+row)*C_ + (TT)*32 + swz(row, c & 3)*8, &smem[(BB)*8192 + 4096 + c*8]); }
#define GCOMP(BB) { \
    const unsigned short* sA = &smem[(BB)*8192]; \
    const unsigned short* sB = &smem[(BB)*8192 + 4096]; \
    us8 af[4], bfr[4]; \
    _Pragma("unroll") \
    for (int mt = 0; mt < 4; ++mt){ int R = wr*64 + mt*16 + lr; af[mt] = *(const us8*)&sA[R*32 + swz(R, lk)*8]; } \
    _Pragma("unroll") \
    for (int nt = 0; nt < 4; ++nt){ int R = wc*64 + nt*16 + lr; bfr[nt] = *(const us8*)&sB[R*32 + swz(R, lk)*8]; } \
    __builtin_amdgcn_s_setprio(1); \
    _Pragma("unroll") \
    for (int mt = 0; mt < 4; ++mt) \
      _Pragma("unroll") \
      for (int nt = 0; nt < 4; ++nt) \
        acc[mt][nt] = mfma16(af[mt], bfr[nt], acc[mt][nt]); \
    __builtin_amdgcn_s_setprio(0); }
#define GSTEP(T, N) { \
    if ((T) + 2 < 16) GSTAGE(((T)+2)%3, (T)+2); \
    WAIT_VM(N); \
    RAW_BAR(); \
    GCOMP((T)%3); }

  GSTAGE(0, 0); GSTAGE(1, 1);
  GSTEP(0, 8)  GSTEP(1, 8)  GSTEP(2, 8)  GSTEP(3, 8)
  GSTEP(4, 8)  GSTEP(5, 8)  GSTEP(6, 8)  GSTEP(7, 8)
  GSTEP(8, 8)  GSTEP(9, 8)  GSTEP(10, 8) GSTEP(11, 8)
  GSTEP(12, 8) GSTEP(13, 8) GSTEP(14, 4) GSTEP(15, 0)
#undef GSTAGE
#undef GCOMP
#undef GSTEP

  #pragma unroll
  for (int mt = 0; mt < 4; ++mt)
    #pragma unroll
    for (int nt = 0; nt < 4; ++nt)
      #pragma unroll
      for (int r = 0; r < 4; ++r){
        int row = m0 + wr*64 + mt*16 + lk*4 + r;
        int col = n0 + wc*64 + nt*16 + lr;
        out[(size_t)row*C_ + col] = acc[mt][nt][r] + bias[col];
      }
}

extern "C" void kernel_launch(void* const* d_in, const int* in_sizes, int n_in,
                              void* d_out, int out_size, void* d_ws, size_t ws_size,
                              hipStream_t stream){
  const float* x  = (const float*)d_in[0];
  const float* y0 = (const float*)d_in[1];
  const float* y1 = (const float*)d_in[2];
  const float* y2 = (const float*)d_in[3];
  const float* Wq = (const float*)d_in[4];
  const float* bq = (const float*)d_in[5];
  const float* Wk = (const float*)d_in[6];
  const float* bk = (const float*)d_in[7];
  const float* Wv = (const float*)d_in[8];
  const float* bv = (const float*)d_in[9];
  const float* Wo = (const float*)d_in[10];
  const float* bo = (const float*)d_in[11];

  char* ws = (char*)d_ws;
  size_t off = 0;
  auto alloc = [&](size_t bytes)->char*{
    char* p = ws + off; off += (bytes + 1023) & ~((size_t)1023); return p;
  };
  unsigned short* wqb   = (unsigned short*)alloc((size_t)C_*C_*2);
  unsigned short* wkb   = (unsigned short*)alloc((size_t)3*C_*C_*2);
  unsigned short* wvb   = (unsigned short*)alloc((size_t)3*C_*C_*2);
  unsigned short* wob   = (unsigned short*)alloc((size_t)C_*C_*2);
  unsigned short* qb    = (unsigned short*)alloc((size_t)M1_*C_*2);
  unsigned short* kbT   = (unsigned short*)alloc((size_t)3*B_*C_*T2_*2);
  unsigned short* vbT   = (unsigned short*)alloc((size_t)3*B_*C_*T2_*2);
  float*          ksum  = (float*)alloc((size_t)3*B_*C_*4);
  float*          part  = (float*)alloc((size_t)3*8*32*4096*4);
  unsigned short* ctxTb = (unsigned short*)alloc((size_t)3*32*4096*2);
  unsigned short* omid  = (unsigned short*)alloc((size_t)M1_*C_*2);

  (void)hipMemsetAsync(ksum, 0, (size_t)3*B_*C_*4, stream);

  // weights-only convert (~1.5 MB)
  cvt_bf16_4<<<dim3(3*C_*C_/4/256, 4), 256, 0, stream>>>(
      Wq, Wk, Wv, Wo, wqb, wkb, wvb, wob,
      C_*C_/4, 3*C_*C_/4, 3*C_*C_/4, C_*C_/4);

  proj<<<2048, 256, 0, stream>>>(x, y0, y1, y2, wqb, wkb, wvb, bq, bk, bv, qb, kbT, vbT, ksum);
  ctx_mfma<<<dim3(32, 8, 3), 256, 0, stream>>>(kbT, vbT, part);
  ctx_reduce<<<dim3(32, 3), 256, 0, stream>>>(part, ctxTb);
  combine<<<512, 256, 0, stream>>>(qb, ctxTb, ksum, omid);
  gemm_bt<<<512, 256, 0, stream>>>(omid, wob, bo, (float*)d_out);
}